// Round 3
// baseline (2222.123 us; speedup 1.0000x reference)
//
#include <hip/hip_runtime.h>
#include <hip/hip_fp16.h>

#define NHEAD 16
#define DHEAD 128
#define DMODEL 2048
#define SEQ 4096
#define BATCH 4
#define MROWS (BATCH*SEQ)   // 16384

typedef _Float16 f16x8 __attribute__((ext_vector_type(8)));
typedef _Float16 f16x4 __attribute__((ext_vector_type(4)));
typedef float f32x4 __attribute__((ext_vector_type(4)));

// ---------------- elementwise fp32 -> fp16 (hi, lo) split ----------------
__global__ __launch_bounds__(256) void split_f32_f16(
    const float* __restrict__ x, _Float16* __restrict__ hi,
    _Float16* __restrict__ lo, int n4) {
  int i = blockIdx.x * blockDim.x + threadIdx.x;
  int stride = gridDim.x * blockDim.x;
  for (; i < n4; i += stride) {
    float4 v = ((const float4*)x)[i];
    f16x4 h, l;
    h[0] = (_Float16)v.x; h[1] = (_Float16)v.y;
    h[2] = (_Float16)v.z; h[3] = (_Float16)v.w;
    ((f16x4*)hi)[i] = h;
    if (lo) {
      l[0] = (_Float16)(v.x - (float)h[0]);
      l[1] = (_Float16)(v.y - (float)h[1]);
      l[2] = (_Float16)(v.z - (float)h[2]);
      l[3] = (_Float16)(v.w - (float)h[3]);
      ((f16x4*)lo)[i] = l;
    }
  }
}

// ------------- weight transpose + split: W[K][N] -> WT[N][K] f16 ---------
__global__ __launch_bounds__(256) void transpose_split(
    const float* __restrict__ W, _Float16* __restrict__ hi,
    _Float16* __restrict__ lo, int rows, int cols) {
  __shared__ float tile[32][33];
  int tx = threadIdx.x, ty = threadIdx.y;          // 32 x 8
  int c = blockIdx.x * 32 + tx;
  for (int r0 = 0; r0 < 32; r0 += 8) {
    int r = blockIdx.y * 32 + ty + r0;
    tile[ty + r0][tx] = W[(size_t)r * cols + c];
  }
  __syncthreads();
  for (int r0 = 0; r0 < 32; r0 += 8) {
    int n = blockIdx.x * 32 + ty + r0;             // WT row = original col
    int k = blockIdx.y * 32 + tx;                  // WT col = original row
    float v = tile[tx][ty + r0];                   // = W[k][n]
    _Float16 h = (_Float16)v;
    hi[(size_t)n * rows + k] = h;
    if (lo) lo[(size_t)n * rows + k] = (_Float16)(v - (float)h);
  }
}

// ---- per-head column sums of W: CS[k][h] = sum_d W[k][h*128+d] ----------
// computed in fp64, stored fp32 (rel err 6e-8 into rs: far below budget)
__global__ __launch_bounds__(256) void colsum_f64(
    const float* __restrict__ W, float* __restrict__ CS) {
  const int k = blockIdx.x;                 // row of W
  const int t = threadIdx.x;
  const int h = t >> 4, s = t & 15;
  double acc = 0.0;
  const float* p = W + (size_t)k * DMODEL + h * DHEAD + s * 8;
#pragma unroll
  for (int i = 0; i < 8; i++) acc += (double)p[i];
#pragma unroll
  for (int m = 1; m < 16; m <<= 1) acc += __shfl_xor(acc, m, 64);
  if (s == 0) CS[(size_t)k * NHEAD + h] = (float)acc;
}

// ---- exact per-head row sums: rs[row][h] = sum_k X[row][k] * CS[k][h] ----
// coalesced CS walk: 16 h-lanes read consecutive floats; fp64 accumulate.
__global__ __launch_bounds__(256) void rowsum_f32cs(
    const float* __restrict__ X, const float* __restrict__ CS,
    float* __restrict__ rs) {
  const int t = threadIdx.x;
  const int h = t & 15, rl = t >> 4;        // 16 heads x 16 row-lanes
  const int r0 = blockIdx.x * 64;
#pragma unroll
  for (int j = 0; j < 4; j++) {
    const int row = r0 + rl + 16 * j;
    const float* xp = X + (size_t)row * DMODEL;
    double acc0 = 0.0, acc1 = 0.0;
#pragma unroll 4
    for (int k = 0; k < DMODEL; k += 2) {
      acc0 += (double)xp[k]     * (double)CS[(size_t)k       * NHEAD + h];
      acc1 += (double)xp[k + 1] * (double)CS[(size_t)(k + 1) * NHEAD + h];
    }
    rs[(size_t)row * NHEAD + h] = (float)(acc0 + acc1);
  }
}

// ---------------- fp16(-split) MFMA GEMM: C[M,N] = A[M,K] @ BT[N,K]^T ----
__device__ inline void glds16(const void* g, void* l) {
  __builtin_amdgcn_global_load_lds(
      (const __attribute__((address_space(1))) unsigned int*)g,
      (__attribute__((address_space(3))) unsigned int*)l, 16, 0, 0);
}

template <int NPASS, int OUT_HALF>
__global__ __launch_bounds__(256) void gemm_f16(
    const _Float16* __restrict__ Ahi, const _Float16* __restrict__ Alo,
    const _Float16* __restrict__ Bhi, const _Float16* __restrict__ Blo,
    float* __restrict__ Cf, _Float16* __restrict__ Ch,
    int M, int N, int Kd) {
  __shared__ _Float16 lds[4 * 128 * 32];
  _Float16* sAh = lds;
  _Float16* sAl = lds + 4096;
  _Float16* sBh = lds + 8192;
  _Float16* sBl = lds + 12288;

  const int t = threadIdx.x;
  const int lane = t & 63, wid = t >> 6;
  const int wm = wid >> 1, wn = wid & 1;           // 2x2 waves, 64x64 each
  const int lr = lane & 15, lk = (lane >> 4) * 8;

  // XCD-chunked bijective swizzle (nwg % 8 == 0) + ny-fast supertile order:
  // 16 consecutive same-XCD blocks share one A panel -> L2 reuse.
  const int mtiles = M >> 7, ntiles = N >> 7;
  const int nwg = mtiles * ntiles;
  const int qq = nwg >> 3;
  const int v = (blockIdx.x & 7) * qq + (blockIdx.x >> 3);
  const int mx = v / ntiles, ny = v % ntiles;
  const int m0 = mx * 128, n0 = ny * 128;

  f32x4 acc[4][4] = {};

  for (int k0 = 0; k0 < Kd; k0 += 32) {
    // stage: 128x32 f16 tile, linear LDS, 2 x 16B per thread per tile
#pragma unroll
    for (int i = 0; i < 2; i++) {
      int slot = t + i * 256;
      int row = slot >> 2, kc = (slot & 3) * 8;
      glds16(Ahi + (size_t)(m0 + row) * Kd + k0 + kc, sAh + slot * 8);
      glds16(Bhi + (size_t)(n0 + row) * Kd + k0 + kc, sBh + slot * 8);
      if (NPASS == 3) {
        glds16(Alo + (size_t)(m0 + row) * Kd + k0 + kc, sAl + slot * 8);
        glds16(Blo + (size_t)(n0 + row) * Kd + k0 + kc, sBl + slot * 8);
      }
    }
    __syncthreads();

    f16x8 ah[4], bh[4], al[4], bl[4];
#pragma unroll
    for (int f = 0; f < 4; f++) {
      ah[f] = *(const f16x8*)&sAh[(wm * 64 + f * 16 + lr) * 32 + lk];
      bh[f] = *(const f16x8*)&sBh[(wn * 64 + f * 16 + lr) * 32 + lk];
      if (NPASS == 3) {
        al[f] = *(const f16x8*)&sAl[(wm * 64 + f * 16 + lr) * 32 + lk];
        bl[f] = *(const f16x8*)&sBl[(wn * 64 + f * 16 + lr) * 32 + lk];
      }
    }
#pragma unroll
    for (int i = 0; i < 4; i++)
#pragma unroll
      for (int j = 0; j < 4; j++) {
        acc[i][j] = __builtin_amdgcn_mfma_f32_16x16x32_f16(ah[i], bh[j], acc[i][j], 0, 0, 0);
        if (NPASS == 3) {
          acc[i][j] = __builtin_amdgcn_mfma_f32_16x16x32_f16(ah[i], bl[j], acc[i][j], 0, 0, 0);
          acc[i][j] = __builtin_amdgcn_mfma_f32_16x16x32_f16(al[i], bh[j], acc[i][j], 0, 0, 0);
        }
      }
    __syncthreads();
  }

  // epilogue: C[row][col], row=(lane>>4)*4+r within 16-frag, col=lane&15
#pragma unroll
  for (int i = 0; i < 4; i++) {
    int row = m0 + wm * 64 + i * 16 + (lane >> 4) * 4;
#pragma unroll
    for (int j = 0; j < 4; j++) {
      int col = n0 + wn * 64 + j * 16 + (lane & 15);
#pragma unroll
      for (int r = 0; r < 4; r++) {
        if (OUT_HALF)
          Ch[(size_t)(row + r) * N + col] = (_Float16)acc[i][j][r];
        else
          Cf[(size_t)(row + r) * N + col] = acc[i][j][r];
      }
    }
  }
}

// -------- per-position head attention: 1 block (256 thr) per (b,s) -------
__global__ __launch_bounds__(256) void attn_kernel(
    const float* __restrict__ Q, const float* __restrict__ K,
    const _Float16* __restrict__ V, const float* __restrict__ mask,
    const float* __restrict__ rsQ, const float* __restrict__ rsK,
    float* __restrict__ wout, _Float16* __restrict__ aout) {
  __shared__ float lq[16][129], lkk[16][129], lv[16][128], lw[16][16];
  const int pos = blockIdx.x;
  const int t = threadIdx.x;
  const int h = t >> 4, j = t & 15;
  const size_t base = (size_t)pos * DMODEL + h * DHEAD + j;

  // load q and k rows; normalize by the EXACT (fp64-path) row sums
  const float iq = 1.f / (rsQ[(size_t)pos * NHEAD + h] + 1e-6f);
  const float ik = 1.f / (rsK[(size_t)pos * NHEAD + h] + 1e-6f);
#pragma unroll
  for (int i = 0; i < 8; i++) lq[h][j + 16 * i] = Q[base + 16 * i] * iq;
#pragma unroll
  for (int i = 0; i < 8; i++) lkk[h][j + 16 * i] = K[base + 16 * i] * ik;
#pragma unroll
  for (int i = 0; i < 8; i++) lv[h][j + 16 * i] = (float)V[base + 16 * i];
  __syncthreads();

  // logits: thread t -> (q=h, k=j)
  float dot = 0.f;
#pragma unroll 8
  for (int d = 0; d < 128; d++) dot += lq[h][d] * lkk[j][d];
  float mk = mask[(size_t)pos * 256 + t];
  float x = (dot - 1e9f * mk) * 0.08838834764831845f;  // 1/sqrt(128)
  float mx = x;
#pragma unroll
  for (int m = 1; m < 16; m <<= 1) mx = fmaxf(mx, __shfl_xor(mx, m, 64));
  float e = expf(x - mx);
  float den = e;
#pragma unroll
  for (int m = 1; m < 16; m <<= 1) den += __shfl_xor(den, m, 64);
  float w = e / den;
  wout[(size_t)pos * 256 + t] = w;
  lw[h][j] = w;
  __syncthreads();

  // attn[q][d] = sum_k w[q][k] * v[k][d]; thread t -> q=h, d = j + 16*i
#pragma unroll
  for (int i = 0; i < 8; i++) {
    int d = j + 16 * i;
    float a = 0.f;
#pragma unroll
    for (int k2 = 0; k2 < 16; k2++) a += lw[h][k2] * lv[k2][d];
    aout[(size_t)pos * DMODEL + h * DHEAD + d] = (_Float16)a;
  }
}

// -------------------------------------------------------------------------
extern "C" void kernel_launch(void* const* d_in, const int* in_sizes, int n_in,
                              void* d_out, int out_size, void* d_ws, size_t ws_size,
                              hipStream_t stream) {
  const float* query = (const float*)d_in[0];
  const float* key   = (const float*)d_in[1];
  const float* value = (const float*)d_in[2];
  const float* mask  = (const float*)d_in[3];
  const float* Wq = (const float*)d_in[4];
  const float* Wk = (const float*)d_in[5];
  const float* Wv = (const float*)d_in[6];
  const float* Wo = (const float*)d_in[7];

  float* out  = (float*)d_out;                       // [16384, 2048] fp32
  float* wout = out + (size_t)MROWS * DMODEL;        // [16384, 256] fp32

  const size_t SZ_HALF = (size_t)MROWS * DMODEL * 2; // 67.1 MB
  const size_t SZ_F32  = (size_t)MROWS * DMODEL * 4; // 134.2 MB
  const size_t SZ_W    = (size_t)DMODEL * DMODEL * 2;// 8.4 MB
  const size_t SZ_CS   = (size_t)DMODEL * NHEAD * 4; // 128 KB (fp32)
  const size_t SZ_RS   = (size_t)MROWS * NHEAD * 4;  // 1 MB
  const size_t NEED = 3 * SZ_HALF + SZ_F32 + 2 * SZ_W + 2 * SZ_CS + 2 * SZ_RS;
  if (ws_size < NEED) return;  // workspace too small — fail visibly

  char* ws = (char*)d_ws;
  _Float16* a_hi  = (_Float16*)ws;
  _Float16* a_lo  = (_Float16*)(ws + SZ_HALF);
  float*    Kbuf  = (float*)   (ws + 2 * SZ_HALF);
  _Float16* Vbuf  = (_Float16*)(ws + 2 * SZ_HALF + SZ_F32);
  _Float16* wT_hi = (_Float16*)(ws + 3 * SZ_HALF + SZ_F32);
  _Float16* wT_lo = (_Float16*)(ws + 3 * SZ_HALF + SZ_F32 + SZ_W);
  float*    CSq   = (float*)   (ws + 3 * SZ_HALF + SZ_F32 + 2 * SZ_W);
  float*    CSk   = (float*)   (ws + 3 * SZ_HALF + SZ_F32 + 2 * SZ_W + SZ_CS);
  float*    rsQ   = (float*)   (ws + 3 * SZ_HALF + SZ_F32 + 2 * SZ_W + 2 * SZ_CS);
  float*    rsK   = (float*)   (ws + 3 * SZ_HALF + SZ_F32 + 2 * SZ_W + 2 * SZ_CS + SZ_RS);
  _Float16* attn  = a_hi;        // reused after V-GEMM consumed a_hi
  float*    Qbuf  = out;         // Q fp32 parked in d_out, overwritten last

  const int n4 = MROWS * DMODEL / 4;
  const int ggrid = (MROWS / 128) * (DMODEL / 128);  // 2048 blocks, 1D
  dim3 tgrid(DMODEL / 32, DMODEL / 32);
  dim3 tblk(32, 8);

  // exact per-head row sums (fp64 accumulate, fp32 colsum table)
  colsum_f64<<<DMODEL, 256, 0, stream>>>(Wq, CSq);
  colsum_f64<<<DMODEL, 256, 0, stream>>>(Wk, CSk);
  rowsum_f32cs<<<MROWS / 64, 256, 0, stream>>>(query, CSq, rsQ);
  rowsum_f32cs<<<MROWS / 64, 256, 0, stream>>>(key, CSk, rsK);

  // Q path (3-pass split fp16 -> near-fp32)
  split_f32_f16<<<4096, 256, 0, stream>>>(query, a_hi, a_lo, n4);
  transpose_split<<<tgrid, tblk, 0, stream>>>(Wq, wT_hi, wT_lo, DMODEL, DMODEL);
  gemm_f16<3, 0><<<ggrid, 256, 0, stream>>>(a_hi, a_lo, wT_hi, wT_lo,
                                            Qbuf, nullptr, MROWS, DMODEL, DMODEL);
  // K path
  split_f32_f16<<<4096, 256, 0, stream>>>(key, a_hi, a_lo, n4);
  transpose_split<<<tgrid, tblk, 0, stream>>>(Wk, wT_hi, wT_lo, DMODEL, DMODEL);
  gemm_f16<3, 0><<<ggrid, 256, 0, stream>>>(a_hi, a_lo, wT_hi, wT_lo,
                                            Kbuf, nullptr, MROWS, DMODEL, DMODEL);
  // V path (1-pass fp16)
  split_f32_f16<<<4096, 256, 0, stream>>>(value, a_hi, nullptr, n4);
  transpose_split<<<tgrid, tblk, 0, stream>>>(Wv, wT_hi, nullptr, DMODEL, DMODEL);
  gemm_f16<1, 1><<<ggrid, 256, 0, stream>>>(a_hi, nullptr, wT_hi, nullptr,
                                            nullptr, Vbuf, MROWS, DMODEL, DMODEL);
  // per-position head attention
  attn_kernel<<<MROWS, 256, 0, stream>>>(Qbuf, Kbuf, Vbuf, mask, rsQ, rsK, wout, attn);
  // output GEMM (1-pass fp16)
  transpose_split<<<tgrid, tblk, 0, stream>>>(Wo, wT_hi, nullptr, DMODEL, DMODEL);
  gemm_f16<1, 0><<<ggrid, 256, 0, stream>>>(attn, nullptr, wT_hi, nullptr,
                                            out, nullptr, MROWS, DMODEL, DMODEL);
}

// Round 4
// 2198.158 us; speedup vs baseline: 1.0109x; 1.0109x over previous
//
#include <hip/hip_runtime.h>
#include <hip/hip_fp16.h>

#define NHEAD 16
#define DHEAD 128
#define DMODEL 2048
#define SEQ 4096
#define BATCH 4
#define MROWS (BATCH*SEQ)   // 16384

typedef _Float16 f16x8 __attribute__((ext_vector_type(8)));
typedef _Float16 f16x4 __attribute__((ext_vector_type(4)));
typedef float f32x4 __attribute__((ext_vector_type(4)));

// ---------------- elementwise fp32 -> fp16 (hi, lo) split ----------------
__global__ __launch_bounds__(256) void split_f32_f16(
    const float* __restrict__ x, _Float16* __restrict__ hi,
    _Float16* __restrict__ lo, int n4) {
  int i = blockIdx.x * blockDim.x + threadIdx.x;
  int stride = gridDim.x * blockDim.x;
  for (; i < n4; i += stride) {
    float4 v = ((const float4*)x)[i];
    f16x4 h, l;
    h[0] = (_Float16)v.x; h[1] = (_Float16)v.y;
    h[2] = (_Float16)v.z; h[3] = (_Float16)v.w;
    ((f16x4*)hi)[i] = h;
    if (lo) {
      l[0] = (_Float16)(v.x - (float)h[0]);
      l[1] = (_Float16)(v.y - (float)h[1]);
      l[2] = (_Float16)(v.z - (float)h[2]);
      l[3] = (_Float16)(v.w - (float)h[3]);
      ((f16x4*)lo)[i] = l;
    }
  }
}

// ------------- weight transpose + split: W[K][N] -> WT[N][K] f16 ---------
__global__ __launch_bounds__(256) void transpose_split(
    const float* __restrict__ W, _Float16* __restrict__ hi,
    _Float16* __restrict__ lo, int rows, int cols) {
  __shared__ float tile[32][33];
  int tx = threadIdx.x, ty = threadIdx.y;          // 32 x 8
  int c = blockIdx.x * 32 + tx;
  for (int r0 = 0; r0 < 32; r0 += 8) {
    int r = blockIdx.y * 32 + ty + r0;
    tile[ty + r0][tx] = W[(size_t)r * cols + c];
  }
  __syncthreads();
  for (int r0 = 0; r0 < 32; r0 += 8) {
    int n = blockIdx.x * 32 + ty + r0;             // WT row = original col
    int k = blockIdx.y * 32 + tx;                  // WT col = original row
    float v = tile[tx][ty + r0];                   // = W[k][n]
    _Float16 h = (_Float16)v;
    hi[(size_t)n * rows + k] = h;
    if (lo) lo[(size_t)n * rows + k] = (_Float16)(v - (float)h);
  }
}

// ---- per-head column sums of W: CS[k][h] = sum_d W[k][h*128+d] ----------
__global__ __launch_bounds__(256) void colsum_f64(
    const float* __restrict__ W, float* __restrict__ CS) {
  const int k = blockIdx.x;                 // row of W
  const int t = threadIdx.x;
  const int h = t >> 4, s = t & 15;
  double acc = 0.0;
  const float* p = W + (size_t)k * DMODEL + h * DHEAD + s * 8;
#pragma unroll
  for (int i = 0; i < 8; i++) acc += (double)p[i];
#pragma unroll
  for (int m = 1; m < 16; m <<= 1) acc += __shfl_xor(acc, m, 64);
  if (s == 0) CS[(size_t)k * NHEAD + h] = (float)acc;
}

// ---- exact per-head row sums: rs[row][h] = sum_k X[row][k] * CS[k][h] ----
__global__ __launch_bounds__(256) void rowsum_f32cs(
    const float* __restrict__ X, const float* __restrict__ CS,
    float* __restrict__ rs) {
  const int t = threadIdx.x;
  const int h = t & 15, rl = t >> 4;        // 16 heads x 16 row-lanes
  const int r0 = blockIdx.x * 64;
#pragma unroll
  for (int j = 0; j < 4; j++) {
    const int row = r0 + rl + 16 * j;
    const float* xp = X + (size_t)row * DMODEL;
    double acc0 = 0.0, acc1 = 0.0;
#pragma unroll 4
    for (int k = 0; k < DMODEL; k += 2) {
      acc0 += (double)xp[k]     * (double)CS[(size_t)k       * NHEAD + h];
      acc1 += (double)xp[k + 1] * (double)CS[(size_t)(k + 1) * NHEAD + h];
    }
    rs[(size_t)row * NHEAD + h] = (float)(acc0 + acc1);
  }
}

// ---------------- fp16(-split) MFMA GEMM: C[M,N] = A[M,K] @ BT[N,K]^T ----
__device__ inline void glds16(const void* g, void* l) {
  __builtin_amdgcn_global_load_lds(
      (const __attribute__((address_space(1))) unsigned int*)g,
      (__attribute__((address_space(3))) unsigned int*)l, 16, 0, 0);
}

template <int NPASS, int OUT_HALF>
__global__ __launch_bounds__(256) void gemm_f16(
    const _Float16* __restrict__ Ahi, const _Float16* __restrict__ Alo,
    const _Float16* __restrict__ Bhi, const _Float16* __restrict__ Blo,
    float* __restrict__ Cf, _Float16* __restrict__ Ch,
    int M, int N, int Kd) {
  constexpr int TILE = 128 * 32;                   // elems per LDS tile
  __shared__ _Float16 lds[(NPASS == 3 ? 4 : 2) * TILE];
  _Float16* sAh = lds;
  _Float16* sBh = lds + (NPASS == 3 ? 2 : 1) * TILE;
  _Float16* sAl = lds + TILE;                      // used only if NPASS==3
  _Float16* sBl = lds + 3 * TILE;                  // used only if NPASS==3

  const int t = threadIdx.x;
  const int lane = t & 63, wid = t >> 6;
  const int wm = wid >> 1, wn = wid & 1;           // 2x2 waves, 64x64 each
  const int lr = lane & 15, lk = (lane >> 4) * 8;

  // XCD-chunked bijective swizzle (nwg % 8 == 0) + ny-fast supertile order
  const int mtiles = M >> 7, ntiles = N >> 7;
  const int nwg = mtiles * ntiles;
  const int qq = nwg >> 3;
  const int v = (blockIdx.x & 7) * qq + (blockIdx.x >> 3);
  const int mx = v / ntiles, ny = v % ntiles;
  const int m0 = mx * 128, n0 = ny * 128;

  f32x4 acc[4][4] = {};

  for (int k0 = 0; k0 < Kd; k0 += 32) {
#pragma unroll
    for (int i = 0; i < 2; i++) {
      int slot = t + i * 256;
      int row = slot >> 2, kc = (slot & 3) * 8;
      glds16(Ahi + (size_t)(m0 + row) * Kd + k0 + kc, sAh + slot * 8);
      glds16(Bhi + (size_t)(n0 + row) * Kd + k0 + kc, sBh + slot * 8);
      if (NPASS == 3) {
        glds16(Alo + (size_t)(m0 + row) * Kd + k0 + kc, sAl + slot * 8);
        glds16(Blo + (size_t)(n0 + row) * Kd + k0 + kc, sBl + slot * 8);
      }
    }
    __syncthreads();

    f16x8 ah[4], bh[4], al[4], bl[4];
#pragma unroll
    for (int f = 0; f < 4; f++) {
      ah[f] = *(const f16x8*)&sAh[(wm * 64 + f * 16 + lr) * 32 + lk];
      bh[f] = *(const f16x8*)&sBh[(wn * 64 + f * 16 + lr) * 32 + lk];
      if (NPASS == 3) {
        al[f] = *(const f16x8*)&sAl[(wm * 64 + f * 16 + lr) * 32 + lk];
        bl[f] = *(const f16x8*)&sBl[(wn * 64 + f * 16 + lr) * 32 + lk];
      }
    }
#pragma unroll
    for (int i = 0; i < 4; i++)
#pragma unroll
      for (int j = 0; j < 4; j++) {
        acc[i][j] = __builtin_amdgcn_mfma_f32_16x16x32_f16(ah[i], bh[j], acc[i][j], 0, 0, 0);
        if (NPASS == 3) {
          acc[i][j] = __builtin_amdgcn_mfma_f32_16x16x32_f16(ah[i], bl[j], acc[i][j], 0, 0, 0);
          acc[i][j] = __builtin_amdgcn_mfma_f32_16x16x32_f16(al[i], bh[j], acc[i][j], 0, 0, 0);
        }
      }
    __syncthreads();
  }

#pragma unroll
  for (int i = 0; i < 4; i++) {
    int row = m0 + wm * 64 + i * 16 + (lane >> 4) * 4;
#pragma unroll
    for (int j = 0; j < 4; j++) {
      int col = n0 + wn * 64 + j * 16 + (lane & 15);
#pragma unroll
      for (int r = 0; r < 4; r++) {
        if (OUT_HALF)
          Ch[(size_t)(row + r) * N + col] = (_Float16)acc[i][j][r];
        else
          Cf[(size_t)(row + r) * N + col] = acc[i][j][r];
      }
    }
  }
}

// -------- per-position head attention: 1 block (256 thr) per (b,s) -------
// Vectorized LDS data paths: b128 reads/writes, conflict-free lane layouts.
__global__ __launch_bounds__(256) void attn_kernel(
    const float* __restrict__ Q, const float* __restrict__ K,
    const _Float16* __restrict__ V, const float* __restrict__ mask,
    const float* __restrict__ rsQ, const float* __restrict__ rsK,
    float* __restrict__ wout, _Float16* __restrict__ aout) {
  __shared__ float lq[16][132], lkk[16][132], lv[16][132];
  __shared__ float lw[16][17];
  const int pos = blockIdx.x;
  const int t = threadIdx.x;
  const int h = t >> 4, j = t & 15;
  const size_t rowbase = (size_t)pos * DMODEL + h * DHEAD;

  const float iq = 1.f / (rsQ[(size_t)pos * NHEAD + h] + 1e-6f);
  const float ik = 1.f / (rsK[(size_t)pos * NHEAD + h] + 1e-6f);

  // stage: thread (h,j) covers d = 4j..4j+3 and 64+4j..64+4j+3
  {
    const int dlo = 4 * j, dhi = 64 + 4 * j;
    float4 q0 = *(const float4*)&Q[rowbase + dlo];
    float4 q1 = *(const float4*)&Q[rowbase + dhi];
    q0.x *= iq; q0.y *= iq; q0.z *= iq; q0.w *= iq;
    q1.x *= iq; q1.y *= iq; q1.z *= iq; q1.w *= iq;
    *(float4*)&lq[h][dlo] = q0;
    *(float4*)&lq[h][dhi] = q1;
    float4 k0 = *(const float4*)&K[rowbase + dlo];
    float4 k1 = *(const float4*)&K[rowbase + dhi];
    k0.x *= ik; k0.y *= ik; k0.z *= ik; k0.w *= ik;
    k1.x *= ik; k1.y *= ik; k1.z *= ik; k1.w *= ik;
    *(float4*)&lkk[h][dlo] = k0;
    *(float4*)&lkk[h][dhi] = k1;
    f16x4 v0 = *(const f16x4*)&V[rowbase + dlo];
    f16x4 v1 = *(const f16x4*)&V[rowbase + dhi];
    float4 vf0 = {(float)v0[0], (float)v0[1], (float)v0[2], (float)v0[3]};
    float4 vf1 = {(float)v1[0], (float)v1[1], (float)v1[2], (float)v1[3]};
    *(float4*)&lv[h][dlo] = vf0;
    *(float4*)&lv[h][dhi] = vf1;
  }
  __syncthreads();

  // logits: thread (h,j) -> full 128-dot via float4
  const float4* qr = (const float4*)&lq[h][0];
  const float4* kr = (const float4*)&lkk[j][0];
  float dot = 0.f;
#pragma unroll
  for (int d4 = 0; d4 < 32; d4++) {
    float4 a = qr[d4], b = kr[d4];
    dot = fmaf(a.x, b.x, dot); dot = fmaf(a.y, b.y, dot);
    dot = fmaf(a.z, b.z, dot); dot = fmaf(a.w, b.w, dot);
  }
  float mk = mask[(size_t)pos * 256 + t];
  float x = (dot - 1e9f * mk) * 0.08838834764831845f;  // 1/sqrt(128)
  float mx = x;
#pragma unroll
  for (int m = 1; m < 16; m <<= 1) mx = fmaxf(mx, __shfl_xor(mx, m, 64));
  float e = expf(x - mx);
  float den = e;
#pragma unroll
  for (int m = 1; m < 16; m <<= 1) den += __shfl_xor(den, m, 64);
  float w = e / den;
  wout[(size_t)pos * 256 + t] = w;
  lw[h][j] = w;
  __syncthreads();

  // PV: thread (h,j) computes attn[h][4j..4j+3] and attn[h][64+4j..+3]
  float wreg[16];
#pragma unroll
  for (int k2 = 0; k2 < 16; k2++) wreg[k2] = lw[h][k2];
  float4 a0 = {0.f, 0.f, 0.f, 0.f}, a1 = {0.f, 0.f, 0.f, 0.f};
  const int dlo = 4 * j, dhi = 64 + 4 * j;
#pragma unroll
  for (int k2 = 0; k2 < 16; k2++) {
    float4 v0 = *(const float4*)&lv[k2][dlo];
    float4 v1 = *(const float4*)&lv[k2][dhi];
    float wk = wreg[k2];
    a0.x = fmaf(wk, v0.x, a0.x); a0.y = fmaf(wk, v0.y, a0.y);
    a0.z = fmaf(wk, v0.z, a0.z); a0.w = fmaf(wk, v0.w, a0.w);
    a1.x = fmaf(wk, v1.x, a1.x); a1.y = fmaf(wk, v1.y, a1.y);
    a1.z = fmaf(wk, v1.z, a1.z); a1.w = fmaf(wk, v1.w, a1.w);
  }
  f16x4 o0, o1;
  o0[0] = (_Float16)a0.x; o0[1] = (_Float16)a0.y;
  o0[2] = (_Float16)a0.z; o0[3] = (_Float16)a0.w;
  o1[0] = (_Float16)a1.x; o1[1] = (_Float16)a1.y;
  o1[2] = (_Float16)a1.z; o1[3] = (_Float16)a1.w;
  *(f16x4*)&aout[rowbase + dlo] = o0;
  *(f16x4*)&aout[rowbase + dhi] = o1;
}

// -------------------------------------------------------------------------
extern "C" void kernel_launch(void* const* d_in, const int* in_sizes, int n_in,
                              void* d_out, int out_size, void* d_ws, size_t ws_size,
                              hipStream_t stream) {
  const float* query = (const float*)d_in[0];
  const float* key   = (const float*)d_in[1];
  const float* value = (const float*)d_in[2];
  const float* mask  = (const float*)d_in[3];
  const float* Wq = (const float*)d_in[4];
  const float* Wk = (const float*)d_in[5];
  const float* Wv = (const float*)d_in[6];
  const float* Wo = (const float*)d_in[7];

  float* out  = (float*)d_out;                       // [16384, 2048] fp32
  float* wout = out + (size_t)MROWS * DMODEL;        // [16384, 256] fp32

  const size_t SZ_HALF = (size_t)MROWS * DMODEL * 2; // 67.1 MB
  const size_t SZ_F32  = (size_t)MROWS * DMODEL * 4; // 134.2 MB
  const size_t SZ_W    = (size_t)DMODEL * DMODEL * 2;// 8.4 MB
  const size_t SZ_CS   = (size_t)DMODEL * NHEAD * 4; // 128 KB (fp32)
  const size_t SZ_RS   = (size_t)MROWS * NHEAD * 4;  // 1 MB
  const size_t NEED = 3 * SZ_HALF + SZ_F32 + 2 * SZ_W + 2 * SZ_CS + 2 * SZ_RS;
  if (ws_size < NEED) return;  // workspace too small — fail visibly

  char* ws = (char*)d_ws;
  _Float16* a_hi  = (_Float16*)ws;
  _Float16* a_lo  = (_Float16*)(ws + SZ_HALF);
  float*    Kbuf  = (float*)   (ws + 2 * SZ_HALF);
  _Float16* Vbuf  = (_Float16*)(ws + 2 * SZ_HALF + SZ_F32);
  _Float16* wT_hi = (_Float16*)(ws + 3 * SZ_HALF + SZ_F32);
  _Float16* wT_lo = (_Float16*)(ws + 3 * SZ_HALF + SZ_F32 + SZ_W);
  float*    CSq   = (float*)   (ws + 3 * SZ_HALF + SZ_F32 + 2 * SZ_W);
  float*    CSk   = (float*)   (ws + 3 * SZ_HALF + SZ_F32 + 2 * SZ_W + SZ_CS);
  float*    rsQ   = (float*)   (ws + 3 * SZ_HALF + SZ_F32 + 2 * SZ_W + 2 * SZ_CS);
  float*    rsK   = (float*)   (ws + 3 * SZ_HALF + SZ_F32 + 2 * SZ_W + 2 * SZ_CS + SZ_RS);
  _Float16* attn  = a_hi;        // reused after V-GEMM consumed a_hi
  float*    Qbuf  = out;         // Q fp32 parked in d_out, overwritten last

  const int n4 = MROWS * DMODEL / 4;
  const int ggrid = (MROWS / 128) * (DMODEL / 128);  // 2048 blocks, 1D
  dim3 tgrid(DMODEL / 32, DMODEL / 32);
  dim3 tblk(32, 8);

  // exact per-head row sums (fp64 accumulate, fp32 colsum table)
  colsum_f64<<<DMODEL, 256, 0, stream>>>(Wq, CSq);
  colsum_f64<<<DMODEL, 256, 0, stream>>>(Wk, CSk);
  rowsum_f32cs<<<MROWS / 64, 256, 0, stream>>>(query, CSq, rsQ);
  rowsum_f32cs<<<MROWS / 64, 256, 0, stream>>>(key, CSk, rsK);

  // Q path (3-pass split fp16 -> near-fp32)
  split_f32_f16<<<4096, 256, 0, stream>>>(query, a_hi, a_lo, n4);
  transpose_split<<<tgrid, tblk, 0, stream>>>(Wq, wT_hi, wT_lo, DMODEL, DMODEL);
  gemm_f16<3, 0><<<ggrid, 256, 0, stream>>>(a_hi, a_lo, wT_hi, wT_lo,
                                            Qbuf, nullptr, MROWS, DMODEL, DMODEL);
  // K path
  split_f32_f16<<<4096, 256, 0, stream>>>(key, a_hi, a_lo, n4);
  transpose_split<<<tgrid, tblk, 0, stream>>>(Wk, wT_hi, wT_lo, DMODEL, DMODEL);
  gemm_f16<3, 0><<<ggrid, 256, 0, stream>>>(a_hi, a_lo, wT_hi, wT_lo,
                                            Kbuf, nullptr, MROWS, DMODEL, DMODEL);
  // V path (1-pass fp16)
  split_f32_f16<<<4096, 256, 0, stream>>>(value, a_hi, nullptr, n4);
  transpose_split<<<tgrid, tblk, 0, stream>>>(Wv, wT_hi, nullptr, DMODEL, DMODEL);
  gemm_f16<1, 1><<<ggrid, 256, 0, stream>>>(a_hi, nullptr, wT_hi, nullptr,
                                            nullptr, Vbuf, MROWS, DMODEL, DMODEL);
  // per-position head attention
  attn_kernel<<<MROWS, 256, 0, stream>>>(Qbuf, Kbuf, Vbuf, mask, rsQ, rsK, wout, attn);
  // output GEMM (1-pass fp16)
  transpose_split<<<tgrid, tblk, 0, stream>>>(Wo, wT_hi, nullptr, DMODEL, DMODEL);
  gemm_f16<1, 0><<<ggrid, 256, 0, stream>>>(attn, nullptr, wT_hi, nullptr,
                                            out, nullptr, MROWS, DMODEL, DMODEL);
}

// Round 5
// 2071.778 us; speedup vs baseline: 1.0726x; 1.0610x over previous
//
#include <hip/hip_runtime.h>
#include <hip/hip_fp16.h>

#define NHEAD 16
#define DHEAD 128
#define DMODEL 2048
#define SEQ 4096
#define BATCH 4
#define MROWS (BATCH*SEQ)   // 16384

typedef _Float16 f16x8 __attribute__((ext_vector_type(8)));
typedef _Float16 f16x4 __attribute__((ext_vector_type(4)));
typedef float f32x4 __attribute__((ext_vector_type(4)));

// ---------------- fp32 -> fp16 (hi, lo) split, 8 elems/thread ------------
__device__ inline void split8(const float* __restrict__ x, _Float16* __restrict__ hi,
                              _Float16* __restrict__ lo, int i8) {
  float4 v0 = ((const float4*)x)[2 * i8];
  float4 v1 = ((const float4*)x)[2 * i8 + 1];
  f16x8 h, l;
  h[0] = (_Float16)v0.x; h[1] = (_Float16)v0.y;
  h[2] = (_Float16)v0.z; h[3] = (_Float16)v0.w;
  h[4] = (_Float16)v1.x; h[5] = (_Float16)v1.y;
  h[6] = (_Float16)v1.z; h[7] = (_Float16)v1.w;
  ((f16x8*)hi)[i8] = h;
  if (lo) {
    l[0] = (_Float16)(v0.x - (float)h[0]);
    l[1] = (_Float16)(v0.y - (float)h[1]);
    l[2] = (_Float16)(v0.z - (float)h[2]);
    l[3] = (_Float16)(v0.w - (float)h[3]);
    l[4] = (_Float16)(v1.x - (float)h[4]);
    l[5] = (_Float16)(v1.y - (float)h[5]);
    l[6] = (_Float16)(v1.z - (float)h[6]);
    l[7] = (_Float16)(v1.w - (float)h[7]);
    ((f16x8*)lo)[i8] = l;
  }
}

// one matrix per launch (fallback path)
__global__ __launch_bounds__(256) void split_f32_f16(
    const float* __restrict__ x, _Float16* __restrict__ hi,
    _Float16* __restrict__ lo, int n8) {
  int i = blockIdx.x * blockDim.x + threadIdx.x;
  int stride = gridDim.x * blockDim.x;
  for (; i < n8; i += stride) split8(x, hi, lo, i);
}

// all three matrices in one launch (blockIdx.y selects)
__global__ __launch_bounds__(256) void split_all(
    const float* __restrict__ q, const float* __restrict__ k,
    const float* __restrict__ v,
    _Float16* __restrict__ qh, _Float16* __restrict__ ql,
    _Float16* __restrict__ kh, _Float16* __restrict__ kl,
    _Float16* __restrict__ vh, int n8) {
  const float* x; _Float16* hi; _Float16* lo;
  if (blockIdx.y == 0)      { x = q; hi = qh; lo = ql; }
  else if (blockIdx.y == 1) { x = k; hi = kh; lo = kl; }
  else                      { x = v; hi = vh; lo = nullptr; }
  int i = blockIdx.x * blockDim.x + threadIdx.x;
  int stride = gridDim.x * blockDim.x;
  for (; i < n8; i += stride) split8(x, hi, lo, i);
}

// ------------- weight transpose + split: W[K][N] -> WT[N][K] f16 ---------
__device__ inline void transpose_body(const float* __restrict__ W,
                                      _Float16* __restrict__ hi,
                                      _Float16* __restrict__ lo,
                                      int bx, int by, int tx, int ty) {
  __shared__ float tile[32][33];
  int c = bx * 32 + tx;
  for (int r0 = 0; r0 < 32; r0 += 8) {
    int r = by * 32 + ty + r0;
    tile[ty + r0][tx] = W[(size_t)r * DMODEL + c];
  }
  __syncthreads();
  for (int r0 = 0; r0 < 32; r0 += 8) {
    int n = bx * 32 + ty + r0;             // WT row = original col
    int k = by * 32 + tx;                  // WT col = original row
    float v = tile[tx][ty + r0];           // = W[k][n]
    _Float16 h = (_Float16)v;
    hi[(size_t)n * DMODEL + k] = h;
    if (lo) lo[(size_t)n * DMODEL + k] = (_Float16)(v - (float)h);
  }
}

__global__ __launch_bounds__(256) void transpose_split(
    const float* __restrict__ W, _Float16* __restrict__ hi,
    _Float16* __restrict__ lo) {
  transpose_body(W, hi, lo, blockIdx.x, blockIdx.y, threadIdx.x, threadIdx.y);
}

// all four weights in one launch (blockIdx.z selects)
__global__ __launch_bounds__(256) void transpose_all(
    const float* __restrict__ Wq, const float* __restrict__ Wk,
    const float* __restrict__ Wv, const float* __restrict__ Wo,
    _Float16* __restrict__ qh, _Float16* __restrict__ ql,
    _Float16* __restrict__ kh, _Float16* __restrict__ kl,
    _Float16* __restrict__ vh, _Float16* __restrict__ oh) {
  const float* W; _Float16* hi; _Float16* lo;
  switch (blockIdx.z) {
    case 0:  W = Wq; hi = qh; lo = ql;      break;
    case 1:  W = Wk; hi = kh; lo = kl;      break;
    case 2:  W = Wv; hi = vh; lo = nullptr; break;
    default: W = Wo; hi = oh; lo = nullptr; break;
  }
  transpose_body(W, hi, lo, blockIdx.x, blockIdx.y, threadIdx.x, threadIdx.y);
}

// ---- per-head column sums of W, stored TRANSPOSED: CS_T[h][k] -----------
__global__ __launch_bounds__(256) void colsum_f64(
    const float* __restrict__ W, float* __restrict__ CS) {
  const int k = blockIdx.x;                 // row of W
  const int t = threadIdx.x;
  const int h = t >> 4, s = t & 15;
  double acc = 0.0;
  const float* p = W + (size_t)k * DMODEL + h * DHEAD + s * 8;
#pragma unroll
  for (int i = 0; i < 8; i++) acc += (double)p[i];
#pragma unroll
  for (int m = 1; m < 16; m <<= 1) acc += __shfl_xor(acc, m, 64);
  if (s == 0) CS[(size_t)h * DMODEL + k] = (float)acc;
}

// ---- exact per-head row sums for BOTH q and k: rs[row][h] ---------------
__global__ __launch_bounds__(256) void rowsum_qk(
    const float* __restrict__ q, const float* __restrict__ k,
    const float* __restrict__ CSq, const float* __restrict__ CSk,
    float* __restrict__ rsQ, float* __restrict__ rsK) {
  const float* X;  const float* CS;  float* rs;
  if (blockIdx.y == 0) { X = q; CS = CSq; rs = rsQ; }
  else                 { X = k; CS = CSk; rs = rsK; }
  const int t = threadIdx.x;
  const int h = t & 15, rl = t >> 4;        // 16 heads x 16 rows per block
  const int row = blockIdx.x * 16 + rl;
  const float4* xp = (const float4*)(X + (size_t)row * DMODEL);
  const float4* cp = (const float4*)(CS + (size_t)h * DMODEL);
  double a0 = 0.0, a1 = 0.0, a2 = 0.0, a3 = 0.0;
#pragma unroll 4
  for (int i = 0; i < DMODEL / 4; i++) {
    float4 xv = xp[i], cv = cp[i];
    a0 += (double)xv.x * (double)cv.x;
    a1 += (double)xv.y * (double)cv.y;
    a2 += (double)xv.z * (double)cv.z;
    a3 += (double)xv.w * (double)cv.w;
  }
  rs[(size_t)row * NHEAD + h] = (float)((a0 + a1) + (a2 + a3));
}

// ---------------- fp16(-split) MFMA GEMM: C[M,N] = A[M,K] @ BT[N,K]^T ----
__device__ inline void glds16(const void* g, void* l) {
  __builtin_amdgcn_global_load_lds(
      (const __attribute__((address_space(1))) unsigned int*)g,
      (__attribute__((address_space(3))) unsigned int*)l, 16, 0, 0);
}

template <int NPASS, int OUT_HALF>
__global__ __launch_bounds__(256) void gemm_f16(
    const _Float16* __restrict__ Ahi, const _Float16* __restrict__ Alo,
    const _Float16* __restrict__ Bhi, const _Float16* __restrict__ Blo,
    float* __restrict__ Cf, _Float16* __restrict__ Ch,
    int M, int N, int Kd) {
  constexpr int TILE = 128 * 32;                   // elems per LDS tile
  __shared__ _Float16 lds[(NPASS == 3 ? 4 : 2) * TILE];
  _Float16* sAh = lds;
  _Float16* sBh = lds + (NPASS == 3 ? 2 : 1) * TILE;
  _Float16* sAl = lds + TILE;                      // used only if NPASS==3
  _Float16* sBl = lds + 3 * TILE;                  // used only if NPASS==3

  const int t = threadIdx.x;
  const int lane = t & 63, wid = t >> 6;
  const int wm = wid >> 1, wn = wid & 1;           // 2x2 waves, 64x64 each
  const int lr = lane & 15, lk = (lane >> 4) * 8;

  // XCD-chunked bijective swizzle (nwg % 8 == 0) + ny-fast supertile order
  const int mtiles = M >> 7, ntiles = N >> 7;
  const int nwg = mtiles * ntiles;
  const int qq = nwg >> 3;
  const int v = (blockIdx.x & 7) * qq + (blockIdx.x >> 3);
  const int mx = v / ntiles, ny = v % ntiles;
  const int m0 = mx * 128, n0 = ny * 128;

  f32x4 acc[4][4] = {};

  for (int k0 = 0; k0 < Kd; k0 += 32) {
#pragma unroll
    for (int i = 0; i < 2; i++) {
      int slot = t + i * 256;
      int row = slot >> 2, kc = (slot & 3) * 8;
      glds16(Ahi + (size_t)(m0 + row) * Kd + k0 + kc, sAh + slot * 8);
      glds16(Bhi + (size_t)(n0 + row) * Kd + k0 + kc, sBh + slot * 8);
      if (NPASS == 3) {
        glds16(Alo + (size_t)(m0 + row) * Kd + k0 + kc, sAl + slot * 8);
        glds16(Blo + (size_t)(n0 + row) * Kd + k0 + kc, sBl + slot * 8);
      }
    }
    __syncthreads();

    f16x8 ah[4], bh[4], al[4], bl[4];
#pragma unroll
    for (int f = 0; f < 4; f++) {
      ah[f] = *(const f16x8*)&sAh[(wm * 64 + f * 16 + lr) * 32 + lk];
      bh[f] = *(const f16x8*)&sBh[(wn * 64 + f * 16 + lr) * 32 + lk];
      if (NPASS == 3) {
        al[f] = *(const f16x8*)&sAl[(wm * 64 + f * 16 + lr) * 32 + lk];
        bl[f] = *(const f16x8*)&sBl[(wn * 64 + f * 16 + lr) * 32 + lk];
      }
    }
#pragma unroll
    for (int i = 0; i < 4; i++)
#pragma unroll
      for (int j = 0; j < 4; j++) {
        acc[i][j] = __builtin_amdgcn_mfma_f32_16x16x32_f16(ah[i], bh[j], acc[i][j], 0, 0, 0);
        if (NPASS == 3) {
          acc[i][j] = __builtin_amdgcn_mfma_f32_16x16x32_f16(ah[i], bl[j], acc[i][j], 0, 0, 0);
          acc[i][j] = __builtin_amdgcn_mfma_f32_16x16x32_f16(al[i], bh[j], acc[i][j], 0, 0, 0);
        }
      }
    __syncthreads();
  }

#pragma unroll
  for (int i = 0; i < 4; i++) {
    int row = m0 + wm * 64 + i * 16 + (lane >> 4) * 4;
#pragma unroll
    for (int j = 0; j < 4; j++) {
      int col = n0 + wn * 64 + j * 16 + (lane & 15);
#pragma unroll
      for (int r = 0; r < 4; r++) {
        if (OUT_HALF)
          Ch[(size_t)(row + r) * N + col] = (_Float16)acc[i][j][r];
        else
          Cf[(size_t)(row + r) * N + col] = acc[i][j][r];
      }
    }
  }
}

// -------- per-position head attention: 1 block (256 thr) per (b,s) -------
__global__ __launch_bounds__(256) void attn_kernel(
    const float* __restrict__ Q, const float* __restrict__ K,
    const _Float16* __restrict__ V, const float* __restrict__ mask,
    const float* __restrict__ rsQ, const float* __restrict__ rsK,
    float* __restrict__ wout, _Float16* __restrict__ aout) {
  __shared__ float lq[16][132], lkk[16][132], lv[16][132];
  __shared__ float lw[16][17];
  const int pos = blockIdx.x;
  const int t = threadIdx.x;
  const int h = t >> 4, j = t & 15;
  const size_t rowbase = (size_t)pos * DMODEL + h * DHEAD;

  const float iq = 1.f / (rsQ[(size_t)pos * NHEAD + h] + 1e-6f);
  const float ik = 1.f / (rsK[(size_t)pos * NHEAD + h] + 1e-6f);

  {
    const int dlo = 4 * j, dhi = 64 + 4 * j;
    float4 q0 = *(const float4*)&Q[rowbase + dlo];
    float4 q1 = *(const float4*)&Q[rowbase + dhi];
    q0.x *= iq; q0.y *= iq; q0.z *= iq; q0.w *= iq;
    q1.x *= iq; q1.y *= iq; q1.z *= iq; q1.w *= iq;
    *(float4*)&lq[h][dlo] = q0;
    *(float4*)&lq[h][dhi] = q1;
    float4 k0 = *(const float4*)&K[rowbase + dlo];
    float4 k1 = *(const float4*)&K[rowbase + dhi];
    k0.x *= ik; k0.y *= ik; k0.z *= ik; k0.w *= ik;
    k1.x *= ik; k1.y *= ik; k1.z *= ik; k1.w *= ik;
    *(float4*)&lkk[h][dlo] = k0;
    *(float4*)&lkk[h][dhi] = k1;
    f16x4 v0 = *(const f16x4*)&V[rowbase + dlo];
    f16x4 v1 = *(const f16x4*)&V[rowbase + dhi];
    float4 vf0 = {(float)v0[0], (float)v0[1], (float)v0[2], (float)v0[3]};
    float4 vf1 = {(float)v1[0], (float)v1[1], (float)v1[2], (float)v1[3]};
    *(float4*)&lv[h][dlo] = vf0;
    *(float4*)&lv[h][dhi] = vf1;
  }
  __syncthreads();

  const float4* qr = (const float4*)&lq[h][0];
  const float4* kr = (const float4*)&lkk[j][0];
  float dot = 0.f;
#pragma unroll
  for (int d4 = 0; d4 < 32; d4++) {
    float4 a = qr[d4], b = kr[d4];
    dot = fmaf(a.x, b.x, dot); dot = fmaf(a.y, b.y, dot);
    dot = fmaf(a.z, b.z, dot); dot = fmaf(a.w, b.w, dot);
  }
  float mk = mask[(size_t)pos * 256 + t];
  float x = (dot - 1e9f * mk) * 0.08838834764831845f;  // 1/sqrt(128)
  float mx = x;
#pragma unroll
  for (int m = 1; m < 16; m <<= 1) mx = fmaxf(mx, __shfl_xor(mx, m, 64));
  float e = expf(x - mx);
  float den = e;
#pragma unroll
  for (int m = 1; m < 16; m <<= 1) den += __shfl_xor(den, m, 64);
  float w = e / den;
  wout[(size_t)pos * 256 + t] = w;
  lw[h][j] = w;
  __syncthreads();

  float wreg[16];
#pragma unroll
  for (int k2 = 0; k2 < 16; k2++) wreg[k2] = lw[h][k2];
  float4 a0 = {0.f, 0.f, 0.f, 0.f}, a1 = {0.f, 0.f, 0.f, 0.f};
  const int dlo = 4 * j, dhi = 64 + 4 * j;
#pragma unroll
  for (int k2 = 0; k2 < 16; k2++) {
    float4 v0 = *(const float4*)&lv[k2][dlo];
    float4 v1 = *(const float4*)&lv[k2][dhi];
    float wk = wreg[k2];
    a0.x = fmaf(wk, v0.x, a0.x); a0.y = fmaf(wk, v0.y, a0.y);
    a0.z = fmaf(wk, v0.z, a0.z); a0.w = fmaf(wk, v0.w, a0.w);
    a1.x = fmaf(wk, v1.x, a1.x); a1.y = fmaf(wk, v1.y, a1.y);
    a1.z = fmaf(wk, v1.z, a1.z); a1.w = fmaf(wk, v1.w, a1.w);
  }
  f16x4 o0, o1;
  o0[0] = (_Float16)a0.x; o0[1] = (_Float16)a0.y;
  o0[2] = (_Float16)a0.z; o0[3] = (_Float16)a0.w;
  o1[0] = (_Float16)a1.x; o1[1] = (_Float16)a1.y;
  o1[2] = (_Float16)a1.z; o1[3] = (_Float16)a1.w;
  *(f16x4*)&aout[rowbase + dlo] = o0;
  *(f16x4*)&aout[rowbase + dhi] = o1;
}

// -------------------------------------------------------------------------
extern "C" void kernel_launch(void* const* d_in, const int* in_sizes, int n_in,
                              void* d_out, int out_size, void* d_ws, size_t ws_size,
                              hipStream_t stream) {
  const float* query = (const float*)d_in[0];
  const float* key   = (const float*)d_in[1];
  const float* value = (const float*)d_in[2];
  const float* mask  = (const float*)d_in[3];
  const float* Wq = (const float*)d_in[4];
  const float* Wk = (const float*)d_in[5];
  const float* Wv = (const float*)d_in[6];
  const float* Wo = (const float*)d_in[7];

  float* out  = (float*)d_out;                       // [16384, 2048] fp32
  float* wout = out + (size_t)MROWS * DMODEL;        // [16384, 256] fp32

  const size_t SZ_HALF = (size_t)MROWS * DMODEL * 2; // 67.1 MB
  const size_t SZ_F32  = (size_t)MROWS * DMODEL * 4; // 134.2 MB
  const size_t SZ_W    = (size_t)DMODEL * DMODEL * 2;// 8.4 MB
  const size_t SZ_CS   = (size_t)DMODEL * NHEAD * 4; // 128 KB (fp32)
  const size_t SZ_RS   = (size_t)MROWS * NHEAD * 4;  // 1 MB

  const int n8 = MROWS * DMODEL / 8;
  const int ggrid = (MROWS / 128) * (DMODEL / 128);  // 2048 blocks, 1D
  dim3 tgrid4(DMODEL / 32, DMODEL / 32, 4);
  dim3 tgrid(DMODEL / 32, DMODEL / 32);
  dim3 tblk(32, 8);
  float* Qbuf = out;   // Q fp32 parked in d_out, overwritten by final GEMM

  // Dedicated-buffer fused layout (10 dispatches) when workspace allows.
  const size_t NEED_A = 5 * SZ_HALF + SZ_F32 + 6 * SZ_W + 2 * SZ_CS + 2 * SZ_RS;
  const size_t NEED_B = 3 * SZ_HALF + SZ_F32 + 2 * SZ_W + 2 * SZ_CS + 2 * SZ_RS;
  char* ws = (char*)d_ws;

  if (ws_size >= NEED_A) {
    size_t off = 0;
    _Float16* qh = (_Float16*)(ws + off); off += SZ_HALF;
    _Float16* ql = (_Float16*)(ws + off); off += SZ_HALF;
    _Float16* kh = (_Float16*)(ws + off); off += SZ_HALF;
    _Float16* kl = (_Float16*)(ws + off); off += SZ_HALF;
    _Float16* vh = (_Float16*)(ws + off); off += SZ_HALF;
    float*  Kbuf = (float*)   (ws + off); off += SZ_F32;
    _Float16* wqh = (_Float16*)(ws + off); off += SZ_W;
    _Float16* wql = (_Float16*)(ws + off); off += SZ_W;
    _Float16* wkh = (_Float16*)(ws + off); off += SZ_W;
    _Float16* wkl = (_Float16*)(ws + off); off += SZ_W;
    _Float16* wvh = (_Float16*)(ws + off); off += SZ_W;
    _Float16* woh = (_Float16*)(ws + off); off += SZ_W;
    float* CSq = (float*)(ws + off); off += SZ_CS;
    float* CSk = (float*)(ws + off); off += SZ_CS;
    float* rsQ = (float*)(ws + off); off += SZ_RS;
    float* rsK = (float*)(ws + off); off += SZ_RS;
    _Float16* Vbuf   = qh;   // qh dead after g3Q
    _Float16* attn16 = ql;   // ql dead after g3Q

    colsum_f64<<<DMODEL, 256, 0, stream>>>(Wq, CSq);
    colsum_f64<<<DMODEL, 256, 0, stream>>>(Wk, CSk);
    rowsum_qk<<<dim3(MROWS / 16, 2), 256, 0, stream>>>(query, key, CSq, CSk, rsQ, rsK);
    transpose_all<<<tgrid4, tblk, 0, stream>>>(Wq, Wk, Wv, Wo, wqh, wql, wkh, wkl, wvh, woh);
    split_all<<<dim3(4096, 3), 256, 0, stream>>>(query, key, value, qh, ql, kh, kl, vh, n8);
    gemm_f16<3, 0><<<ggrid, 256, 0, stream>>>(qh, ql, wqh, wql, Qbuf, nullptr, MROWS, DMODEL, DMODEL);
    gemm_f16<3, 0><<<ggrid, 256, 0, stream>>>(kh, kl, wkh, wkl, Kbuf, nullptr, MROWS, DMODEL, DMODEL);
    gemm_f16<1, 1><<<ggrid, 256, 0, stream>>>(vh, nullptr, wvh, nullptr, nullptr, Vbuf, MROWS, DMODEL, DMODEL);
    attn_kernel<<<MROWS, 256, 0, stream>>>(Qbuf, Kbuf, Vbuf, mask, rsQ, rsK, wout, attn16);
    gemm_f16<1, 0><<<ggrid, 256, 0, stream>>>(attn16, nullptr, woh, nullptr, out, nullptr, MROWS, DMODEL, DMODEL);
    return;
  }

  if (ws_size < NEED_B) return;  // workspace too small — fail visibly

  // Fallback: sequential-reuse layout (proven R4 structure)
  _Float16* a_hi  = (_Float16*)ws;
  _Float16* a_lo  = (_Float16*)(ws + SZ_HALF);
  float*    Kbuf  = (float*)   (ws + 2 * SZ_HALF);
  _Float16* Vbuf  = (_Float16*)(ws + 2 * SZ_HALF + SZ_F32);
  _Float16* wT_hi = (_Float16*)(ws + 3 * SZ_HALF + SZ_F32);
  _Float16* wT_lo = (_Float16*)(ws + 3 * SZ_HALF + SZ_F32 + SZ_W);
  float*    CSq   = (float*)   (ws + 3 * SZ_HALF + SZ_F32 + 2 * SZ_W);
  float*    CSk   = (float*)   (ws + 3 * SZ_HALF + SZ_F32 + 2 * SZ_W + SZ_CS);
  float*    rsQ   = (float*)   (ws + 3 * SZ_HALF + SZ_F32 + 2 * SZ_W + 2 * SZ_CS);
  float*    rsK   = (float*)   (ws + 3 * SZ_HALF + SZ_F32 + 2 * SZ_W + 2 * SZ_CS + SZ_RS);
  _Float16* attn16 = a_hi;       // reused after V-GEMM consumed a_hi

  colsum_f64<<<DMODEL, 256, 0, stream>>>(Wq, CSq);
  colsum_f64<<<DMODEL, 256, 0, stream>>>(Wk, CSk);
  rowsum_qk<<<dim3(MROWS / 16, 2), 256, 0, stream>>>(query, key, CSq, CSk, rsQ, rsK);

  split_f32_f16<<<4096, 256, 0, stream>>>(query, a_hi, a_lo, n8);
  transpose_split<<<tgrid, tblk, 0, stream>>>(Wq, wT_hi, wT_lo);
  gemm_f16<3, 0><<<ggrid, 256, 0, stream>>>(a_hi, a_lo, wT_hi, wT_lo, Qbuf, nullptr, MROWS, DMODEL, DMODEL);
  split_f32_f16<<<4096, 256, 0, stream>>>(key, a_hi, a_lo, n8);
  transpose_split<<<tgrid, tblk, 0, stream>>>(Wk, wT_hi, wT_lo);
  gemm_f16<3, 0><<<ggrid, 256, 0, stream>>>(a_hi, a_lo, wT_hi, wT_lo, Kbuf, nullptr, MROWS, DMODEL, DMODEL);
  split_f32_f16<<<4096, 256, 0, stream>>>(value, a_hi, nullptr, n8);
  transpose_split<<<tgrid, tblk, 0, stream>>>(Wv, wT_hi, nullptr);
  gemm_f16<1, 1><<<ggrid, 256, 0, stream>>>(a_hi, nullptr, wT_hi, nullptr, nullptr, Vbuf, MROWS, DMODEL, DMODEL);
  attn_kernel<<<MROWS, 256, 0, stream>>>(Qbuf, Kbuf, Vbuf, mask, rsQ, rsK, wout, attn16);
  transpose_split<<<tgrid, tblk, 0, stream>>>(Wo, wT_hi, nullptr);
  gemm_f16<1, 0><<<ggrid, 256, 0, stream>>>(attn16, nullptr, wT_hi, nullptr, out, nullptr, MROWS, DMODEL, DMODEL);
}

// Round 6
// 1988.966 us; speedup vs baseline: 1.1172x; 1.0416x over previous
//
#include <hip/hip_runtime.h>
#include <hip/hip_fp16.h>

#define NHEAD 16
#define DHEAD 128
#define DMODEL 2048
#define SEQ 4096
#define BATCH 4
#define MROWS (BATCH*SEQ)   // 16384

typedef _Float16 f16x8 __attribute__((ext_vector_type(8)));
typedef _Float16 f16x4 __attribute__((ext_vector_type(4)));
typedef float f32x4 __attribute__((ext_vector_type(4)));

// ---------------- fp32 -> fp16 (hi, lo) split, 8 elems/thread ------------
__device__ inline void split8(const float* __restrict__ x, _Float16* __restrict__ hi,
                              _Float16* __restrict__ lo, int i8) {
  float4 v0 = ((const float4*)x)[2 * i8];
  float4 v1 = ((const float4*)x)[2 * i8 + 1];
  f16x8 h, l;
  h[0] = (_Float16)v0.x; h[1] = (_Float16)v0.y;
  h[2] = (_Float16)v0.z; h[3] = (_Float16)v0.w;
  h[4] = (_Float16)v1.x; h[5] = (_Float16)v1.y;
  h[6] = (_Float16)v1.z; h[7] = (_Float16)v1.w;
  ((f16x8*)hi)[i8] = h;
  if (lo) {
    l[0] = (_Float16)(v0.x - (float)h[0]);
    l[1] = (_Float16)(v0.y - (float)h[1]);
    l[2] = (_Float16)(v0.z - (float)h[2]);
    l[3] = (_Float16)(v0.w - (float)h[3]);
    l[4] = (_Float16)(v1.x - (float)h[4]);
    l[5] = (_Float16)(v1.y - (float)h[5]);
    l[6] = (_Float16)(v1.z - (float)h[6]);
    l[7] = (_Float16)(v1.w - (float)h[7]);
    ((f16x8*)lo)[i8] = l;
  }
}

// one matrix per launch (fallback path)
__global__ __launch_bounds__(256) void split_f32_f16(
    const float* __restrict__ x, _Float16* __restrict__ hi,
    _Float16* __restrict__ lo, int n8) {
  int i = blockIdx.x * blockDim.x + threadIdx.x;
  int stride = gridDim.x * blockDim.x;
  for (; i < n8; i += stride) split8(x, hi, lo, i);
}

// all three matrices in one launch (blockIdx.y selects)
__global__ __launch_bounds__(256) void split_all(
    const float* __restrict__ q, const float* __restrict__ k,
    const float* __restrict__ v,
    _Float16* __restrict__ qh, _Float16* __restrict__ ql,
    _Float16* __restrict__ kh, _Float16* __restrict__ kl,
    _Float16* __restrict__ vh, int n8) {
  const float* x; _Float16* hi; _Float16* lo;
  if (blockIdx.y == 0)      { x = q; hi = qh; lo = ql; }
  else if (blockIdx.y == 1) { x = k; hi = kh; lo = kl; }
  else                      { x = v; hi = vh; lo = nullptr; }
  int i = blockIdx.x * blockDim.x + threadIdx.x;
  int stride = gridDim.x * blockDim.x;
  for (; i < n8; i += stride) split8(x, hi, lo, i);
}

// ------------- weight transpose + split: W[K][N] -> WT[N][K] f16 ---------
__device__ inline void transpose_body(const float* __restrict__ W,
                                      _Float16* __restrict__ hi,
                                      _Float16* __restrict__ lo,
                                      int bx, int by, int tx, int ty) {
  __shared__ float tile[32][33];
  int c = bx * 32 + tx;
  for (int r0 = 0; r0 < 32; r0 += 8) {
    int r = by * 32 + ty + r0;
    tile[ty + r0][tx] = W[(size_t)r * DMODEL + c];
  }
  __syncthreads();
  for (int r0 = 0; r0 < 32; r0 += 8) {
    int n = bx * 32 + ty + r0;             // WT row = original col
    int k = by * 32 + tx;                  // WT col = original row
    float v = tile[tx][ty + r0];           // = W[k][n]
    _Float16 h = (_Float16)v;
    hi[(size_t)n * DMODEL + k] = h;
    if (lo) lo[(size_t)n * DMODEL + k] = (_Float16)(v - (float)h);
  }
}

__global__ __launch_bounds__(256) void transpose_split(
    const float* __restrict__ W, _Float16* __restrict__ hi,
    _Float16* __restrict__ lo) {
  transpose_body(W, hi, lo, blockIdx.x, blockIdx.y, threadIdx.x, threadIdx.y);
}

// all four weights in one launch (blockIdx.z selects)
__global__ __launch_bounds__(256) void transpose_all(
    const float* __restrict__ Wq, const float* __restrict__ Wk,
    const float* __restrict__ Wv, const float* __restrict__ Wo,
    _Float16* __restrict__ qh, _Float16* __restrict__ ql,
    _Float16* __restrict__ kh, _Float16* __restrict__ kl,
    _Float16* __restrict__ vh, _Float16* __restrict__ oh) {
  const float* W; _Float16* hi; _Float16* lo;
  switch (blockIdx.z) {
    case 0:  W = Wq; hi = qh; lo = ql;      break;
    case 1:  W = Wk; hi = kh; lo = kl;      break;
    case 2:  W = Wv; hi = vh; lo = nullptr; break;
    default: W = Wo; hi = oh; lo = nullptr; break;
  }
  transpose_body(W, hi, lo, blockIdx.x, blockIdx.y, threadIdx.x, threadIdx.y);
}

// ---- per-head column sums of W, stored TRANSPOSED: CS_T[h][k] -----------
__global__ __launch_bounds__(256) void colsum_f64(
    const float* __restrict__ W, float* __restrict__ CS) {
  const int k = blockIdx.x;                 // row of W
  const int t = threadIdx.x;
  const int h = t >> 4, s = t & 15;
  double acc = 0.0;
  const float* p = W + (size_t)k * DMODEL + h * DHEAD + s * 8;
#pragma unroll
  for (int i = 0; i < 8; i++) acc += (double)p[i];
#pragma unroll
  for (int m = 1; m < 16; m <<= 1) acc += __shfl_xor(acc, m, 64);
  if (s == 0) CS[(size_t)h * DMODEL + k] = (float)acc;
}

// ---- exact per-head row sums, LDS-staged & coalesced --------------------
// rs[row][h] = sum_k X[row][k] * CS_T[h][k]; fp64 accumulate.
// Block: 256 thr, 4 rows. Stage 4x2048 f32 in LDS (coalesced float4),
// then thread (h=t&15, qt=(t>>4)&3, r=t>>6) does a 512-elem f64 dot.
__global__ __launch_bounds__(256) void rowsum_v2(
    const float* __restrict__ q, const float* __restrict__ k,
    const float* __restrict__ CSq, const float* __restrict__ CSk,
    float* __restrict__ rsQ, float* __restrict__ rsK) {
  const float* X;  const float* CS;  float* rs;
  if (blockIdx.y == 0) { X = q; CS = CSq; rs = rsQ; }
  else                 { X = k; CS = CSk; rs = rsK; }
  __shared__ float lx[4][2052];             // +4 pad: 2-way bank alias only
  const int t = threadIdx.x;
  const int row0 = blockIdx.x * 4;

  // stage: 8 iters x 256 thr x float4 = 4 rows x 2048 floats
#pragma unroll
  for (int it = 0; it < 8; it++) {
    int idx = it * 1024 + t * 4;            // 0..8191
    int r = idx >> 11, c = idx & 2047;
    *(float4*)&lx[r][c] = *(const float4*)&X[((size_t)(row0 + r) << 11) + c];
  }
  __syncthreads();

  const int h = t & 15, qt = (t >> 4) & 3, r = t >> 6;
  const float4* xr4 = (const float4*)&lx[r][qt * 512];
  const float4* cs4 = (const float4*)(CS + (size_t)h * DMODEL + qt * 512);
  double a0 = 0.0, a1 = 0.0;
#pragma unroll 4
  for (int i = 0; i < 128; i++) {
    float4 xv = xr4[i], cv = cs4[i];
    a0 += (double)xv.x * (double)cv.x + (double)xv.y * (double)cv.y;
    a1 += (double)xv.z * (double)cv.z + (double)xv.w * (double)cv.w;
  }
  double acc = a0 + a1;
  acc += __shfl_xor(acc, 16, 64);           // combine quarters 0<->1, 2<->3
  acc += __shfl_xor(acc, 32, 64);           // combine quarter pairs
  if (((t >> 4) & 3) == 0)                  // one lane-group per (r,h)
    rs[(size_t)(row0 + r) * NHEAD + h] = (float)acc;
}

// ---------------- fp16(-split) MFMA GEMM: C[M,N] = A[M,K] @ BT[N,K]^T ----
__device__ inline void glds16(const void* g, void* l) {
  __builtin_amdgcn_global_load_lds(
      (const __attribute__((address_space(1))) unsigned int*)g,
      (__attribute__((address_space(3))) unsigned int*)l, 16, 0, 0);
}

template <int NPASS, int OUT_HALF>
__global__ __launch_bounds__(256) void gemm_f16(
    const _Float16* __restrict__ Ahi, const _Float16* __restrict__ Alo,
    const _Float16* __restrict__ Bhi, const _Float16* __restrict__ Blo,
    float* __restrict__ Cf, _Float16* __restrict__ Ch,
    int M, int N, int Kd) {
  constexpr int TILE = 128 * 32;                   // elems per LDS tile
  __shared__ _Float16 lds[(NPASS == 3 ? 4 : 2) * TILE];
  _Float16* sAh = lds;
  _Float16* sBh = lds + (NPASS == 3 ? 2 : 1) * TILE;
  _Float16* sAl = lds + TILE;                      // used only if NPASS==3
  _Float16* sBl = lds + 3 * TILE;                  // used only if NPASS==3

  const int t = threadIdx.x;
  const int lane = t & 63, wid = t >> 6;
  const int wm = wid >> 1, wn = wid & 1;           // 2x2 waves, 64x64 each
  const int lr = lane & 15, lk = (lane >> 4) * 8;

  // XCD-chunked bijective swizzle (nwg % 8 == 0) + ny-fast supertile order
  const int mtiles = M >> 7, ntiles = N >> 7;
  const int nwg = mtiles * ntiles;
  const int qq = nwg >> 3;
  const int v = (blockIdx.x & 7) * qq + (blockIdx.x >> 3);
  const int mx = v / ntiles, ny = v % ntiles;
  const int m0 = mx * 128, n0 = ny * 128;

  f32x4 acc[4][4] = {};

  for (int k0 = 0; k0 < Kd; k0 += 32) {
#pragma unroll
    for (int i = 0; i < 2; i++) {
      int slot = t + i * 256;
      int row = slot >> 2, kc = (slot & 3) * 8;
      glds16(Ahi + (size_t)(m0 + row) * Kd + k0 + kc, sAh + slot * 8);
      glds16(Bhi + (size_t)(n0 + row) * Kd + k0 + kc, sBh + slot * 8);
      if (NPASS == 3) {
        glds16(Alo + (size_t)(m0 + row) * Kd + k0 + kc, sAl + slot * 8);
        glds16(Blo + (size_t)(n0 + row) * Kd + k0 + kc, sBl + slot * 8);
      }
    }
    __syncthreads();

    f16x8 ah[4], bh[4], al[4], bl[4];
#pragma unroll
    for (int f = 0; f < 4; f++) {
      ah[f] = *(const f16x8*)&sAh[(wm * 64 + f * 16 + lr) * 32 + lk];
      bh[f] = *(const f16x8*)&sBh[(wn * 64 + f * 16 + lr) * 32 + lk];
      if (NPASS == 3) {
        al[f] = *(const f16x8*)&sAl[(wm * 64 + f * 16 + lr) * 32 + lk];
        bl[f] = *(const f16x8*)&sBl[(wn * 64 + f * 16 + lr) * 32 + lk];
      }
    }
#pragma unroll
    for (int i = 0; i < 4; i++)
#pragma unroll
      for (int j = 0; j < 4; j++) {
        acc[i][j] = __builtin_amdgcn_mfma_f32_16x16x32_f16(ah[i], bh[j], acc[i][j], 0, 0, 0);
        if (NPASS == 3) {
          acc[i][j] = __builtin_amdgcn_mfma_f32_16x16x32_f16(ah[i], bl[j], acc[i][j], 0, 0, 0);
          acc[i][j] = __builtin_amdgcn_mfma_f32_16x16x32_f16(al[i], bh[j], acc[i][j], 0, 0, 0);
        }
      }
    __syncthreads();
  }

#pragma unroll
  for (int i = 0; i < 4; i++) {
    int row = m0 + wm * 64 + i * 16 + (lane >> 4) * 4;
#pragma unroll
    for (int j = 0; j < 4; j++) {
      int col = n0 + wn * 64 + j * 16 + (lane & 15);
#pragma unroll
      for (int r = 0; r < 4; r++) {
        if (OUT_HALF)
          Ch[(size_t)(row + r) * N + col] = (_Float16)acc[i][j][r];
        else
          Cf[(size_t)(row + r) * N + col] = acc[i][j][r];
      }
    }
  }
}

// -------- per-position head attention: 1 block (256 thr) per (b,s) -------
__global__ __launch_bounds__(256) void attn_kernel(
    const float* __restrict__ Q, const float* __restrict__ K,
    const _Float16* __restrict__ V, const float* __restrict__ mask,
    const float* __restrict__ rsQ, const float* __restrict__ rsK,
    float* __restrict__ wout, _Float16* __restrict__ aout) {
  __shared__ float lq[16][132], lkk[16][132], lv[16][132];
  __shared__ float lw[16][17];
  const int pos = blockIdx.x;
  const int t = threadIdx.x;
  const int h = t >> 4, j = t & 15;
  const size_t rowbase = (size_t)pos * DMODEL + h * DHEAD;

  const float iq = 1.f / (rsQ[(size_t)pos * NHEAD + h] + 1e-6f);
  const float ik = 1.f / (rsK[(size_t)pos * NHEAD + h] + 1e-6f);

  {
    const int dlo = 4 * j, dhi = 64 + 4 * j;
    float4 q0 = *(const float4*)&Q[rowbase + dlo];
    float4 q1 = *(const float4*)&Q[rowbase + dhi];
    q0.x *= iq; q0.y *= iq; q0.z *= iq; q0.w *= iq;
    q1.x *= iq; q1.y *= iq; q1.z *= iq; q1.w *= iq;
    *(float4*)&lq[h][dlo] = q0;
    *(float4*)&lq[h][dhi] = q1;
    float4 k0 = *(const float4*)&K[rowbase + dlo];
    float4 k1 = *(const float4*)&K[rowbase + dhi];
    k0.x *= ik; k0.y *= ik; k0.z *= ik; k0.w *= ik;
    k1.x *= ik; k1.y *= ik; k1.z *= ik; k1.w *= ik;
    *(float4*)&lkk[h][dlo] = k0;
    *(float4*)&lkk[h][dhi] = k1;
    f16x4 v0 = *(const f16x4*)&V[rowbase + dlo];
    f16x4 v1 = *(const f16x4*)&V[rowbase + dhi];
    float4 vf0 = {(float)v0[0], (float)v0[1], (float)v0[2], (float)v0[3]};
    float4 vf1 = {(float)v1[0], (float)v1[1], (float)v1[2], (float)v1[3]};
    *(float4*)&lv[h][dlo] = vf0;
    *(float4*)&lv[h][dhi] = vf1;
  }
  __syncthreads();

  const float4* qr = (const float4*)&lq[h][0];
  const float4* kr = (const float4*)&lkk[j][0];
  float dot = 0.f;
#pragma unroll
  for (int d4 = 0; d4 < 32; d4++) {
    float4 a = qr[d4], b = kr[d4];
    dot = fmaf(a.x, b.x, dot); dot = fmaf(a.y, b.y, dot);
    dot = fmaf(a.z, b.z, dot); dot = fmaf(a.w, b.w, dot);
  }
  float mk = mask[(size_t)pos * 256 + t];
  float x = (dot - 1e9f * mk) * 0.08838834764831845f;  // 1/sqrt(128)
  float mx = x;
#pragma unroll
  for (int m = 1; m < 16; m <<= 1) mx = fmaxf(mx, __shfl_xor(mx, m, 64));
  float e = expf(x - mx);
  float den = e;
#pragma unroll
  for (int m = 1; m < 16; m <<= 1) den += __shfl_xor(den, m, 64);
  float w = e / den;
  wout[(size_t)pos * 256 + t] = w;
  lw[h][j] = w;
  __syncthreads();

  float wreg[16];
#pragma unroll
  for (int k2 = 0; k2 < 16; k2++) wreg[k2] = lw[h][k2];
  float4 a0 = {0.f, 0.f, 0.f, 0.f}, a1 = {0.f, 0.f, 0.f, 0.f};
  const int dlo = 4 * j, dhi = 64 + 4 * j;
#pragma unroll
  for (int k2 = 0; k2 < 16; k2++) {
    float4 v0 = *(const float4*)&lv[k2][dlo];
    float4 v1 = *(const float4*)&lv[k2][dhi];
    float wk = wreg[k2];
    a0.x = fmaf(wk, v0.x, a0.x); a0.y = fmaf(wk, v0.y, a0.y);
    a0.z = fmaf(wk, v0.z, a0.z); a0.w = fmaf(wk, v0.w, a0.w);
    a1.x = fmaf(wk, v1.x, a1.x); a1.y = fmaf(wk, v1.y, a1.y);
    a1.z = fmaf(wk, v1.z, a1.z); a1.w = fmaf(wk, v1.w, a1.w);
  }
  f16x4 o0, o1;
  o0[0] = (_Float16)a0.x; o0[1] = (_Float16)a0.y;
  o0[2] = (_Float16)a0.z; o0[3] = (_Float16)a0.w;
  o1[0] = (_Float16)a1.x; o1[1] = (_Float16)a1.y;
  o1[2] = (_Float16)a1.z; o1[3] = (_Float16)a1.w;
  *(f16x4*)&aout[rowbase + dlo] = o0;
  *(f16x4*)&aout[rowbase + dhi] = o1;
}

// -------------------------------------------------------------------------
extern "C" void kernel_launch(void* const* d_in, const int* in_sizes, int n_in,
                              void* d_out, int out_size, void* d_ws, size_t ws_size,
                              hipStream_t stream) {
  const float* query = (const float*)d_in[0];
  const float* key   = (const float*)d_in[1];
  const float* value = (const float*)d_in[2];
  const float* mask  = (const float*)d_in[3];
  const float* Wq = (const float*)d_in[4];
  const float* Wk = (const float*)d_in[5];
  const float* Wv = (const float*)d_in[6];
  const float* Wo = (const float*)d_in[7];

  float* out  = (float*)d_out;                       // [16384, 2048] fp32
  float* wout = out + (size_t)MROWS * DMODEL;        // [16384, 256] fp32

  const size_t SZ_HALF = (size_t)MROWS * DMODEL * 2; // 67.1 MB
  const size_t SZ_F32  = (size_t)MROWS * DMODEL * 4; // 134.2 MB
  const size_t SZ_W    = (size_t)DMODEL * DMODEL * 2;// 8.4 MB
  const size_t SZ_CS   = (size_t)DMODEL * NHEAD * 4; // 128 KB (fp32)
  const size_t SZ_RS   = (size_t)MROWS * NHEAD * 4;  // 1 MB

  const int n8 = MROWS * DMODEL / 8;
  const int ggrid = (MROWS / 128) * (DMODEL / 128);  // 2048 blocks, 1D
  dim3 tgrid4(DMODEL / 32, DMODEL / 32, 4);
  dim3 tgrid(DMODEL / 32, DMODEL / 32);
  dim3 tblk(32, 8);
  dim3 rsgrid(MROWS / 4, 2);
  float* Qbuf = out;   // Q fp32 parked in d_out, overwritten by final GEMM

  // Dedicated-buffer fused layout (10 dispatches) when workspace allows.
  const size_t NEED_A = 5 * SZ_HALF + SZ_F32 + 6 * SZ_W + 2 * SZ_CS + 2 * SZ_RS;
  const size_t NEED_B = 3 * SZ_HALF + SZ_F32 + 2 * SZ_W + 2 * SZ_CS + 2 * SZ_RS;
  char* ws = (char*)d_ws;

  if (ws_size >= NEED_A) {
    size_t off = 0;
    _Float16* qh = (_Float16*)(ws + off); off += SZ_HALF;
    _Float16* ql = (_Float16*)(ws + off); off += SZ_HALF;
    _Float16* kh = (_Float16*)(ws + off); off += SZ_HALF;
    _Float16* kl = (_Float16*)(ws + off); off += SZ_HALF;
    _Float16* vh = (_Float16*)(ws + off); off += SZ_HALF;
    float*  Kbuf = (float*)   (ws + off); off += SZ_F32;
    _Float16* wqh = (_Float16*)(ws + off); off += SZ_W;
    _Float16* wql = (_Float16*)(ws + off); off += SZ_W;
    _Float16* wkh = (_Float16*)(ws + off); off += SZ_W;
    _Float16* wkl = (_Float16*)(ws + off); off += SZ_W;
    _Float16* wvh = (_Float16*)(ws + off); off += SZ_W;
    _Float16* woh = (_Float16*)(ws + off); off += SZ_W;
    float* CSq = (float*)(ws + off); off += SZ_CS;
    float* CSk = (float*)(ws + off); off += SZ_CS;
    float* rsQ = (float*)(ws + off); off += SZ_RS;
    float* rsK = (float*)(ws + off); off += SZ_RS;
    _Float16* Vbuf   = qh;   // qh dead after g3Q
    _Float16* attn16 = ql;   // ql dead after g3Q

    colsum_f64<<<DMODEL, 256, 0, stream>>>(Wq, CSq);
    colsum_f64<<<DMODEL, 256, 0, stream>>>(Wk, CSk);
    rowsum_v2<<<rsgrid, 256, 0, stream>>>(query, key, CSq, CSk, rsQ, rsK);
    transpose_all<<<tgrid4, tblk, 0, stream>>>(Wq, Wk, Wv, Wo, wqh, wql, wkh, wkl, wvh, woh);
    split_all<<<dim3(4096, 3), 256, 0, stream>>>(query, key, value, qh, ql, kh, kl, vh, n8);
    gemm_f16<3, 0><<<ggrid, 256, 0, stream>>>(qh, ql, wqh, wql, Qbuf, nullptr, MROWS, DMODEL, DMODEL);
    gemm_f16<3, 0><<<ggrid, 256, 0, stream>>>(kh, kl, wkh, wkl, Kbuf, nullptr, MROWS, DMODEL, DMODEL);
    gemm_f16<1, 1><<<ggrid, 256, 0, stream>>>(vh, nullptr, wvh, nullptr, nullptr, Vbuf, MROWS, DMODEL, DMODEL);
    attn_kernel<<<MROWS, 256, 0, stream>>>(Qbuf, Kbuf, Vbuf, mask, rsQ, rsK, wout, attn16);
    gemm_f16<1, 0><<<ggrid, 256, 0, stream>>>(attn16, nullptr, woh, nullptr, out, nullptr, MROWS, DMODEL, DMODEL);
    return;
  }

  if (ws_size < NEED_B) return;  // workspace too small — fail visibly

  // Fallback: sequential-reuse layout
  _Float16* a_hi  = (_Float16*)ws;
  _Float16* a_lo  = (_Float16*)(ws + SZ_HALF);
  float*    Kbuf  = (float*)   (ws + 2 * SZ_HALF);
  _Float16* Vbuf  = (_Float16*)(ws + 2 * SZ_HALF + SZ_F32);
  _Float16* wT_hi = (_Float16*)(ws + 3 * SZ_HALF + SZ_F32);
  _Float16* wT_lo = (_Float16*)(ws + 3 * SZ_HALF + SZ_F32 + SZ_W);
  float*    CSq   = (float*)   (ws + 3 * SZ_HALF + SZ_F32 + 2 * SZ_W);
  float*    CSk   = (float*)   (ws + 3 * SZ_HALF + SZ_F32 + 2 * SZ_W + SZ_CS);
  float*    rsQ   = (float*)   (ws + 3 * SZ_HALF + SZ_F32 + 2 * SZ_W + 2 * SZ_CS);
  float*    rsK   = (float*)   (ws + 3 * SZ_HALF + SZ_F32 + 2 * SZ_W + 2 * SZ_CS + SZ_RS);
  _Float16* attn16 = a_hi;       // reused after V-GEMM consumed a_hi

  colsum_f64<<<DMODEL, 256, 0, stream>>>(Wq, CSq);
  colsum_f64<<<DMODEL, 256, 0, stream>>>(Wk, CSk);
  rowsum_v2<<<rsgrid, 256, 0, stream>>>(query, key, CSq, CSk, rsQ, rsK);

  split_f32_f16<<<4096, 256, 0, stream>>>(query, a_hi, a_lo, n8);
  transpose_split<<<tgrid, tblk, 0, stream>>>(Wq, wT_hi, wT_lo);
  gemm_f16<3, 0><<<ggrid, 256, 0, stream>>>(a_hi, a_lo, wT_hi, wT_lo, Qbuf, nullptr, MROWS, DMODEL, DMODEL);
  split_f32_f16<<<4096, 256, 0, stream>>>(key, a_hi, a_lo, n8);
  transpose_split<<<tgrid, tblk, 0, stream>>>(Wk, wT_hi, wT_lo);
  gemm_f16<3, 0><<<ggrid, 256, 0, stream>>>(a_hi, a_lo, wT_hi, wT_lo, Kbuf, nullptr, MROWS, DMODEL, DMODEL);
  split_f32_f16<<<4096, 256, 0, stream>>>(value, a_hi, nullptr, n8);
  transpose_split<<<tgrid, tblk, 0, stream>>>(Wv, wT_hi, nullptr);
  gemm_f16<1, 1><<<ggrid, 256, 0, stream>>>(a_hi, nullptr, wT_hi, nullptr, nullptr, Vbuf, MROWS, DMODEL, DMODEL);
  attn_kernel<<<MROWS, 256, 0, stream>>>(Qbuf, Kbuf, Vbuf, mask, rsQ, rsK, wout, attn16);
  transpose_split<<<tgrid, tblk, 0, stream>>>(Wo, wT_hi, nullptr);
  gemm_f16<1, 0><<<ggrid, 256, 0, stream>>>(attn16, nullptr, wT_hi, nullptr, out, nullptr, MROWS, DMODEL, DMODEL);
}

// Round 7
// 1790.560 us; speedup vs baseline: 1.2410x; 1.1108x over previous
//
#include <hip/hip_runtime.h>
#include <hip/hip_fp16.h>

#define NHEAD 16
#define DHEAD 128
#define DMODEL 2048
#define SEQ 4096
#define BATCH 4
#define MROWS (BATCH*SEQ)   // 16384

typedef _Float16 f16x8 __attribute__((ext_vector_type(8)));
typedef _Float16 f16x4 __attribute__((ext_vector_type(4)));
typedef float f32x4 __attribute__((ext_vector_type(4)));

// ---------------- fp32 -> fp16 (hi, lo) split, 8 elems/thread ------------
__device__ inline void split8(const float* __restrict__ x, _Float16* __restrict__ hi,
                              _Float16* __restrict__ lo, int i8) {
  float4 v0 = ((const float4*)x)[2 * i8];
  float4 v1 = ((const float4*)x)[2 * i8 + 1];
  f16x8 h, l;
  h[0] = (_Float16)v0.x; h[1] = (_Float16)v0.y;
  h[2] = (_Float16)v0.z; h[3] = (_Float16)v0.w;
  h[4] = (_Float16)v1.x; h[5] = (_Float16)v1.y;
  h[6] = (_Float16)v1.z; h[7] = (_Float16)v1.w;
  ((f16x8*)hi)[i8] = h;
  if (lo) {
    l[0] = (_Float16)(v0.x - (float)h[0]);
    l[1] = (_Float16)(v0.y - (float)h[1]);
    l[2] = (_Float16)(v0.z - (float)h[2]);
    l[3] = (_Float16)(v0.w - (float)h[3]);
    l[4] = (_Float16)(v1.x - (float)h[4]);
    l[5] = (_Float16)(v1.y - (float)h[5]);
    l[6] = (_Float16)(v1.z - (float)h[6]);
    l[7] = (_Float16)(v1.w - (float)h[7]);
    ((f16x8*)lo)[i8] = l;
  }
}

// one matrix per launch (fallback path)
__global__ __launch_bounds__(256) void split_f32_f16(
    const float* __restrict__ x, _Float16* __restrict__ hi,
    _Float16* __restrict__ lo, int n8) {
  int i = blockIdx.x * blockDim.x + threadIdx.x;
  int stride = gridDim.x * blockDim.x;
  for (; i < n8; i += stride) split8(x, hi, lo, i);
}

// all three matrices in one launch (blockIdx.y selects)
__global__ __launch_bounds__(256) void split_all(
    const float* __restrict__ q, const float* __restrict__ k,
    const float* __restrict__ v,
    _Float16* __restrict__ qh, _Float16* __restrict__ ql,
    _Float16* __restrict__ kh, _Float16* __restrict__ kl,
    _Float16* __restrict__ vh, int n8) {
  const float* x; _Float16* hi; _Float16* lo;
  if (blockIdx.y == 0)      { x = q; hi = qh; lo = ql; }
  else if (blockIdx.y == 1) { x = k; hi = kh; lo = kl; }
  else                      { x = v; hi = vh; lo = nullptr; }
  int i = blockIdx.x * blockDim.x + threadIdx.x;
  int stride = gridDim.x * blockDim.x;
  for (; i < n8; i += stride) split8(x, hi, lo, i);
}

// ------------- weight transpose + split: W[K][N] -> WT[N][K] f16 ---------
__device__ inline void transpose_body(const float* __restrict__ W,
                                      _Float16* __restrict__ hi,
                                      _Float16* __restrict__ lo,
                                      int bx, int by, int tx, int ty) {
  __shared__ float tile[32][33];
  int c = bx * 32 + tx;
  for (int r0 = 0; r0 < 32; r0 += 8) {
    int r = by * 32 + ty + r0;
    tile[ty + r0][tx] = W[(size_t)r * DMODEL + c];
  }
  __syncthreads();
  for (int r0 = 0; r0 < 32; r0 += 8) {
    int n = bx * 32 + ty + r0;             // WT row = original col
    int k = by * 32 + tx;                  // WT col = original row
    float v = tile[tx][ty + r0];           // = W[k][n]
    _Float16 h = (_Float16)v;
    hi[(size_t)n * DMODEL + k] = h;
    if (lo) lo[(size_t)n * DMODEL + k] = (_Float16)(v - (float)h);
  }
}

__global__ __launch_bounds__(256) void transpose_split(
    const float* __restrict__ W, _Float16* __restrict__ hi,
    _Float16* __restrict__ lo) {
  transpose_body(W, hi, lo, blockIdx.x, blockIdx.y, threadIdx.x, threadIdx.y);
}

// all four weights in one launch (blockIdx.z selects)
__global__ __launch_bounds__(256) void transpose_all(
    const float* __restrict__ Wq, const float* __restrict__ Wk,
    const float* __restrict__ Wv, const float* __restrict__ Wo,
    _Float16* __restrict__ qh, _Float16* __restrict__ ql,
    _Float16* __restrict__ kh, _Float16* __restrict__ kl,
    _Float16* __restrict__ vh, _Float16* __restrict__ oh) {
  const float* W; _Float16* hi; _Float16* lo;
  switch (blockIdx.z) {
    case 0:  W = Wq; hi = qh; lo = ql;      break;
    case 1:  W = Wk; hi = kh; lo = kl;      break;
    case 2:  W = Wv; hi = vh; lo = nullptr; break;
    default: W = Wo; hi = oh; lo = nullptr; break;
  }
  transpose_body(W, hi, lo, blockIdx.x, blockIdx.y, threadIdx.x, threadIdx.y);
}

// ---- per-head column sums of W, stored TRANSPOSED: CS_T[h][k] -----------
__global__ __launch_bounds__(256) void colsum_f64(
    const float* __restrict__ W, float* __restrict__ CS) {
  const int k = blockIdx.x;                 // row of W
  const int t = threadIdx.x;
  const int h = t >> 4, s = t & 15;
  double acc = 0.0;
  const float* p = W + (size_t)k * DMODEL + h * DHEAD + s * 8;
#pragma unroll
  for (int i = 0; i < 8; i++) acc += (double)p[i];
#pragma unroll
  for (int m = 1; m < 16; m <<= 1) acc += __shfl_xor(acc, m, 64);
  if (s == 0) CS[(size_t)h * DMODEL + k] = (float)acc;
}

// ---- exact per-head row sums, v3: both operands lane-consecutive --------
// rs[row][h] = sum_k X[row][k] * CS_T[h][k]; fp64 accumulate.
// Wave w owns 2 rows; lane owns float4 chunk (i*64+lane): X and CS loads
// are both fully coalesced (1 KB/instr); no LDS, no barriers.
__global__ __launch_bounds__(256) void rowsum_v3(
    const float* __restrict__ q, const float* __restrict__ k,
    const float* __restrict__ CSq, const float* __restrict__ CSk,
    float* __restrict__ rsQ, float* __restrict__ rsK) {
  const float* X;  const float* CS;  float* rs;
  if (blockIdx.y == 0) { X = q; CS = CSq; rs = rsQ; }
  else                 { X = k; CS = CSk; rs = rsK; }
  const int t = threadIdx.x;
  const int lane = t & 63, w = t >> 6;
  const int row0 = blockIdx.x * 8 + w * 2;     // 2 rows per wave

  const float4* x0 = (const float4*)(X + ((size_t)row0 << 11));
  const float4* x1 = (const float4*)(X + ((size_t)(row0 + 1) << 11));
  float4 xa[8], xb[8];
#pragma unroll
  for (int i = 0; i < 8; i++) {
    xa[i] = x0[i * 64 + lane];
    xb[i] = x1[i * 64 + lane];
  }
  const float4* cs4 = (const float4*)CS;

  for (int h = 0; h < 16; h++) {
    double a0 = 0.0, a1 = 0.0;
#pragma unroll
    for (int i = 0; i < 8; i++) {
      float4 cv = cs4[h * 512 + i * 64 + lane];
      a0 += (double)xa[i].x * (double)cv.x + (double)xa[i].y * (double)cv.y
          + (double)xa[i].z * (double)cv.z + (double)xa[i].w * (double)cv.w;
      a1 += (double)xb[i].x * (double)cv.x + (double)xb[i].y * (double)cv.y
          + (double)xb[i].z * (double)cv.z + (double)xb[i].w * (double)cv.w;
    }
#pragma unroll
    for (int m = 1; m < 64; m <<= 1) {
      a0 += __shfl_xor(a0, m, 64);
      a1 += __shfl_xor(a1, m, 64);
    }
    if (lane == 0) {
      rs[(size_t)row0 * NHEAD + h]       = (float)a0;
      rs[(size_t)(row0 + 1) * NHEAD + h] = (float)a1;
    }
  }
}

// ---------------- fp16(-split) MFMA GEMM: C[M,N] = A[M,K] @ BT[N,K]^T ----
__device__ inline void glds16(const void* g, void* l) {
  __builtin_amdgcn_global_load_lds(
      (const __attribute__((address_space(1))) unsigned int*)g,
      (__attribute__((address_space(3))) unsigned int*)l, 16, 0, 0);
}

template <int NPASS, int OUT_HALF>
__global__ __launch_bounds__(256) void gemm_f16(
    const _Float16* __restrict__ Ahi, const _Float16* __restrict__ Alo,
    const _Float16* __restrict__ Bhi, const _Float16* __restrict__ Blo,
    float* __restrict__ Cf, _Float16* __restrict__ Ch,
    int M, int N, int Kd) {
  constexpr int TILE = 128 * 32;                   // elems per LDS tile
  __shared__ _Float16 lds[(NPASS == 3 ? 4 : 2) * TILE];
  _Float16* sAh = lds;
  _Float16* sBh = lds + (NPASS == 3 ? 2 : 1) * TILE;
  _Float16* sAl = lds + TILE;                      // used only if NPASS==3
  _Float16* sBl = lds + 3 * TILE;                  // used only if NPASS==3

  const int t = threadIdx.x;
  const int lane = t & 63, wid = t >> 6;
  const int wm = wid >> 1, wn = wid & 1;           // 2x2 waves, 64x64 each
  const int lr = lane & 15, lk = (lane >> 4) * 8;

  // XCD-chunked bijective swizzle (nwg % 8 == 0) + ny-fast supertile order
  const int mtiles = M >> 7, ntiles = N >> 7;
  const int nwg = mtiles * ntiles;
  const int qq = nwg >> 3;
  const int v = (blockIdx.x & 7) * qq + (blockIdx.x >> 3);
  const int mx = v / ntiles, ny = v % ntiles;
  const int m0 = mx * 128, n0 = ny * 128;

  f32x4 acc[4][4] = {};

  for (int k0 = 0; k0 < Kd; k0 += 32) {
#pragma unroll
    for (int i = 0; i < 2; i++) {
      int slot = t + i * 256;
      int row = slot >> 2, kc = (slot & 3) * 8;
      glds16(Ahi + (size_t)(m0 + row) * Kd + k0 + kc, sAh + slot * 8);
      glds16(Bhi + (size_t)(n0 + row) * Kd + k0 + kc, sBh + slot * 8);
      if (NPASS == 3) {
        glds16(Alo + (size_t)(m0 + row) * Kd + k0 + kc, sAl + slot * 8);
        glds16(Blo + (size_t)(n0 + row) * Kd + k0 + kc, sBl + slot * 8);
      }
    }
    __syncthreads();

    f16x8 ah[4], bh[4], al[4], bl[4];
#pragma unroll
    for (int f = 0; f < 4; f++) {
      ah[f] = *(const f16x8*)&sAh[(wm * 64 + f * 16 + lr) * 32 + lk];
      bh[f] = *(const f16x8*)&sBh[(wn * 64 + f * 16 + lr) * 32 + lk];
      if (NPASS == 3) {
        al[f] = *(const f16x8*)&sAl[(wm * 64 + f * 16 + lr) * 32 + lk];
        bl[f] = *(const f16x8*)&sBl[(wn * 64 + f * 16 + lr) * 32 + lk];
      }
    }
#pragma unroll
    for (int i = 0; i < 4; i++)
#pragma unroll
      for (int j = 0; j < 4; j++) {
        acc[i][j] = __builtin_amdgcn_mfma_f32_16x16x32_f16(ah[i], bh[j], acc[i][j], 0, 0, 0);
        if (NPASS == 3) {
          acc[i][j] = __builtin_amdgcn_mfma_f32_16x16x32_f16(ah[i], bl[j], acc[i][j], 0, 0, 0);
          acc[i][j] = __builtin_amdgcn_mfma_f32_16x16x32_f16(al[i], bh[j], acc[i][j], 0, 0, 0);
        }
      }
    __syncthreads();
  }

#pragma unroll
  for (int i = 0; i < 4; i++) {
    int row = m0 + wm * 64 + i * 16 + (lane >> 4) * 4;
#pragma unroll
    for (int j = 0; j < 4; j++) {
      int col = n0 + wn * 64 + j * 16 + (lane & 15);
#pragma unroll
      for (int r = 0; r < 4; r++) {
        if (OUT_HALF)
          Ch[(size_t)(row + r) * N + col] = (_Float16)acc[i][j][r];
        else
          Cf[(size_t)(row + r) * N + col] = acc[i][j][r];
      }
    }
  }
}

// -------- per-position head attention: 1 block (256 thr) per (b,s) -------
__global__ __launch_bounds__(256) void attn_kernel(
    const float* __restrict__ Q, const float* __restrict__ K,
    const _Float16* __restrict__ V, const float* __restrict__ mask,
    const float* __restrict__ rsQ, const float* __restrict__ rsK,
    float* __restrict__ wout, _Float16* __restrict__ aout) {
  __shared__ float lq[16][132], lkk[16][132], lv[16][132];
  __shared__ float lw[16][17];
  const int pos = blockIdx.x;
  const int t = threadIdx.x;
  const int h = t >> 4, j = t & 15;
  const size_t rowbase = (size_t)pos * DMODEL + h * DHEAD;

  const float iq = 1.f / (rsQ[(size_t)pos * NHEAD + h] + 1e-6f);
  const float ik = 1.f / (rsK[(size_t)pos * NHEAD + h] + 1e-6f);

  {
    const int dlo = 4 * j, dhi = 64 + 4 * j;
    float4 q0 = *(const float4*)&Q[rowbase + dlo];
    float4 q1 = *(const float4*)&Q[rowbase + dhi];
    q0.x *= iq; q0.y *= iq; q0.z *= iq; q0.w *= iq;
    q1.x *= iq; q1.y *= iq; q1.z *= iq; q1.w *= iq;
    *(float4*)&lq[h][dlo] = q0;
    *(float4*)&lq[h][dhi] = q1;
    float4 k0 = *(const float4*)&K[rowbase + dlo];
    float4 k1 = *(const float4*)&K[rowbase + dhi];
    k0.x *= ik; k0.y *= ik; k0.z *= ik; k0.w *= ik;
    k1.x *= ik; k1.y *= ik; k1.z *= ik; k1.w *= ik;
    *(float4*)&lkk[h][dlo] = k0;
    *(float4*)&lkk[h][dhi] = k1;
    f16x4 v0 = *(const f16x4*)&V[rowbase + dlo];
    f16x4 v1 = *(const f16x4*)&V[rowbase + dhi];
    float4 vf0 = {(float)v0[0], (float)v0[1], (float)v0[2], (float)v0[3]};
    float4 vf1 = {(float)v1[0], (float)v1[1], (float)v1[2], (float)v1[3]};
    *(float4*)&lv[h][dlo] = vf0;
    *(float4*)&lv[h][dhi] = vf1;
  }
  __syncthreads();

  const float4* qr = (const float4*)&lq[h][0];
  const float4* kr = (const float4*)&lkk[j][0];
  float dot = 0.f;
#pragma unroll
  for (int d4 = 0; d4 < 32; d4++) {
    float4 a = qr[d4], b = kr[d4];
    dot = fmaf(a.x, b.x, dot); dot = fmaf(a.y, b.y, dot);
    dot = fmaf(a.z, b.z, dot); dot = fmaf(a.w, b.w, dot);
  }
  float mk = mask[(size_t)pos * 256 + t];
  float x = (dot - 1e9f * mk) * 0.08838834764831845f;  // 1/sqrt(128)
  float mx = x;
#pragma unroll
  for (int m = 1; m < 16; m <<= 1) mx = fmaxf(mx, __shfl_xor(mx, m, 64));
  float e = expf(x - mx);
  float den = e;
#pragma unroll
  for (int m = 1; m < 16; m <<= 1) den += __shfl_xor(den, m, 64);
  float w = e / den;
  wout[(size_t)pos * 256 + t] = w;
  lw[h][j] = w;
  __syncthreads();

  float wreg[16];
#pragma unroll
  for (int k2 = 0; k2 < 16; k2++) wreg[k2] = lw[h][k2];
  float4 a0 = {0.f, 0.f, 0.f, 0.f}, a1 = {0.f, 0.f, 0.f, 0.f};
  const int dlo = 4 * j, dhi = 64 + 4 * j;
#pragma unroll
  for (int k2 = 0; k2 < 16; k2++) {
    float4 v0 = *(const float4*)&lv[k2][dlo];
    float4 v1 = *(const float4*)&lv[k2][dhi];
    float wk = wreg[k2];
    a0.x = fmaf(wk, v0.x, a0.x); a0.y = fmaf(wk, v0.y, a0.y);
    a0.z = fmaf(wk, v0.z, a0.z); a0.w = fmaf(wk, v0.w, a0.w);
    a1.x = fmaf(wk, v1.x, a1.x); a1.y = fmaf(wk, v1.y, a1.y);
    a1.z = fmaf(wk, v1.z, a1.z); a1.w = fmaf(wk, v1.w, a1.w);
  }
  f16x4 o0, o1;
  o0[0] = (_Float16)a0.x; o0[1] = (_Float16)a0.y;
  o0[2] = (_Float16)a0.z; o0[3] = (_Float16)a0.w;
  o1[0] = (_Float16)a1.x; o1[1] = (_Float16)a1.y;
  o1[2] = (_Float16)a1.z; o1[3] = (_Float16)a1.w;
  *(f16x4*)&aout[rowbase + dlo] = o0;
  *(f16x4*)&aout[rowbase + dhi] = o1;
}

// -------------------------------------------------------------------------
extern "C" void kernel_launch(void* const* d_in, const int* in_sizes, int n_in,
                              void* d_out, int out_size, void* d_ws, size_t ws_size,
                              hipStream_t stream) {
  const float* query = (const float*)d_in[0];
  const float* key   = (const float*)d_in[1];
  const float* value = (const float*)d_in[2];
  const float* mask  = (const float*)d_in[3];
  const float* Wq = (const float*)d_in[4];
  const float* Wk = (const float*)d_in[5];
  const float* Wv = (const float*)d_in[6];
  const float* Wo = (const float*)d_in[7];

  float* out  = (float*)d_out;                       // [16384, 2048] fp32
  float* wout = out + (size_t)MROWS * DMODEL;        // [16384, 256] fp32

  const size_t SZ_HALF = (size_t)MROWS * DMODEL * 2; // 67.1 MB
  const size_t SZ_F32  = (size_t)MROWS * DMODEL * 4; // 134.2 MB
  const size_t SZ_W    = (size_t)DMODEL * DMODEL * 2;// 8.4 MB
  const size_t SZ_CS   = (size_t)DMODEL * NHEAD * 4; // 128 KB (fp32)
  const size_t SZ_RS   = (size_t)MROWS * NHEAD * 4;  // 1 MB

  const int n8 = MROWS * DMODEL / 8;
  const int ggrid = (MROWS / 128) * (DMODEL / 128);  // 2048 blocks, 1D
  dim3 tgrid4(DMODEL / 32, DMODEL / 32, 4);
  dim3 tgrid(DMODEL / 32, DMODEL / 32);
  dim3 tblk(32, 8);
  dim3 rsgrid(MROWS / 8, 2);
  float* Qbuf = out;   // Q fp32 parked in d_out, overwritten by final GEMM

  // Dedicated-buffer fused layout (10 dispatches) when workspace allows.
  const size_t NEED_A = 5 * SZ_HALF + SZ_F32 + 6 * SZ_W + 2 * SZ_CS + 2 * SZ_RS;
  const size_t NEED_B = 3 * SZ_HALF + SZ_F32 + 2 * SZ_W + 2 * SZ_CS + 2 * SZ_RS;
  char* ws = (char*)d_ws;

  if (ws_size >= NEED_A) {
    size_t off = 0;
    _Float16* qh = (_Float16*)(ws + off); off += SZ_HALF;
    _Float16* ql = (_Float16*)(ws + off); off += SZ_HALF;
    _Float16* kh = (_Float16*)(ws + off); off += SZ_HALF;
    _Float16* kl = (_Float16*)(ws + off); off += SZ_HALF;
    _Float16* vh = (_Float16*)(ws + off); off += SZ_HALF;
    float*  Kbuf = (float*)   (ws + off); off += SZ_F32;
    _Float16* wqh = (_Float16*)(ws + off); off += SZ_W;
    _Float16* wql = (_Float16*)(ws + off); off += SZ_W;
    _Float16* wkh = (_Float16*)(ws + off); off += SZ_W;
    _Float16* wkl = (_Float16*)(ws + off); off += SZ_W;
    _Float16* wvh = (_Float16*)(ws + off); off += SZ_W;
    _Float16* woh = (_Float16*)(ws + off); off += SZ_W;
    float* CSq = (float*)(ws + off); off += SZ_CS;
    float* CSk = (float*)(ws + off); off += SZ_CS;
    float* rsQ = (float*)(ws + off); off += SZ_RS;
    float* rsK = (float*)(ws + off); off += SZ_RS;
    _Float16* Vbuf   = qh;   // qh dead after g3Q
    _Float16* attn16 = ql;   // ql dead after g3Q

    colsum_f64<<<DMODEL, 256, 0, stream>>>(Wq, CSq);
    colsum_f64<<<DMODEL, 256, 0, stream>>>(Wk, CSk);
    rowsum_v3<<<rsgrid, 256, 0, stream>>>(query, key, CSq, CSk, rsQ, rsK);
    transpose_all<<<tgrid4, tblk, 0, stream>>>(Wq, Wk, Wv, Wo, wqh, wql, wkh, wkl, wvh, woh);
    split_all<<<dim3(4096, 3), 256, 0, stream>>>(query, key, value, qh, ql, kh, kl, vh, n8);
    gemm_f16<3, 0><<<ggrid, 256, 0, stream>>>(qh, ql, wqh, wql, Qbuf, nullptr, MROWS, DMODEL, DMODEL);
    gemm_f16<3, 0><<<ggrid, 256, 0, stream>>>(kh, kl, wkh, wkl, Kbuf, nullptr, MROWS, DMODEL, DMODEL);
    gemm_f16<1, 1><<<ggrid, 256, 0, stream>>>(vh, nullptr, wvh, nullptr, nullptr, Vbuf, MROWS, DMODEL, DMODEL);
    attn_kernel<<<MROWS, 256, 0, stream>>>(Qbuf, Kbuf, Vbuf, mask, rsQ, rsK, wout, attn16);
    gemm_f16<1, 0><<<ggrid, 256, 0, stream>>>(attn16, nullptr, woh, nullptr, out, nullptr, MROWS, DMODEL, DMODEL);
    return;
  }

  if (ws_size < NEED_B) return;  // workspace too small — fail visibly

  // Fallback: sequential-reuse layout
  _Float16* a_hi  = (_Float16*)ws;
  _Float16* a_lo  = (_Float16*)(ws + SZ_HALF);
  float*    Kbuf  = (float*)   (ws + 2 * SZ_HALF);
  _Float16* Vbuf  = (_Float16*)(ws + 2 * SZ_HALF + SZ_F32);
  _Float16* wT_hi = (_Float16*)(ws + 3 * SZ_HALF + SZ_F32);
  _Float16* wT_lo = (_Float16*)(ws + 3 * SZ_HALF + SZ_F32 + SZ_W);
  float*    CSq   = (float*)   (ws + 3 * SZ_HALF + SZ_F32 + 2 * SZ_W);
  float*    CSk   = (float*)   (ws + 3 * SZ_HALF + SZ_F32 + 2 * SZ_W + SZ_CS);
  float*    rsQ   = (float*)   (ws + 3 * SZ_HALF + SZ_F32 + 2 * SZ_W + 2 * SZ_CS);
  float*    rsK   = (float*)   (ws + 3 * SZ_HALF + SZ_F32 + 2 * SZ_W + 2 * SZ_CS + SZ_RS);
  _Float16* attn16 = a_hi;       // reused after V-GEMM consumed a_hi

  colsum_f64<<<DMODEL, 256, 0, stream>>>(Wq, CSq);
  colsum_f64<<<DMODEL, 256, 0, stream>>>(Wk, CSk);
  rowsum_v3<<<rsgrid, 256, 0, stream>>>(query, key, CSq, CSk, rsQ, rsK);

  split_f32_f16<<<4096, 256, 0, stream>>>(query, a_hi, a_lo, n8);
  transpose_split<<<tgrid, tblk, 0, stream>>>(Wq, wT_hi, wT_lo);
  gemm_f16<3, 0><<<ggrid, 256, 0, stream>>>(a_hi, a_lo, wT_hi, wT_lo, Qbuf, nullptr, MROWS, DMODEL, DMODEL);
  split_f32_f16<<<4096, 256, 0, stream>>>(key, a_hi, a_lo, n8);
  transpose_split<<<tgrid, tblk, 0, stream>>>(Wk, wT_hi, wT_lo);
  gemm_f16<3, 0><<<ggrid, 256, 0, stream>>>(a_hi, a_lo, wT_hi, wT_lo, Kbuf, nullptr, MROWS, DMODEL, DMODEL);
  split_f32_f16<<<4096, 256, 0, stream>>>(value, a_hi, nullptr, n8);
  transpose_split<<<tgrid, tblk, 0, stream>>>(Wv, wT_hi, nullptr);
  gemm_f16<1, 1><<<ggrid, 256, 0, stream>>>(a_hi, nullptr, wT_hi, nullptr, nullptr, Vbuf, MROWS, DMODEL, DMODEL);
  attn_kernel<<<MROWS, 256, 0, stream>>>(Qbuf, Kbuf, Vbuf, mask, rsQ, rsK, wout, attn16);
  transpose_split<<<tgrid, tblk, 0, stream>>>(Wo, wT_hi, nullptr);
  gemm_f16<1, 0><<<ggrid, 256, 0, stream>>>(attn16, nullptr, wT_hi, nullptr, out, nullptr, MROWS, DMODEL, DMODEL);
}

// Round 8
// 1574.406 us; speedup vs baseline: 1.4114x; 1.1373x over previous
//
#include <hip/hip_runtime.h>
#include <hip/hip_fp16.h>

#define NHEAD 16
#define DHEAD 128
#define DMODEL 2048
#define SEQ 4096
#define BATCH 4
#define MROWS (BATCH*SEQ)   // 16384

typedef _Float16 f16x8 __attribute__((ext_vector_type(8)));
typedef _Float16 f16x4 __attribute__((ext_vector_type(4)));
typedef float f32x4 __attribute__((ext_vector_type(4)));

// ---------------- fp32 -> fp16 (hi, lo) split, 8 elems/thread ------------
__device__ inline void split8(const float* __restrict__ x, _Float16* __restrict__ hi,
                              _Float16* __restrict__ lo, int i8) {
  float4 v0 = ((const float4*)x)[2 * i8];
  float4 v1 = ((const float4*)x)[2 * i8 + 1];
  f16x8 h, l;
  h[0] = (_Float16)v0.x; h[1] = (_Float16)v0.y;
  h[2] = (_Float16)v0.z; h[3] = (_Float16)v0.w;
  h[4] = (_Float16)v1.x; h[5] = (_Float16)v1.y;
  h[6] = (_Float16)v1.z; h[7] = (_Float16)v1.w;
  ((f16x8*)hi)[i8] = h;
  if (lo) {
    l[0] = (_Float16)(v0.x - (float)h[0]);
    l[1] = (_Float16)(v0.y - (float)h[1]);
    l[2] = (_Float16)(v0.z - (float)h[2]);
    l[3] = (_Float16)(v0.w - (float)h[3]);
    l[4] = (_Float16)(v1.x - (float)h[4]);
    l[5] = (_Float16)(v1.y - (float)h[5]);
    l[6] = (_Float16)(v1.z - (float)h[6]);
    l[7] = (_Float16)(v1.w - (float)h[7]);
    ((f16x8*)lo)[i8] = l;
  }
}

// one matrix per launch (fallback path)
__global__ __launch_bounds__(256) void split_f32_f16(
    const float* __restrict__ x, _Float16* __restrict__ hi,
    _Float16* __restrict__ lo, int n8) {
  int i = blockIdx.x * blockDim.x + threadIdx.x;
  int stride = gridDim.x * blockDim.x;
  for (; i < n8; i += stride) split8(x, hi, lo, i);
}

// all three matrices in one launch (blockIdx.y selects)
__global__ __launch_bounds__(256) void split_all(
    const float* __restrict__ q, const float* __restrict__ k,
    const float* __restrict__ v,
    _Float16* __restrict__ qh, _Float16* __restrict__ ql,
    _Float16* __restrict__ kh, _Float16* __restrict__ kl,
    _Float16* __restrict__ vh, int n8) {
  const float* x; _Float16* hi; _Float16* lo;
  if (blockIdx.y == 0)      { x = q; hi = qh; lo = ql; }
  else if (blockIdx.y == 1) { x = k; hi = kh; lo = kl; }
  else                      { x = v; hi = vh; lo = nullptr; }
  int i = blockIdx.x * blockDim.x + threadIdx.x;
  int stride = gridDim.x * blockDim.x;
  for (; i < n8; i += stride) split8(x, hi, lo, i);
}

// ------------- weight transpose + split: W[K][N] -> WT[N][K] f16 ---------
__device__ inline void transpose_body(const float* __restrict__ W,
                                      _Float16* __restrict__ hi,
                                      _Float16* __restrict__ lo,
                                      int bx, int by, int tx, int ty) {
  __shared__ float tile[32][33];
  int c = bx * 32 + tx;
  for (int r0 = 0; r0 < 32; r0 += 8) {
    int r = by * 32 + ty + r0;
    tile[ty + r0][tx] = W[(size_t)r * DMODEL + c];
  }
  __syncthreads();
  for (int r0 = 0; r0 < 32; r0 += 8) {
    int n = bx * 32 + ty + r0;             // WT row = original col
    int k = by * 32 + tx;                  // WT col = original row
    float v = tile[tx][ty + r0];           // = W[k][n]
    _Float16 h = (_Float16)v;
    hi[(size_t)n * DMODEL + k] = h;
    if (lo) lo[(size_t)n * DMODEL + k] = (_Float16)(v - (float)h);
  }
}

__global__ __launch_bounds__(256) void transpose_split(
    const float* __restrict__ W, _Float16* __restrict__ hi,
    _Float16* __restrict__ lo) {
  transpose_body(W, hi, lo, blockIdx.x, blockIdx.y, threadIdx.x, threadIdx.y);
}

// all four weights in one launch (blockIdx.z selects)
__global__ __launch_bounds__(256) void transpose_all(
    const float* __restrict__ Wq, const float* __restrict__ Wk,
    const float* __restrict__ Wv, const float* __restrict__ Wo,
    _Float16* __restrict__ qh, _Float16* __restrict__ ql,
    _Float16* __restrict__ kh, _Float16* __restrict__ kl,
    _Float16* __restrict__ vh, _Float16* __restrict__ oh) {
  const float* W; _Float16* hi; _Float16* lo;
  switch (blockIdx.z) {
    case 0:  W = Wq; hi = qh; lo = ql;      break;
    case 1:  W = Wk; hi = kh; lo = kl;      break;
    case 2:  W = Wv; hi = vh; lo = nullptr; break;
    default: W = Wo; hi = oh; lo = nullptr; break;
  }
  transpose_body(W, hi, lo, blockIdx.x, blockIdx.y, threadIdx.x, threadIdx.y);
}

// ---- per-head column sums of W, stored TRANSPOSED: CS_T[h][k] -----------
__global__ __launch_bounds__(256) void colsum_f64(
    const float* __restrict__ W, float* __restrict__ CS) {
  const int k = blockIdx.x;                 // row of W
  const int t = threadIdx.x;
  const int h = t >> 4, s = t & 15;
  double acc = 0.0;
  const float* p = W + (size_t)k * DMODEL + h * DHEAD + s * 8;
#pragma unroll
  for (int i = 0; i < 8; i++) acc += (double)p[i];
#pragma unroll
  for (int m = 1; m < 16; m <<= 1) acc += __shfl_xor(acc, m, 64);
  if (s == 0) CS[(size_t)h * DMODEL + k] = (float)acc;
}

// ---- exact per-head row sums, v3: both operands lane-consecutive --------
__global__ __launch_bounds__(256) void rowsum_v3(
    const float* __restrict__ q, const float* __restrict__ k,
    const float* __restrict__ CSq, const float* __restrict__ CSk,
    float* __restrict__ rsQ, float* __restrict__ rsK) {
  const float* X;  const float* CS;  float* rs;
  if (blockIdx.y == 0) { X = q; CS = CSq; rs = rsQ; }
  else                 { X = k; CS = CSk; rs = rsK; }
  const int t = threadIdx.x;
  const int lane = t & 63, w = t >> 6;
  const int row0 = blockIdx.x * 8 + w * 2;     // 2 rows per wave

  const float4* x0 = (const float4*)(X + ((size_t)row0 << 11));
  const float4* x1 = (const float4*)(X + ((size_t)(row0 + 1) << 11));
  float4 xa[8], xb[8];
#pragma unroll
  for (int i = 0; i < 8; i++) {
    xa[i] = x0[i * 64 + lane];
    xb[i] = x1[i * 64 + lane];
  }
  const float4* cs4 = (const float4*)CS;

  for (int h = 0; h < 16; h++) {
    double a0 = 0.0, a1 = 0.0;
#pragma unroll
    for (int i = 0; i < 8; i++) {
      float4 cv = cs4[h * 512 + i * 64 + lane];
      a0 += (double)xa[i].x * (double)cv.x + (double)xa[i].y * (double)cv.y
          + (double)xa[i].z * (double)cv.z + (double)xa[i].w * (double)cv.w;
      a1 += (double)xb[i].x * (double)cv.x + (double)xb[i].y * (double)cv.y
          + (double)xb[i].z * (double)cv.z + (double)xb[i].w * (double)cv.w;
    }
#pragma unroll
    for (int m = 1; m < 64; m <<= 1) {
      a0 += __shfl_xor(a0, m, 64);
      a1 += __shfl_xor(a1, m, 64);
    }
    if (lane == 0) {
      rs[(size_t)row0 * NHEAD + h]       = (float)a0;
      rs[(size_t)(row0 + 1) * NHEAD + h] = (float)a1;
    }
  }
}

// -------------------------- async global->LDS ----------------------------
__device__ inline void glds16(const void* g, void* l) {
  __builtin_amdgcn_global_load_lds(
      (const __attribute__((address_space(1))) unsigned int*)g,
      (__attribute__((address_space(3))) unsigned int*)l, 16, 0, 0);
}

// ========== deep-pipelined 256x256 GEMM, counted vmcnt/lgkmcnt ===========
// C[M,N] = A[M,K] @ BT[N,K]^T ; NPASS=3: near-fp32 via hi/lo fp16 split.
// 8 waves (2m x 4n), per-wave 128x64 output. BK=32. Double-buffered LDS:
// NPASS=3: {Ahi,Alo,Bhi,Blo} x 16KB x 2buf = 128KB ; NPASS=1: 64KB.
// Schedule per K-tile t (buf c=t&1): pipelined quadrant ds_reads with
// counted lgkm; raw s_barrier (NO vmcnt-drain); stage(t+2) into buf c
// issued only after block-wide read-complete barrier; vmcnt(8/4) waits
// tile t+1 landed while t+2's loads stay in flight across barriers.
#define DP_LGKM_P() do { \
  if constexpr (NPASS == 3) asm volatile("s_waitcnt lgkmcnt(4)" ::: "memory"); \
  else                      asm volatile("s_waitcnt lgkmcnt(2)" ::: "memory"); \
  __builtin_amdgcn_sched_barrier(0); } while (0)
#define DP_LGKM_0() do { \
  asm volatile("s_waitcnt lgkmcnt(0)" ::: "memory"); \
  __builtin_amdgcn_sched_barrier(0); } while (0)
#define DP_VMCNT_P() do { \
  if constexpr (NPASS == 3) asm volatile("s_waitcnt vmcnt(8)" ::: "memory"); \
  else                      asm volatile("s_waitcnt vmcnt(4)" ::: "memory"); \
  __builtin_amdgcn_sched_barrier(0); } while (0)
#define DP_VMCNT_0() do { \
  asm volatile("s_waitcnt vmcnt(0)" ::: "memory"); \
  __builtin_amdgcn_sched_barrier(0); } while (0)
#define DP_BAR() do { \
  asm volatile("" ::: "memory"); \
  __builtin_amdgcn_s_barrier(); \
  asm volatile("" ::: "memory"); } while (0)
#define DP_QUAD(AR, P) do { \
  __builtin_amdgcn_s_setprio(1); \
  _Pragma("unroll") \
  for (int i_ = 0; i_ < 2; i_++) \
    _Pragma("unroll") \
    for (int n_ = 0; n_ < 4; n_++) { \
      acc[2*(P)+i_][n_] = __builtin_amdgcn_mfma_f32_16x16x32_f16(AR[i_], bhF[n_], acc[2*(P)+i_][n_], 0, 0, 0); \
      if constexpr (NPASS == 3) { \
        acc[2*(P)+i_][n_] = __builtin_amdgcn_mfma_f32_16x16x32_f16(AR[i_], blF[n_], acc[2*(P)+i_][n_], 0, 0, 0); \
        acc[2*(P)+i_][n_] = __builtin_amdgcn_mfma_f32_16x16x32_f16(AR[2+i_], bhF[n_], acc[2*(P)+i_][n_], 0, 0, 0); \
      } \
    } \
  __builtin_amdgcn_s_setprio(0); } while (0)

template <int NPASS, int OUT_HALF>
__global__ __launch_bounds__(512, 2) void gemm_dp(
    const _Float16* __restrict__ Ahi, const _Float16* __restrict__ Alo,
    const _Float16* __restrict__ Bhi, const _Float16* __restrict__ Blo,
    float* __restrict__ Cf, _Float16* __restrict__ Ch,
    int M, int N, int Kd) {
  extern __shared__ char smem_raw[];
  constexpr int NMAT = (NPASS == 3) ? 4 : 2;
  constexpr int BUFB = NMAT * 16384;                  // bytes per K-tile buf
  constexpr int BOFF = (NPASS == 3) ? 32768 : 16384;  // Bhi byte offset

  const int t = threadIdx.x;
  const int lane = t & 63, wid = t >> 6;
  const int wm = wid >> 2, wn = wid & 3;              // 2 x 4 waves
  const int lr = lane & 15;
  const int lkb = (lane >> 4) * 16;                   // k-byte offset in row

  // XCD-chunked bijective swizzle (nwg = 512, %8 == 0)
  const int mtiles = M >> 8, ntiles = N >> 8;
  const int nwg = mtiles * ntiles;
  const int qq = nwg >> 3;
  const int v = (blockIdx.x & 7) * qq + (blockIdx.x >> 3);
  const int m0 = (v / ntiles) << 8, n0 = (v % ntiles) << 8;
  const int NT = Kd >> 5;

  f32x4 acc[8][4] = {};
  f16x8 bhF[4], blF[4], aA[4], aB[4];

  auto STAGE = [&](int kt, int c) {
    char* dstb = smem_raw + c * BUFB;
    const size_t kOff = (size_t)kt << 5;
#pragma unroll
    for (int j = 0; j < NMAT * 2; j++) {
      int s = t + j * 512;                 // slot; 64-lane runs never cross
      int mm = s >> 10;                    //   a 1024-slot matrix boundary
      int r = (s & 1023) >> 2;
      int c8 = (s & 3) << 3;
      const _Float16* src; int rb;
      if (mm == 0)      { src = Ahi; rb = m0 + r; }
      else if (mm == 1) { src = (NPASS == 3) ? Alo : Bhi;
                          rb = ((NPASS == 3) ? m0 : n0) + r; }
      else if (mm == 2) { src = Bhi; rb = n0 + r; }
      else              { src = Blo; rb = n0 + r; }
      glds16(src + (size_t)rb * Kd + kOff + c8, dstb + (size_t)s * 16);
    }
  };
  auto RD_B = [&](const char* buf) {
#pragma unroll
    for (int n = 0; n < 4; n++) {
      int row = wn * 64 + n * 16 + lr;
      bhF[n] = *(const f16x8*)(buf + BOFF + row * 64 + lkb);
      if constexpr (NPASS == 3)
        blF[n] = *(const f16x8*)(buf + BOFF + 16384 + row * 64 + lkb);
    }
  };
  auto RD_A = [&](const char* buf, int p, f16x8* d) {
#pragma unroll
    for (int i = 0; i < 2; i++) {
      int row = wm * 128 + (2 * p + i) * 16 + lr;
      d[i] = *(const f16x8*)(buf + row * 64 + lkb);
      if constexpr (NPASS == 3)
        d[2 + i] = *(const f16x8*)(buf + 16384 + row * 64 + lkb);
    }
  };

  // prologue: tiles 0 and 1 staged; wait tile 0 landed (counted)
  STAGE(0, 0);
  STAGE(1, 1);
  DP_VMCNT_P();
  DP_BAR();

  for (int kt = 0; kt < NT; kt++) {
    const char* buf = (const char*)smem_raw + (kt & 1) * BUFB;
    RD_B(buf);
    RD_A(buf, 0, aA);
    RD_A(buf, 1, aB);
    DP_LGKM_P();                 // B + A-pair0 in regs (A-pair1 in flight)
    DP_QUAD(aA, 0);
    RD_A(buf, 2, aA);
    DP_LGKM_P();                 // A-pair1 ready
    DP_QUAD(aB, 1);
    RD_A(buf, 3, aB);
    DP_LGKM_P();                 // A-pair2 ready
    DP_QUAD(aA, 2);
    DP_LGKM_0();                 // all reads of tile kt done (this wave)
    DP_BAR();                    // ... and block-wide -> safe to overwrite
    if (kt + 2 < NT) {
      STAGE(kt + 2, kt & 1);     // into the buffer we just finished reading
      DP_QUAD(aB, 3);
      DP_VMCNT_P();              // tile kt+1 landed; kt+2 stays in flight
    } else {
      DP_QUAD(aB, 3);
      DP_VMCNT_0();              // epilogue drain
    }
    DP_BAR();                    // publish buf (kt+1)&1
  }

  // epilogue: C write
#pragma unroll
  for (int mi = 0; mi < 8; mi++) {
    int row = m0 + wm * 128 + mi * 16 + ((lane >> 4) << 2);
#pragma unroll
    for (int n = 0; n < 4; n++) {
      int col = n0 + wn * 64 + n * 16 + (lane & 15);
#pragma unroll
      for (int r = 0; r < 4; r++) {
        if constexpr (OUT_HALF)
          Ch[(size_t)(row + r) * N + col] = (_Float16)acc[mi][n][r];
        else
          Cf[(size_t)(row + r) * N + col] = acc[mi][n][r];
      }
    }
  }
}
#undef DP_LGKM_P
#undef DP_LGKM_0
#undef DP_VMCNT_P
#undef DP_VMCNT_0
#undef DP_BAR
#undef DP_QUAD

// ---------------- fallback 128x128 2-phase GEMM (proven) -----------------
template <int NPASS, int OUT_HALF>
__global__ __launch_bounds__(256) void gemm_f16(
    const _Float16* __restrict__ Ahi, const _Float16* __restrict__ Alo,
    const _Float16* __restrict__ Bhi, const _Float16* __restrict__ Blo,
    float* __restrict__ Cf, _Float16* __restrict__ Ch,
    int M, int N, int Kd) {
  constexpr int TILE = 128 * 32;
  __shared__ _Float16 lds[(NPASS == 3 ? 4 : 2) * TILE];
  _Float16* sAh = lds;
  _Float16* sBh = lds + (NPASS == 3 ? 2 : 1) * TILE;
  _Float16* sAl = lds + TILE;
  _Float16* sBl = lds + 3 * TILE;

  const int t = threadIdx.x;
  const int lane = t & 63, wid = t >> 6;
  const int wm = wid >> 1, wn = wid & 1;
  const int lr = lane & 15, lk = (lane >> 4) * 8;

  const int mtiles = M >> 7, ntiles = N >> 7;
  const int nwg = mtiles * ntiles;
  const int qq = nwg >> 3;
  const int v = (blockIdx.x & 7) * qq + (blockIdx.x >> 3);
  const int mx = v / ntiles, ny = v % ntiles;
  const int m0 = mx * 128, n0 = ny * 128;

  f32x4 acc[4][4] = {};

  for (int k0 = 0; k0 < Kd; k0 += 32) {
#pragma unroll
    for (int i = 0; i < 2; i++) {
      int slot = t + i * 256;
      int row = slot >> 2, kc = (slot & 3) * 8;
      glds16(Ahi + (size_t)(m0 + row) * Kd + k0 + kc, sAh + slot * 8);
      glds16(Bhi + (size_t)(n0 + row) * Kd + k0 + kc, sBh + slot * 8);
      if (NPASS == 3) {
        glds16(Alo + (size_t)(m0 + row) * Kd + k0 + kc, sAl + slot * 8);
        glds16(Blo + (size_t)(n0 + row) * Kd + k0 + kc, sBl + slot * 8);
      }
    }
    __syncthreads();

    f16x8 ah[4], bh[4], al[4], bl[4];
#pragma unroll
    for (int f = 0; f < 4; f++) {
      ah[f] = *(const f16x8*)&sAh[(wm * 64 + f * 16 + lr) * 32 + lk];
      bh[f] = *(const f16x8*)&sBh[(wn * 64 + f * 16 + lr) * 32 + lk];
      if (NPASS == 3) {
        al[f] = *(const f16x8*)&sAl[(wm * 64 + f * 16 + lr) * 32 + lk];
        bl[f] = *(const f16x8*)&sBl[(wn * 64 + f * 16 + lr) * 32 + lk];
      }
    }
#pragma unroll
    for (int i = 0; i < 4; i++)
#pragma unroll
      for (int j = 0; j < 4; j++) {
        acc[i][j] = __builtin_amdgcn_mfma_f32_16x16x32_f16(ah[i], bh[j], acc[i][j], 0, 0, 0);
        if (NPASS == 3) {
          acc[i][j] = __builtin_amdgcn_mfma_f32_16x16x32_f16(ah[i], bl[j], acc[i][j], 0, 0, 0);
          acc[i][j] = __builtin_amdgcn_mfma_f32_16x16x32_f16(al[i], bh[j], acc[i][j], 0, 0, 0);
        }
      }
    __syncthreads();
  }

#pragma unroll
  for (int i = 0; i < 4; i++) {
    int row = m0 + wm * 64 + i * 16 + (lane >> 4) * 4;
#pragma unroll
    for (int j = 0; j < 4; j++) {
      int col = n0 + wn * 64 + j * 16 + (lane & 15);
#pragma unroll
      for (int r = 0; r < 4; r++) {
        if (OUT_HALF)
          Ch[(size_t)(row + r) * N + col] = (_Float16)acc[i][j][r];
        else
          Cf[(size_t)(row + r) * N + col] = acc[i][j][r];
      }
    }
  }
}

// -------- per-position head attention: 1 block (256 thr) per (b,s) -------
__global__ __launch_bounds__(256) void attn_kernel(
    const float* __restrict__ Q, const float* __restrict__ K,
    const _Float16* __restrict__ V, const float* __restrict__ mask,
    const float* __restrict__ rsQ, const float* __restrict__ rsK,
    float* __restrict__ wout, _Float16* __restrict__ aout) {
  __shared__ float lq[16][132], lkk[16][132], lv[16][132];
  __shared__ float lw[16][17];
  const int pos = blockIdx.x;
  const int t = threadIdx.x;
  const int h = t >> 4, j = t & 15;
  const size_t rowbase = (size_t)pos * DMODEL + h * DHEAD;

  const float iq = 1.f / (rsQ[(size_t)pos * NHEAD + h] + 1e-6f);
  const float ik = 1.f / (rsK[(size_t)pos * NHEAD + h] + 1e-6f);

  {
    const int dlo = 4 * j, dhi = 64 + 4 * j;
    float4 q0 = *(const float4*)&Q[rowbase + dlo];
    float4 q1 = *(const float4*)&Q[rowbase + dhi];
    q0.x *= iq; q0.y *= iq; q0.z *= iq; q0.w *= iq;
    q1.x *= iq; q1.y *= iq; q1.z *= iq; q1.w *= iq;
    *(float4*)&lq[h][dlo] = q0;
    *(float4*)&lq[h][dhi] = q1;
    float4 k0 = *(const float4*)&K[rowbase + dlo];
    float4 k1 = *(const float4*)&K[rowbase + dhi];
    k0.x *= ik; k0.y *= ik; k0.z *= ik; k0.w *= ik;
    k1.x *= ik; k1.y *= ik; k1.z *= ik; k1.w *= ik;
    *(float4*)&lkk[h][dlo] = k0;
    *(float4*)&lkk[h][dhi] = k1;
    f16x4 v0 = *(const f16x4*)&V[rowbase + dlo];
    f16x4 v1 = *(const f16x4*)&V[rowbase + dhi];
    float4 vf0 = {(float)v0[0], (float)v0[1], (float)v0[2], (float)v0[3]};
    float4 vf1 = {(float)v1[0], (float)v1[1], (float)v1[2], (float)v1[3]};
    *(float4*)&lv[h][dlo] = vf0;
    *(float4*)&lv[h][dhi] = vf1;
  }
  __syncthreads();

  const float4* qr = (const float4*)&lq[h][0];
  const float4* kr = (const float4*)&lkk[j][0];
  float dot = 0.f;
#pragma unroll
  for (int d4 = 0; d4 < 32; d4++) {
    float4 a = qr[d4], b = kr[d4];
    dot = fmaf(a.x, b.x, dot); dot = fmaf(a.y, b.y, dot);
    dot = fmaf(a.z, b.z, dot); dot = fmaf(a.w, b.w, dot);
  }
  float mk = mask[(size_t)pos * 256 + t];
  float x = (dot - 1e9f * mk) * 0.08838834764831845f;  // 1/sqrt(128)
  float mx = x;
#pragma unroll
  for (int m = 1; m < 16; m <<= 1) mx = fmaxf(mx, __shfl_xor(mx, m, 64));
  float e = expf(x - mx);
  float den = e;
#pragma unroll
  for (int m = 1; m < 16; m <<= 1) den += __shfl_xor(den, m, 64);
  float w = e / den;
  wout[(size_t)pos * 256 + t] = w;
  lw[h][j] = w;
  __syncthreads();

  float wreg[16];
#pragma unroll
  for (int k2 = 0; k2 < 16; k2++) wreg[k2] = lw[h][k2];
  float4 a0 = {0.f, 0.f, 0.f, 0.f}, a1 = {0.f, 0.f, 0.f, 0.f};
  const int dlo = 4 * j, dhi = 64 + 4 * j;
#pragma unroll
  for (int k2 = 0; k2 < 16; k2++) {
    float4 v0 = *(const float4*)&lv[k2][dlo];
    float4 v1 = *(const float4*)&lv[k2][dhi];
    float wk = wreg[k2];
    a0.x = fmaf(wk, v0.x, a0.x); a0.y = fmaf(wk, v0.y, a0.y);
    a0.z = fmaf(wk, v0.z, a0.z); a0.w = fmaf(wk, v0.w, a0.w);
    a1.x = fmaf(wk, v1.x, a1.x); a1.y = fmaf(wk, v1.y, a1.y);
    a1.z = fmaf(wk, v1.z, a1.z); a1.w = fmaf(wk, v1.w, a1.w);
  }
  f16x4 o0, o1;
  o0[0] = (_Float16)a0.x; o0[1] = (_Float16)a0.y;
  o0[2] = (_Float16)a0.z; o0[3] = (_Float16)a0.w;
  o1[0] = (_Float16)a1.x; o1[1] = (_Float16)a1.y;
  o1[2] = (_Float16)a1.z; o1[3] = (_Float16)a1.w;
  *(f16x4*)&aout[rowbase + dlo] = o0;
  *(f16x4*)&aout[rowbase + dhi] = o1;
}

// -------------------------------------------------------------------------
extern "C" void kernel_launch(void* const* d_in, const int* in_sizes, int n_in,
                              void* d_out, int out_size, void* d_ws, size_t ws_size,
                              hipStream_t stream) {
  const float* query = (const float*)d_in[0];
  const float* key   = (const float*)d_in[1];
  const float* value = (const float*)d_in[2];
  const float* mask  = (const float*)d_in[3];
  const float* Wq = (const float*)d_in[4];
  const float* Wk = (const float*)d_in[5];
  const float* Wv = (const float*)d_in[6];
  const float* Wo = (const float*)d_in[7];

  float* out  = (float*)d_out;                       // [16384, 2048] fp32
  float* wout = out + (size_t)MROWS * DMODEL;        // [16384, 256] fp32

  const size_t SZ_HALF = (size_t)MROWS * DMODEL * 2; // 67.1 MB
  const size_t SZ_F32  = (size_t)MROWS * DMODEL * 4; // 134.2 MB
  const size_t SZ_W    = (size_t)DMODEL * DMODEL * 2;// 8.4 MB
  const size_t SZ_CS   = (size_t)DMODEL * NHEAD * 4; // 128 KB (fp32)
  const size_t SZ_RS   = (size_t)MROWS * NHEAD * 4;  // 1 MB

  const int n8 = MROWS * DMODEL / 8;
  const int dpgrid = (MROWS / 256) * (DMODEL / 256); // 512 blocks, 1D
  const int ggrid = (MROWS / 128) * (DMODEL / 128);  // fallback grid
  dim3 tgrid4(DMODEL / 32, DMODEL / 32, 4);
  dim3 tgrid(DMODEL / 32, DMODEL / 32);
  dim3 tblk(32, 8);
  dim3 rsgrid(MROWS / 8, 2);
  float* Qbuf = out;   // Q fp32 parked in d_out, overwritten by final GEMM

  const size_t NEED_A = 5 * SZ_HALF + SZ_F32 + 6 * SZ_W + 2 * SZ_CS + 2 * SZ_RS;
  const size_t NEED_B = 3 * SZ_HALF + SZ_F32 + 2 * SZ_W + 2 * SZ_CS + 2 * SZ_RS;
  char* ws = (char*)d_ws;

  if (ws_size >= NEED_A) {
    size_t off = 0;
    _Float16* qh = (_Float16*)(ws + off); off += SZ_HALF;
    _Float16* ql = (_Float16*)(ws + off); off += SZ_HALF;
    _Float16* kh = (_Float16*)(ws + off); off += SZ_HALF;
    _Float16* kl = (_Float16*)(ws + off); off += SZ_HALF;
    _Float16* vh = (_Float16*)(ws + off); off += SZ_HALF;
    float*  Kbuf = (float*)   (ws + off); off += SZ_F32;
    _Float16* wqh = (_Float16*)(ws + off); off += SZ_W;
    _Float16* wql = (_Float16*)(ws + off); off += SZ_W;
    _Float16* wkh = (_Float16*)(ws + off); off += SZ_W;
    _Float16* wkl = (_Float16*)(ws + off); off += SZ_W;
    _Float16* wvh = (_Float16*)(ws + off); off += SZ_W;
    _Float16* woh = (_Float16*)(ws + off); off += SZ_W;
    float* CSq = (float*)(ws + off); off += SZ_CS;
    float* CSk = (float*)(ws + off); off += SZ_CS;
    float* rsQ = (float*)(ws + off); off += SZ_RS;
    float* rsK = (float*)(ws + off); off += SZ_RS;
    _Float16* Vbuf   = qh;   // qh dead after Q-GEMM
    _Float16* attn16 = ql;   // ql dead after Q-GEMM

    colsum_f64<<<DMODEL, 256, 0, stream>>>(Wq, CSq);
    colsum_f64<<<DMODEL, 256, 0, stream>>>(Wk, CSk);
    rowsum_v3<<<rsgrid, 256, 0, stream>>>(query, key, CSq, CSk, rsQ, rsK);
    transpose_all<<<tgrid4, tblk, 0, stream>>>(Wq, Wk, Wv, Wo, wqh, wql, wkh, wkl, wvh, woh);
    split_all<<<dim3(4096, 3), 256, 0, stream>>>(query, key, value, qh, ql, kh, kl, vh, n8);
    gemm_dp<3, 0><<<dpgrid, 512, 131072, stream>>>(qh, ql, wqh, wql, Qbuf, nullptr, MROWS, DMODEL, DMODEL);
    gemm_dp<3, 0><<<dpgrid, 512, 131072, stream>>>(kh, kl, wkh, wkl, Kbuf, nullptr, MROWS, DMODEL, DMODEL);
    gemm_dp<1, 1><<<dpgrid, 512, 65536, stream>>>(vh, nullptr, wvh, nullptr, nullptr, Vbuf, MROWS, DMODEL, DMODEL);
    attn_kernel<<<MROWS, 256, 0, stream>>>(Qbuf, Kbuf, Vbuf, mask, rsQ, rsK, wout, attn16);
    gemm_dp<1, 0><<<dpgrid, 512, 65536, stream>>>(attn16, nullptr, woh, nullptr, out, nullptr, MROWS, DMODEL, DMODEL);
    return;
  }

  if (ws_size < NEED_B) return;  // workspace too small — fail visibly

  // Fallback: sequential-reuse layout with proven 2-phase GEMM
  _Float16* a_hi  = (_Float16*)ws;
  _Float16* a_lo  = (_Float16*)(ws + SZ_HALF);
  float*    Kbuf  = (float*)   (ws + 2 * SZ_HALF);
  _Float16* Vbuf  = (_Float16*)(ws + 2 * SZ_HALF + SZ_F32);
  _Float16* wT_hi = (_Float16*)(ws + 3 * SZ_HALF + SZ_F32);
  _Float16* wT_lo = (_Float16*)(ws + 3 * SZ_HALF + SZ_F32 + SZ_W);
  float*    CSq   = (float*)   (ws + 3 * SZ_HALF + SZ_F32 + 2 * SZ_W);
  float*    CSk   = (float*)   (ws + 3 * SZ_HALF + SZ_F32 + 2 * SZ_W + SZ_CS);
  float*    rsQ   = (float*)   (ws + 3 * SZ_HALF + SZ_F32 + 2 * SZ_W + 2 * SZ_CS);
  float*    rsK   = (float*)   (ws + 3 * SZ_HALF + SZ_F32 + 2 * SZ_W + 2 * SZ_CS + SZ_RS);
  _Float16* attn16 = a_hi;

  colsum_f64<<<DMODEL, 256, 0, stream>>>(Wq, CSq);
  colsum_f64<<<DMODEL, 256, 0, stream>>>(Wk, CSk);
  rowsum_v3<<<rsgrid, 256, 0, stream>>>(query, key, CSq, CSk, rsQ, rsK);

  split_f32_f16<<<4096, 256, 0, stream>>>(query, a_hi, a_lo, n8);
  transpose_split<<<tgrid, tblk, 0, stream>>>(Wq, wT_hi, wT_lo);
  gemm_f16<3, 0><<<ggrid, 256, 0, stream>>>(a_hi, a_lo, wT_hi, wT_lo, Qbuf, nullptr, MROWS, DMODEL, DMODEL);
  split_f32_f16<<<4096, 256, 0, stream>>>(key, a_hi, a_lo, n8);
  transpose_split<<<tgrid, tblk, 0, stream>>>(Wk, wT_hi, wT_lo);
  gemm_f16<3, 0><<<ggrid, 256, 0, stream>>>(a_hi, a_lo, wT_hi, wT_lo, Kbuf, nullptr, MROWS, DMODEL, DMODEL);
  split_f32_f16<<<4096, 256, 0, stream>>>(value, a_hi, nullptr, n8);
  transpose_split<<<tgrid, tblk, 0, stream>>>(Wv, wT_hi, nullptr);
  gemm_f16<1, 1><<<ggrid, 256, 0, stream>>>(a_hi, nullptr, wT_hi, nullptr, nullptr, Vbuf, MROWS, DMODEL, DMODEL);
  attn_kernel<<<MROWS, 256, 0, stream>>>(Qbuf, Kbuf, Vbuf, mask, rsQ, rsK, wout, attn16);
  transpose_split<<<tgrid, tblk, 0, stream>>>(Wo, wT_hi, nullptr);
  gemm_f16<1, 0><<<ggrid, 256, 0, stream>>>(attn16, nullptr, wT_hi, nullptr, out, nullptr, MROWS, DMODEL, DMODEL);
}

// Round 9
// 1557.813 us; speedup vs baseline: 1.4264x; 1.0107x over previous
//
#include <hip/hip_runtime.h>
#include <hip/hip_fp16.h>

#define NHEAD 16
#define DHEAD 128
#define DMODEL 2048
#define SEQ 4096
#define BATCH 4
#define MROWS (BATCH*SEQ)   // 16384

typedef _Float16 f16x8 __attribute__((ext_vector_type(8)));
typedef _Float16 f16x4 __attribute__((ext_vector_type(4)));
typedef float f32x4 __attribute__((ext_vector_type(4)));

// ---------------- fp32 -> fp16 (hi, lo) split, 8 elems/thread ------------
__device__ inline void split8(const float* __restrict__ x, _Float16* __restrict__ hi,
                              _Float16* __restrict__ lo, int i8) {
  float4 v0 = ((const float4*)x)[2 * i8];
  float4 v1 = ((const float4*)x)[2 * i8 + 1];
  f16x8 h, l;
  h[0] = (_Float16)v0.x; h[1] = (_Float16)v0.y;
  h[2] = (_Float16)v0.z; h[3] = (_Float16)v0.w;
  h[4] = (_Float16)v1.x; h[5] = (_Float16)v1.y;
  h[6] = (_Float16)v1.z; h[7] = (_Float16)v1.w;
  ((f16x8*)hi)[i8] = h;
  if (lo) {
    l[0] = (_Float16)(v0.x - (float)h[0]);
    l[1] = (_Float16)(v0.y - (float)h[1]);
    l[2] = (_Float16)(v0.z - (float)h[2]);
    l[3] = (_Float16)(v0.w - (float)h[3]);
    l[4] = (_Float16)(v1.x - (float)h[4]);
    l[5] = (_Float16)(v1.y - (float)h[5]);
    l[6] = (_Float16)(v1.z - (float)h[6]);
    l[7] = (_Float16)(v1.w - (float)h[7]);
    ((f16x8*)lo)[i8] = l;
  }
}

// one matrix per launch (fallback path)
__global__ __launch_bounds__(256) void split_f32_f16(
    const float* __restrict__ x, _Float16* __restrict__ hi,
    _Float16* __restrict__ lo, int n8) {
  int i = blockIdx.x * blockDim.x + threadIdx.x;
  int stride = gridDim.x * blockDim.x;
  for (; i < n8; i += stride) split8(x, hi, lo, i);
}

// all three matrices in one launch (blockIdx.y selects)
__global__ __launch_bounds__(256) void split_all(
    const float* __restrict__ q, const float* __restrict__ k,
    const float* __restrict__ v,
    _Float16* __restrict__ qh, _Float16* __restrict__ ql,
    _Float16* __restrict__ kh, _Float16* __restrict__ kl,
    _Float16* __restrict__ vh, int n8) {
  const float* x; _Float16* hi; _Float16* lo;
  if (blockIdx.y == 0)      { x = q; hi = qh; lo = ql; }
  else if (blockIdx.y == 1) { x = k; hi = kh; lo = kl; }
  else                      { x = v; hi = vh; lo = nullptr; }
  int i = blockIdx.x * blockDim.x + threadIdx.x;
  int stride = gridDim.x * blockDim.x;
  for (; i < n8; i += stride) split8(x, hi, lo, i);
}

// ------------- weight transpose + split: W[K][N] -> WT[N][K] f16 ---------
__device__ inline void transpose_body(const float* __restrict__ W,
                                      _Float16* __restrict__ hi,
                                      _Float16* __restrict__ lo,
                                      int bx, int by, int tx, int ty) {
  __shared__ float tile[32][33];
  int c = bx * 32 + tx;
  for (int r0 = 0; r0 < 32; r0 += 8) {
    int r = by * 32 + ty + r0;
    tile[ty + r0][tx] = W[(size_t)r * DMODEL + c];
  }
  __syncthreads();
  for (int r0 = 0; r0 < 32; r0 += 8) {
    int n = bx * 32 + ty + r0;             // WT row = original col
    int k = by * 32 + tx;                  // WT col = original row
    float v = tile[tx][ty + r0];           // = W[k][n]
    _Float16 h = (_Float16)v;
    hi[(size_t)n * DMODEL + k] = h;
    if (lo) lo[(size_t)n * DMODEL + k] = (_Float16)(v - (float)h);
  }
}

__global__ __launch_bounds__(256) void transpose_split(
    const float* __restrict__ W, _Float16* __restrict__ hi,
    _Float16* __restrict__ lo) {
  transpose_body(W, hi, lo, blockIdx.x, blockIdx.y, threadIdx.x, threadIdx.y);
}

// all four weights in one launch (blockIdx.z selects)
__global__ __launch_bounds__(256) void transpose_all(
    const float* __restrict__ Wq, const float* __restrict__ Wk,
    const float* __restrict__ Wv, const float* __restrict__ Wo,
    _Float16* __restrict__ qh, _Float16* __restrict__ ql,
    _Float16* __restrict__ kh, _Float16* __restrict__ kl,
    _Float16* __restrict__ vh, _Float16* __restrict__ oh) {
  const float* W; _Float16* hi; _Float16* lo;
  switch (blockIdx.z) {
    case 0:  W = Wq; hi = qh; lo = ql;      break;
    case 1:  W = Wk; hi = kh; lo = kl;      break;
    case 2:  W = Wv; hi = vh; lo = nullptr; break;
    default: W = Wo; hi = oh; lo = nullptr; break;
  }
  transpose_body(W, hi, lo, blockIdx.x, blockIdx.y, threadIdx.x, threadIdx.y);
}

// ---- per-head column sums of W, stored TRANSPOSED: CS_T[h][k] -----------
__global__ __launch_bounds__(256) void colsum_f64(
    const float* __restrict__ W, float* __restrict__ CS) {
  const int k = blockIdx.x;                 // row of W
  const int t = threadIdx.x;
  const int h = t >> 4, s = t & 15;
  double acc = 0.0;
  const float* p = W + (size_t)k * DMODEL + h * DHEAD + s * 8;
#pragma unroll
  for (int i = 0; i < 8; i++) acc += (double)p[i];
#pragma unroll
  for (int m = 1; m < 16; m <<= 1) acc += __shfl_xor(acc, m, 64);
  if (s == 0) CS[(size_t)h * DMODEL + k] = (float)acc;
}

// ---- exact per-head row sums, v3: both operands lane-consecutive --------
__global__ __launch_bounds__(256) void rowsum_v3(
    const float* __restrict__ q, const float* __restrict__ k,
    const float* __restrict__ CSq, const float* __restrict__ CSk,
    float* __restrict__ rsQ, float* __restrict__ rsK) {
  const float* X;  const float* CS;  float* rs;
  if (blockIdx.y == 0) { X = q; CS = CSq; rs = rsQ; }
  else                 { X = k; CS = CSk; rs = rsK; }
  const int t = threadIdx.x;
  const int lane = t & 63, w = t >> 6;
  const int row0 = blockIdx.x * 8 + w * 2;     // 2 rows per wave

  const float4* x0 = (const float4*)(X + ((size_t)row0 << 11));
  const float4* x1 = (const float4*)(X + ((size_t)(row0 + 1) << 11));
  float4 xa[8], xb[8];
#pragma unroll
  for (int i = 0; i < 8; i++) {
    xa[i] = x0[i * 64 + lane];
    xb[i] = x1[i * 64 + lane];
  }
  const float4* cs4 = (const float4*)CS;

  for (int h = 0; h < 16; h++) {
    double a0 = 0.0, a1 = 0.0;
#pragma unroll
    for (int i = 0; i < 8; i++) {
      float4 cv = cs4[h * 512 + i * 64 + lane];
      a0 += (double)xa[i].x * (double)cv.x + (double)xa[i].y * (double)cv.y
          + (double)xa[i].z * (double)cv.z + (double)xa[i].w * (double)cv.w;
      a1 += (double)xb[i].x * (double)cv.x + (double)xb[i].y * (double)cv.y
          + (double)xb[i].z * (double)cv.z + (double)xb[i].w * (double)cv.w;
    }
#pragma unroll
    for (int m = 1; m < 64; m <<= 1) {
      a0 += __shfl_xor(a0, m, 64);
      a1 += __shfl_xor(a1, m, 64);
    }
    if (lane == 0) {
      rs[(size_t)row0 * NHEAD + h]       = (float)a0;
      rs[(size_t)(row0 + 1) * NHEAD + h] = (float)a1;
    }
  }
}

// -------------------------- async global->LDS ----------------------------
__device__ inline void glds16(const void* g, void* l) {
  __builtin_amdgcn_global_load_lds(
      (const __attribute__((address_space(1))) unsigned int*)g,
      (__attribute__((address_space(3))) unsigned int*)l, 16, 0, 0);
}

// ========== deep-pipelined 256x256 GEMM, counted vmcnt/lgkmcnt ===========
// C[M,N] = A[M,K] @ BT[N,K]^T ; NPASS=3: near-fp32 via hi/lo fp16 split.
// 8 waves (2m x 4n), per-wave 128x64 output. BK=32. Double-buffered LDS.
// LDS bank-conflict swizzle (T2-analog, rule 21 both-sides): k-chunk g of
// row r stored at slot g^((r>>1)&3) within the row's 64B. Staging keeps
// LDS dest LINEAR (global_load_lds constraint) and pre-swizzles the global
// SOURCE chunk; reads XOR their k-slot. Each 16-lane read phase then hits
// each (row-parity, slot) bank-set with exactly 2 lanes -> conflict-free.
#define DP_LGKM_P() do { \
  if constexpr (NPASS == 3) asm volatile("s_waitcnt lgkmcnt(4)" ::: "memory"); \
  else                      asm volatile("s_waitcnt lgkmcnt(2)" ::: "memory"); \
  __builtin_amdgcn_sched_barrier(0); } while (0)
#define DP_LGKM_0() do { \
  asm volatile("s_waitcnt lgkmcnt(0)" ::: "memory"); \
  __builtin_amdgcn_sched_barrier(0); } while (0)
#define DP_VMCNT_P() do { \
  if constexpr (NPASS == 3) asm volatile("s_waitcnt vmcnt(8)" ::: "memory"); \
  else                      asm volatile("s_waitcnt vmcnt(4)" ::: "memory"); \
  __builtin_amdgcn_sched_barrier(0); } while (0)
#define DP_VMCNT_0() do { \
  asm volatile("s_waitcnt vmcnt(0)" ::: "memory"); \
  __builtin_amdgcn_sched_barrier(0); } while (0)
#define DP_BAR() do { \
  asm volatile("" ::: "memory"); \
  __builtin_amdgcn_s_barrier(); \
  asm volatile("" ::: "memory"); } while (0)
#define DP_QUAD(AR, P) do { \
  __builtin_amdgcn_s_setprio(1); \
  _Pragma("unroll") \
  for (int i_ = 0; i_ < 2; i_++) \
    _Pragma("unroll") \
    for (int n_ = 0; n_ < 4; n_++) { \
      acc[2*(P)+i_][n_] = __builtin_amdgcn_mfma_f32_16x16x32_f16(AR[i_], bhF[n_], acc[2*(P)+i_][n_], 0, 0, 0); \
      if constexpr (NPASS == 3) { \
        acc[2*(P)+i_][n_] = __builtin_amdgcn_mfma_f32_16x16x32_f16(AR[i_], blF[n_], acc[2*(P)+i_][n_], 0, 0, 0); \
        acc[2*(P)+i_][n_] = __builtin_amdgcn_mfma_f32_16x16x32_f16(AR[2+i_], bhF[n_], acc[2*(P)+i_][n_], 0, 0, 0); \
      } \
    } \
  __builtin_amdgcn_s_setprio(0); } while (0)

template <int NPASS, int OUT_HALF>
__global__ __launch_bounds__(512, 2) void gemm_dp(
    const _Float16* __restrict__ Ahi, const _Float16* __restrict__ Alo,
    const _Float16* __restrict__ Bhi, const _Float16* __restrict__ Blo,
    float* __restrict__ Cf, _Float16* __restrict__ Ch,
    int M, int N, int Kd) {
  extern __shared__ char smem_raw[];
  constexpr int NMAT = (NPASS == 3) ? 4 : 2;
  constexpr int NLD  = NMAT * 2;                      // glds16 per thread/tile
  constexpr int BUFB = NMAT * 16384;                  // bytes per K-tile buf
  constexpr int BOFF = (NPASS == 3) ? 32768 : 16384;  // Bhi byte offset

  const int t = threadIdx.x;
  const int lane = t & 63, wid = t >> 6;
  const int wm = wid >> 2, wn = wid & 3;              // 2 x 4 waves
  const int lr = lane & 15;
  // swizzled per-thread k-byte offset for LDS reads (row-quad = (lr>>1)&3)
  const int lkbs = (((lane >> 4) ^ ((lr >> 1) & 3)) << 4);

  // XCD-chunked bijective swizzle (nwg = 512, %8 == 0)
  const int mtiles = M >> 8, ntiles = N >> 8;
  const int nwg = mtiles * ntiles;
  const int qq = nwg >> 3;
  const int v = (blockIdx.x & 7) * qq + (blockIdx.x >> 3);
  const int m0 = (v / ntiles) << 8, n0 = (v % ntiles) << 8;
  const int NT = Kd >> 5;

  f32x4 acc[8][4] = {};
  f16x8 bhF[4], blF[4], aA[4], aB[4];

  // hoisted STAGE addressing: per-thread global base ptrs + LDS dest offs
  const char* gsrc[NLD];
  int ldst[NLD];
#pragma unroll
  for (int j = 0; j < NLD; j++) {
    int s = t + j * 512;                 // slot; runs never cross matrices
    int mm = s >> 10;
    int r = (s & 1023) >> 2;
    int g = s & 3;
    int gs = g ^ ((r >> 1) & 3);         // pre-swizzled source k-chunk
    const _Float16* src; int rb;
    if (mm == 0)      { src = Ahi; rb = m0 + r; }
    else if (mm == 1) { src = (NPASS == 3) ? Alo : Bhi;
                        rb = ((NPASS == 3) ? m0 : n0) + r; }
    else if (mm == 2) { src = Bhi; rb = n0 + r; }
    else              { src = Blo; rb = n0 + r; }
    gsrc[j] = (const char*)(src + (size_t)rb * Kd + gs * 8);
    ldst[j] = s * 16;
  }

  auto STAGE = [&](int kt, int c) {
    char* dstb = smem_raw + c * BUFB;
    const size_t kb = (size_t)kt << 6;   // kt*32 f16 = kt*64 bytes
#pragma unroll
    for (int j = 0; j < NLD; j++)
      glds16(gsrc[j] + kb, dstb + ldst[j]);
  };
  auto RD_B = [&](const char* buf) {
#pragma unroll
    for (int n = 0; n < 4; n++) {
      int row = wn * 64 + n * 16 + lr;
      bhF[n] = *(const f16x8*)(buf + BOFF + row * 64 + lkbs);
      if constexpr (NPASS == 3)
        blF[n] = *(const f16x8*)(buf + BOFF + 16384 + row * 64 + lkbs);
    }
  };
  auto RD_A = [&](const char* buf, int p, f16x8* d) {
#pragma unroll
    for (int i = 0; i < 2; i++) {
      int row = wm * 128 + (2 * p + i) * 16 + lr;
      d[i] = *(const f16x8*)(buf + row * 64 + lkbs);
      if constexpr (NPASS == 3)
        d[2 + i] = *(const f16x8*)(buf + 16384 + row * 64 + lkbs);
    }
  };

  // prologue: tiles 0 and 1 staged; wait tile 0 landed (counted)
  STAGE(0, 0);
  STAGE(1, 1);
  DP_VMCNT_P();
  DP_BAR();

  for (int kt = 0; kt < NT; kt++) {
    const char* buf = (const char*)smem_raw + (kt & 1) * BUFB;
    RD_B(buf);
    RD_A(buf, 0, aA);
    RD_A(buf, 1, aB);
    DP_LGKM_P();                 // B + A-pair0 in regs (A-pair1 in flight)
    DP_QUAD(aA, 0);
    RD_A(buf, 2, aA);
    DP_LGKM_P();                 // A-pair1 ready
    DP_QUAD(aB, 1);
    RD_A(buf, 3, aB);
    DP_LGKM_P();                 // A-pair2 ready
    DP_QUAD(aA, 2);
    DP_LGKM_0();                 // all reads of tile kt done (this wave)
    DP_BAR();                    // ... and block-wide -> safe to overwrite
    if (kt + 2 < NT) {
      STAGE(kt + 2, kt & 1);     // into the buffer we just finished reading
      DP_QUAD(aB, 3);
      DP_VMCNT_P();              // tile kt+1 landed; kt+2 stays in flight
    } else {
      DP_QUAD(aB, 3);
      DP_VMCNT_0();              // epilogue drain
    }
    DP_BAR();                    // publish buf (kt+1)&1
  }

  // epilogue: C write
#pragma unroll
  for (int mi = 0; mi < 8; mi++) {
    int row = m0 + wm * 128 + mi * 16 + ((lane >> 4) << 2);
#pragma unroll
    for (int n = 0; n < 4; n++) {
      int col = n0 + wn * 64 + n * 16 + (lane & 15);
#pragma unroll
      for (int r = 0; r < 4; r++) {
        if constexpr (OUT_HALF)
          Ch[(size_t)(row + r) * N + col] = (_Float16)acc[mi][n][r];
        else
          Cf[(size_t)(row + r) * N + col] = acc[mi][n][r];
      }
    }
  }
}
#undef DP_LGKM_P
#undef DP_LGKM_0
#undef DP_VMCNT_P
#undef DP_VMCNT_0
#undef DP_BAR
#undef DP_QUAD

// ---------------- fallback 128x128 2-phase GEMM (proven) -----------------
template <int NPASS, int OUT_HALF>
__global__ __launch_bounds__(256) void gemm_f16(
    const _Float16* __restrict__ Ahi, const _Float16* __restrict__ Alo,
    const _Float16* __restrict__ Bhi, const _Float16* __restrict__ Blo,
    float* __restrict__ Cf, _Float16* __restrict__ Ch,
    int M, int N, int Kd) {
  constexpr int TILE = 128 * 32;
  __shared__ _Float16 lds[(NPASS == 3 ? 4 : 2) * TILE];
  _Float16* sAh = lds;
  _Float16* sBh = lds + (NPASS == 3 ? 2 : 1) * TILE;
  _Float16* sAl = lds + TILE;
  _Float16* sBl = lds + 3 * TILE;

  const int t = threadIdx.x;
  const int lane = t & 63, wid = t >> 6;
  const int wm = wid >> 1, wn = wid & 1;
  const int lr = lane & 15, lk = (lane >> 4) * 8;

  const int mtiles = M >> 7, ntiles = N >> 7;
  const int nwg = mtiles * ntiles;
  const int qq = nwg >> 3;
  const int v = (blockIdx.x & 7) * qq + (blockIdx.x >> 3);
  const int mx = v / ntiles, ny = v % ntiles;
  const int m0 = mx * 128, n0 = ny * 128;

  f32x4 acc[4][4] = {};

  for (int k0 = 0; k0 < Kd; k0 += 32) {
#pragma unroll
    for (int i = 0; i < 2; i++) {
      int slot = t + i * 256;
      int row = slot >> 2, kc = (slot & 3) * 8;
      glds16(Ahi + (size_t)(m0 + row) * Kd + k0 + kc, sAh + slot * 8);
      glds16(Bhi + (size_t)(n0 + row) * Kd + k0 + kc, sBh + slot * 8);
      if (NPASS == 3) {
        glds16(Alo + (size_t)(m0 + row) * Kd + k0 + kc, sAl + slot * 8);
        glds16(Blo + (size_t)(n0 + row) * Kd + k0 + kc, sBl + slot * 8);
      }
    }
    __syncthreads();

    f16x8 ah[4], bh[4], al[4], bl[4];
#pragma unroll
    for (int f = 0; f < 4; f++) {
      ah[f] = *(const f16x8*)&sAh[(wm * 64 + f * 16 + lr) * 32 + lk];
      bh[f] = *(const f16x8*)&sBh[(wn * 64 + f * 16 + lr) * 32 + lk];
      if (NPASS == 3) {
        al[f] = *(const f16x8*)&sAl[(wm * 64 + f * 16 + lr) * 32 + lk];
        bl[f] = *(const f16x8*)&sBl[(wn * 64 + f * 16 + lr) * 32 + lk];
      }
    }
#pragma unroll
    for (int i = 0; i < 4; i++)
#pragma unroll
      for (int j = 0; j < 4; j++) {
        acc[i][j] = __builtin_amdgcn_mfma_f32_16x16x32_f16(ah[i], bh[j], acc[i][j], 0, 0, 0);
        if (NPASS == 3) {
          acc[i][j] = __builtin_amdgcn_mfma_f32_16x16x32_f16(ah[i], bl[j], acc[i][j], 0, 0, 0);
          acc[i][j] = __builtin_amdgcn_mfma_f32_16x16x32_f16(al[i], bh[j], acc[i][j], 0, 0, 0);
        }
      }
    __syncthreads();
  }

#pragma unroll
  for (int i = 0; i < 4; i++) {
    int row = m0 + wm * 64 + i * 16 + (lane >> 4) * 4;
#pragma unroll
    for (int j = 0; j < 4; j++) {
      int col = n0 + wn * 64 + j * 16 + (lane & 15);
#pragma unroll
      for (int r = 0; r < 4; r++) {
        if (OUT_HALF)
          Ch[(size_t)(row + r) * N + col] = (_Float16)acc[i][j][r];
        else
          Cf[(size_t)(row + r) * N + col] = acc[i][j][r];
      }
    }
  }
}

// -------- per-position head attention: 1 block (256 thr) per (b,s) -------
__global__ __launch_bounds__(256) void attn_kernel(
    const float* __restrict__ Q, const float* __restrict__ K,
    const _Float16* __restrict__ V, const float* __restrict__ mask,
    const float* __restrict__ rsQ, const float* __restrict__ rsK,
    float* __restrict__ wout, _Float16* __restrict__ aout) {
  __shared__ float lq[16][132], lkk[16][132], lv[16][132];
  __shared__ float lw[16][17];
  const int pos = blockIdx.x;
  const int t = threadIdx.x;
  const int h = t >> 4, j = t & 15;
  const size_t rowbase = (size_t)pos * DMODEL + h * DHEAD;

  const float iq = 1.f / (rsQ[(size_t)pos * NHEAD + h] + 1e-6f);
  const float ik = 1.f / (rsK[(size_t)pos * NHEAD + h] + 1e-6f);

  {
    const int dlo = 4 * j, dhi = 64 + 4 * j;
    float4 q0 = *(const float4*)&Q[rowbase + dlo];
    float4 q1 = *(const float4*)&Q[rowbase + dhi];
    q0.x *= iq; q0.y *= iq; q0.z *= iq; q0.w *= iq;
    q1.x *= iq; q1.y *= iq; q1.z *= iq; q1.w *= iq;
    *(float4*)&lq[h][dlo] = q0;
    *(float4*)&lq[h][dhi] = q1;
    float4 k0 = *(const float4*)&K[rowbase + dlo];
    float4 k1 = *(const float4*)&K[rowbase + dhi];
    k0.x *= ik; k0.y *= ik; k0.z *= ik; k0.w *= ik;
    k1.x *= ik; k1.y *= ik; k1.z *= ik; k1.w *= ik;
    *(float4*)&lkk[h][dlo] = k0;
    *(float4*)&lkk[h][dhi] = k1;
    f16x4 v0 = *(const f16x4*)&V[rowbase + dlo];
    f16x4 v1 = *(const f16x4*)&V[rowbase + dhi];
    float4 vf0 = {(float)v0[0], (float)v0[1], (float)v0[2], (float)v0[3]};
    float4 vf1 = {(float)v1[0], (float)v1[1], (float)v1[2], (float)v1[3]};
    *(float4*)&lv[h][dlo] = vf0;
    *(float4*)&lv[h][dhi] = vf1;
  }
  __syncthreads();

  const float4* qr = (const float4*)&lq[h][0];
  const float4* kr = (const float4*)&lkk[j][0];
  float dot = 0.f;
#pragma unroll
  for (int d4 = 0; d4 < 32; d4++) {
    float4 a = qr[d4], b = kr[d4];
    dot = fmaf(a.x, b.x, dot); dot = fmaf(a.y, b.y, dot);
    dot = fmaf(a.z, b.z, dot); dot = fmaf(a.w, b.w, dot);
  }
  float mk = mask[(size_t)pos * 256 + t];
  float x = (dot - 1e9f * mk) * 0.08838834764831845f;  // 1/sqrt(128)
  float mx = x;
#pragma unroll
  for (int m = 1; m < 16; m <<= 1) mx = fmaxf(mx, __shfl_xor(mx, m, 64));
  float e = expf(x - mx);
  float den = e;
#pragma unroll
  for (int m = 1; m < 16; m <<= 1) den += __shfl_xor(den, m, 64);
  float w = e / den;
  wout[(size_t)pos * 256 + t] = w;
  lw[h][j] = w;
  __syncthreads();

  float wreg[16];
#pragma unroll
  for (int k2 = 0; k2 < 16; k2++) wreg[k2] = lw[h][k2];
  float4 a0 = {0.f, 0.f, 0.f, 0.f}, a1 = {0.f, 0.f, 0.f, 0.f};
  const int dlo = 4 * j, dhi = 64 + 4 * j;
#pragma unroll
  for (int k2 = 0; k2 < 16; k2++) {
    float4 v0 = *(const float4*)&lv[k2][dlo];
    float4 v1 = *(const float4*)&lv[k2][dhi];
    float wk = wreg[k2];
    a0.x = fmaf(wk, v0.x, a0.x); a0.y = fmaf(wk, v0.y, a0.y);
    a0.z = fmaf(wk, v0.z, a0.z); a0.w = fmaf(wk, v0.w, a0.w);
    a1.x = fmaf(wk, v1.x, a1.x); a1.y = fmaf(wk, v1.y, a1.y);
    a1.z = fmaf(wk, v1.z, a1.z); a1.w = fmaf(wk, v1.w, a1.w);
  }
  f16x4 o0, o1;
  o0[0] = (_Float16)a0.x; o0[1] = (_Float16)a0.y;
  o0[2] = (_Float16)a0.z; o0[3] = (_Float16)a0.w;
  o1[0] = (_Float16)a1.x; o1[1] = (_Float16)a1.y;
  o1[2] = (_Float16)a1.z; o1[3] = (_Float16)a1.w;
  *(f16x4*)&aout[rowbase + dlo] = o0;
  *(f16x4*)&aout[rowbase + dhi] = o1;
}

// -------------------------------------------------------------------------
extern "C" void kernel_launch(void* const* d_in, const int* in_sizes, int n_in,
                              void* d_out, int out_size, void* d_ws, size_t ws_size,
                              hipStream_t stream) {
  const float* query = (const float*)d_in[0];
  const float* key   = (const float*)d_in[1];
  const float* value = (const float*)d_in[2];
  const float* mask  = (const float*)d_in[3];
  const float* Wq = (const float*)d_in[4];
  const float* Wk = (const float*)d_in[5];
  const float* Wv = (const float*)d_in[6];
  const float* Wo = (const float*)d_in[7];

  float* out  = (float*)d_out;                       // [16384, 2048] fp32
  float* wout = out + (size_t)MROWS * DMODEL;        // [16384, 256] fp32

  const size_t SZ_HALF = (size_t)MROWS * DMODEL * 2; // 67.1 MB
  const size_t SZ_F32  = (size_t)MROWS * DMODEL * 4; // 134.2 MB
  const size_t SZ_W    = (size_t)DMODEL * DMODEL * 2;// 8.4 MB
  const size_t SZ_CS   = (size_t)DMODEL * NHEAD * 4; // 128 KB (fp32)
  const size_t SZ_RS   = (size_t)MROWS * NHEAD * 4;  // 1 MB

  const int n8 = MROWS * DMODEL / 8;
  const int dpgrid = (MROWS / 256) * (DMODEL / 256); // 512 blocks, 1D
  const int ggrid = (MROWS / 128) * (DMODEL / 128);  // fallback grid
  dim3 tgrid4(DMODEL / 32, DMODEL / 32, 4);
  dim3 tgrid(DMODEL / 32, DMODEL / 32);
  dim3 tblk(32, 8);
  dim3 rsgrid(MROWS / 8, 2);
  float* Qbuf = out;   // Q fp32 parked in d_out, overwritten by final GEMM

  const size_t NEED_A = 5 * SZ_HALF + SZ_F32 + 6 * SZ_W + 2 * SZ_CS + 2 * SZ_RS;
  const size_t NEED_B = 3 * SZ_HALF + SZ_F32 + 2 * SZ_W + 2 * SZ_CS + 2 * SZ_RS;
  char* ws = (char*)d_ws;

  if (ws_size >= NEED_A) {
    size_t off = 0;
    _Float16* qh = (_Float16*)(ws + off); off += SZ_HALF;
    _Float16* ql = (_Float16*)(ws + off); off += SZ_HALF;
    _Float16* kh = (_Float16*)(ws + off); off += SZ_HALF;
    _Float16* kl = (_Float16*)(ws + off); off += SZ_HALF;
    _Float16* vh = (_Float16*)(ws + off); off += SZ_HALF;
    float*  Kbuf = (float*)   (ws + off); off += SZ_F32;
    _Float16* wqh = (_Float16*)(ws + off); off += SZ_W;
    _Float16* wql = (_Float16*)(ws + off); off += SZ_W;
    _Float16* wkh = (_Float16*)(ws + off); off += SZ_W;
    _Float16* wkl = (_Float16*)(ws + off); off += SZ_W;
    _Float16* wvh = (_Float16*)(ws + off); off += SZ_W;
    _Float16* woh = (_Float16*)(ws + off); off += SZ_W;
    float* CSq = (float*)(ws + off); off += SZ_CS;
    float* CSk = (float*)(ws + off); off += SZ_CS;
    float* rsQ = (float*)(ws + off); off += SZ_RS;
    float* rsK = (float*)(ws + off); off += SZ_RS;
    _Float16* Vbuf   = qh;   // qh dead after Q-GEMM
    _Float16* attn16 = ql;   // ql dead after Q-GEMM

    colsum_f64<<<DMODEL, 256, 0, stream>>>(Wq, CSq);
    colsum_f64<<<DMODEL, 256, 0, stream>>>(Wk, CSk);
    rowsum_v3<<<rsgrid, 256, 0, stream>>>(query, key, CSq, CSk, rsQ, rsK);
    transpose_all<<<tgrid4, tblk, 0, stream>>>(Wq, Wk, Wv, Wo, wqh, wql, wkh, wkl, wvh, woh);
    split_all<<<dim3(4096, 3), 256, 0, stream>>>(query, key, value, qh, ql, kh, kl, vh, n8);
    gemm_dp<3, 0><<<dpgrid, 512, 131072, stream>>>(qh, ql, wqh, wql, Qbuf, nullptr, MROWS, DMODEL, DMODEL);
    gemm_dp<3, 0><<<dpgrid, 512, 131072, stream>>>(kh, kl, wkh, wkl, Kbuf, nullptr, MROWS, DMODEL, DMODEL);
    gemm_dp<1, 1><<<dpgrid, 512, 65536, stream>>>(vh, nullptr, wvh, nullptr, nullptr, Vbuf, MROWS, DMODEL, DMODEL);
    attn_kernel<<<MROWS, 256, 0, stream>>>(Qbuf, Kbuf, Vbuf, mask, rsQ, rsK, wout, attn16);
    gemm_dp<1, 0><<<dpgrid, 512, 65536, stream>>>(attn16, nullptr, woh, nullptr, out, nullptr, MROWS, DMODEL, DMODEL);
    return;
  }

  if (ws_size < NEED_B) return;  // workspace too small — fail visibly

  // Fallback: sequential-reuse layout with proven 2-phase GEMM
  _Float16* a_hi  = (_Float16*)ws;
  _Float16* a_lo  = (_Float16*)(ws + SZ_HALF);
  float*    Kbuf  = (float*)   (ws + 2 * SZ_HALF);
  _Float16* Vbuf  = (_Float16*)(ws + 2 * SZ_HALF + SZ_F32);
  _Float16* wT_hi = (_Float16*)(ws + 3 * SZ_HALF + SZ_F32);
  _Float16* wT_lo = (_Float16*)(ws + 3 * SZ_HALF + SZ_F32 + SZ_W);
  float*    CSq   = (float*)   (ws + 3 * SZ_HALF + SZ_F32 + 2 * SZ_W);
  float*    CSk   = (float*)   (ws + 3 * SZ_HALF + SZ_F32 + 2 * SZ_W + SZ_CS);
  float*    rsQ   = (float*)   (ws + 3 * SZ_HALF + SZ_F32 + 2 * SZ_W + 2 * SZ_CS);
  float*    rsK   = (float*)   (ws + 3 * SZ_HALF + SZ_F32 + 2 * SZ_W + 2 * SZ_CS + SZ_RS);
  _Float16* attn16 = a_hi;

  colsum_f64<<<DMODEL, 256, 0, stream>>>(Wq, CSq);
  colsum_f64<<<DMODEL, 256, 0, stream>>>(Wk, CSk);
  rowsum_v3<<<rsgrid, 256, 0, stream>>>(query, key, CSq, CSk, rsQ, rsK);

  split_f32_f16<<<4096, 256, 0, stream>>>(query, a_hi, a_lo, n8);
  transpose_split<<<tgrid, tblk, 0, stream>>>(Wq, wT_hi, wT_lo);
  gemm_f16<3, 0><<<ggrid, 256, 0, stream>>>(a_hi, a_lo, wT_hi, wT_lo, Qbuf, nullptr, MROWS, DMODEL, DMODEL);
  split_f32_f16<<<4096, 256, 0, stream>>>(key, a_hi, a_lo, n8);
  transpose_split<<<tgrid, tblk, 0, stream>>>(Wk, wT_hi, wT_lo);
  gemm_f16<3, 0><<<ggrid, 256, 0, stream>>>(a_hi, a_lo, wT_hi, wT_lo, Kbuf, nullptr, MROWS, DMODEL, DMODEL);
  split_f32_f16<<<4096, 256, 0, stream>>>(value, a_hi, nullptr, n8);
  transpose_split<<<tgrid, tblk, 0, stream>>>(Wv, wT_hi, nullptr);
  gemm_f16<1, 1><<<ggrid, 256, 0, stream>>>(a_hi, nullptr, wT_hi, nullptr, nullptr, Vbuf, MROWS, DMODEL, DMODEL);
  attn_kernel<<<MROWS, 256, 0, stream>>>(Qbuf, Kbuf, Vbuf, mask, rsQ, rsK, wout, attn16);
  transpose_split<<<tgrid, tblk, 0, stream>>>(Wo, wT_hi, nullptr);
  gemm_f16<1, 0><<<ggrid, 256, 0, stream>>>(attn16, nullptr, wT_hi, nullptr, out, nullptr, MROWS, DMODEL, DMODEL);
}

// Round 10
// 1552.849 us; speedup vs baseline: 1.4310x; 1.0032x over previous
//
#include <hip/hip_runtime.h>
#include <hip/hip_fp16.h>

#define NHEAD 16
#define DHEAD 128
#define DMODEL 2048
#define SEQ 4096
#define BATCH 4
#define MROWS (BATCH*SEQ)   // 16384

typedef _Float16 f16x8 __attribute__((ext_vector_type(8)));
typedef _Float16 f16x4 __attribute__((ext_vector_type(4)));
typedef float f32x4 __attribute__((ext_vector_type(4)));

// ---------------- fp32 -> fp16 (hi, lo) split, 8 elems/thread ------------
__device__ inline void split8(const float* __restrict__ x, _Float16* __restrict__ hi,
                              _Float16* __restrict__ lo, int i8) {
  float4 v0 = ((const float4*)x)[2 * i8];
  float4 v1 = ((const float4*)x)[2 * i8 + 1];
  f16x8 h, l;
  h[0] = (_Float16)v0.x; h[1] = (_Float16)v0.y;
  h[2] = (_Float16)v0.z; h[3] = (_Float16)v0.w;
  h[4] = (_Float16)v1.x; h[5] = (_Float16)v1.y;
  h[6] = (_Float16)v1.z; h[7] = (_Float16)v1.w;
  ((f16x8*)hi)[i8] = h;
  if (lo) {
    l[0] = (_Float16)(v0.x - (float)h[0]);
    l[1] = (_Float16)(v0.y - (float)h[1]);
    l[2] = (_Float16)(v0.z - (float)h[2]);
    l[3] = (_Float16)(v0.w - (float)h[3]);
    l[4] = (_Float16)(v1.x - (float)h[4]);
    l[5] = (_Float16)(v1.y - (float)h[5]);
    l[6] = (_Float16)(v1.z - (float)h[6]);
    l[7] = (_Float16)(v1.w - (float)h[7]);
    ((f16x8*)lo)[i8] = l;
  }
}

// one matrix per launch (fallback path)
__global__ __launch_bounds__(256) void split_f32_f16(
    const float* __restrict__ x, _Float16* __restrict__ hi,
    _Float16* __restrict__ lo, int n8) {
  int i = blockIdx.x * blockDim.x + threadIdx.x;
  int stride = gridDim.x * blockDim.x;
  for (; i < n8; i += stride) split8(x, hi, lo, i);
}

// all three matrices in one launch (blockIdx.y selects)
__global__ __launch_bounds__(256) void split_all(
    const float* __restrict__ q, const float* __restrict__ k,
    const float* __restrict__ v,
    _Float16* __restrict__ qh, _Float16* __restrict__ ql,
    _Float16* __restrict__ kh, _Float16* __restrict__ kl,
    _Float16* __restrict__ vh, int n8) {
  const float* x; _Float16* hi; _Float16* lo;
  if (blockIdx.y == 0)      { x = q; hi = qh; lo = ql; }
  else if (blockIdx.y == 1) { x = k; hi = kh; lo = kl; }
  else                      { x = v; hi = vh; lo = nullptr; }
  int i = blockIdx.x * blockDim.x + threadIdx.x;
  int stride = gridDim.x * blockDim.x;
  for (; i < n8; i += stride) split8(x, hi, lo, i);
}

// ------------- weight transpose + split: W[K][N] -> WT[N][K] f16 ---------
__device__ inline void transpose_body(const float* __restrict__ W,
                                      _Float16* __restrict__ hi,
                                      _Float16* __restrict__ lo,
                                      int bx, int by, int tx, int ty) {
  __shared__ float tile[32][33];
  int c = bx * 32 + tx;
  for (int r0 = 0; r0 < 32; r0 += 8) {
    int r = by * 32 + ty + r0;
    tile[ty + r0][tx] = W[(size_t)r * DMODEL + c];
  }
  __syncthreads();
  for (int r0 = 0; r0 < 32; r0 += 8) {
    int n = bx * 32 + ty + r0;             // WT row = original col
    int k = by * 32 + tx;                  // WT col = original row
    float v = tile[tx][ty + r0];           // = W[k][n]
    _Float16 h = (_Float16)v;
    hi[(size_t)n * DMODEL + k] = h;
    if (lo) lo[(size_t)n * DMODEL + k] = (_Float16)(v - (float)h);
  }
}

__global__ __launch_bounds__(256) void transpose_split(
    const float* __restrict__ W, _Float16* __restrict__ hi,
    _Float16* __restrict__ lo) {
  transpose_body(W, hi, lo, blockIdx.x, blockIdx.y, threadIdx.x, threadIdx.y);
}

// all four weights in one launch (blockIdx.z selects)
__global__ __launch_bounds__(256) void transpose_all(
    const float* __restrict__ Wq, const float* __restrict__ Wk,
    const float* __restrict__ Wv, const float* __restrict__ Wo,
    _Float16* __restrict__ qh, _Float16* __restrict__ ql,
    _Float16* __restrict__ kh, _Float16* __restrict__ kl,
    _Float16* __restrict__ vh, _Float16* __restrict__ oh) {
  const float* W; _Float16* hi; _Float16* lo;
  switch (blockIdx.z) {
    case 0:  W = Wq; hi = qh; lo = ql;      break;
    case 1:  W = Wk; hi = kh; lo = kl;      break;
    case 2:  W = Wv; hi = vh; lo = nullptr; break;
    default: W = Wo; hi = oh; lo = nullptr; break;
  }
  transpose_body(W, hi, lo, blockIdx.x, blockIdx.y, threadIdx.x, threadIdx.y);
}

// ---- per-head column sums of W, stored TRANSPOSED: CS_T[h][k] -----------
__global__ __launch_bounds__(256) void colsum_f64(
    const float* __restrict__ W, float* __restrict__ CS) {
  const int k = blockIdx.x;                 // row of W
  const int t = threadIdx.x;
  const int h = t >> 4, s = t & 15;
  double acc = 0.0;
  const float* p = W + (size_t)k * DMODEL + h * DHEAD + s * 8;
#pragma unroll
  for (int i = 0; i < 8; i++) acc += (double)p[i];
#pragma unroll
  for (int m = 1; m < 16; m <<= 1) acc += __shfl_xor(acc, m, 64);
  if (s == 0) CS[(size_t)h * DMODEL + k] = (float)acc;
}

// ---- exact per-head row sums, v3: both operands lane-consecutive --------
__global__ __launch_bounds__(256) void rowsum_v3(
    const float* __restrict__ q, const float* __restrict__ k,
    const float* __restrict__ CSq, const float* __restrict__ CSk,
    float* __restrict__ rsQ, float* __restrict__ rsK) {
  const float* X;  const float* CS;  float* rs;
  if (blockIdx.y == 0) { X = q; CS = CSq; rs = rsQ; }
  else                 { X = k; CS = CSk; rs = rsK; }
  const int t = threadIdx.x;
  const int lane = t & 63, w = t >> 6;
  const int row0 = blockIdx.x * 8 + w * 2;     // 2 rows per wave

  const float4* x0 = (const float4*)(X + ((size_t)row0 << 11));
  const float4* x1 = (const float4*)(X + ((size_t)(row0 + 1) << 11));
  float4 xa[8], xb[8];
#pragma unroll
  for (int i = 0; i < 8; i++) {
    xa[i] = x0[i * 64 + lane];
    xb[i] = x1[i * 64 + lane];
  }
  const float4* cs4 = (const float4*)CS;

  for (int h = 0; h < 16; h++) {
    double a0 = 0.0, a1 = 0.0;
#pragma unroll
    for (int i = 0; i < 8; i++) {
      float4 cv = cs4[h * 512 + i * 64 + lane];
      a0 += (double)xa[i].x * (double)cv.x + (double)xa[i].y * (double)cv.y
          + (double)xa[i].z * (double)cv.z + (double)xa[i].w * (double)cv.w;
      a1 += (double)xb[i].x * (double)cv.x + (double)xb[i].y * (double)cv.y
          + (double)xb[i].z * (double)cv.z + (double)xb[i].w * (double)cv.w;
    }
#pragma unroll
    for (int m = 1; m < 64; m <<= 1) {
      a0 += __shfl_xor(a0, m, 64);
      a1 += __shfl_xor(a1, m, 64);
    }
    if (lane == 0) {
      rs[(size_t)row0 * NHEAD + h]       = (float)a0;
      rs[(size_t)(row0 + 1) * NHEAD + h] = (float)a1;
    }
  }
}

// -------------------------- async global->LDS ----------------------------
__device__ inline void glds16(const void* g, void* l) {
  __builtin_amdgcn_global_load_lds(
      (const __attribute__((address_space(1))) unsigned int*)g,
      (__attribute__((address_space(3))) unsigned int*)l, 16, 0, 0);
}

// ========== deep-pipelined 256x256 GEMM, counted vmcnt/lgkmcnt ===========
// C[M,N] = A[M,K] @ BT[N,K]^T ; NPASS=3: near-fp32 via hi/lo fp16 split.
// 8 waves (2m x 4n), per-wave 128x64 output. BK=32. Double-buffered LDS.
// NOTE __launch_bounds__(512, 1): acc needs 128 VGPR + 64 frag regs; the
// earlier (512,2) bound capped VGPR at 128 and SPILLED the accumulators
// (R9: VGPR_Count=120, 3x slowdown). LDS (128KB) limits to 1 block/CU
// anyway for NPASS=3, so min-waves=1 costs nothing.
#define DP_LGKM_P() do { \
  if constexpr (NPASS == 3) asm volatile("s_waitcnt lgkmcnt(4)" ::: "memory"); \
  else                      asm volatile("s_waitcnt lgkmcnt(2)" ::: "memory"); \
  __builtin_amdgcn_sched_barrier(0); } while (0)
#define DP_LGKM_0() do { \
  asm volatile("s_waitcnt lgkmcnt(0)" ::: "memory"); \
  __builtin_amdgcn_sched_barrier(0); } while (0)
#define DP_VMCNT_P() do { \
  if constexpr (NPASS == 3) asm volatile("s_waitcnt vmcnt(8)" ::: "memory"); \
  else                      asm volatile("s_waitcnt vmcnt(4)" ::: "memory"); \
  __builtin_amdgcn_sched_barrier(0); } while (0)
#define DP_VMCNT_0() do { \
  asm volatile("s_waitcnt vmcnt(0)" ::: "memory"); \
  __builtin_amdgcn_sched_barrier(0); } while (0)
#define DP_BAR() do { \
  asm volatile("" ::: "memory"); \
  __builtin_amdgcn_s_barrier(); \
  asm volatile("" ::: "memory"); } while (0)
#define DP_QUAD(AR, P) do { \
  __builtin_amdgcn_s_setprio(1); \
  _Pragma("unroll") \
  for (int i_ = 0; i_ < 2; i_++) \
    _Pragma("unroll") \
    for (int n_ = 0; n_ < 4; n_++) { \
      acc[2*(P)+i_][n_] = __builtin_amdgcn_mfma_f32_16x16x32_f16(AR[i_], bhF[n_], acc[2*(P)+i_][n_], 0, 0, 0); \
      if constexpr (NPASS == 3) { \
        acc[2*(P)+i_][n_] = __builtin_amdgcn_mfma_f32_16x16x32_f16(AR[i_], blF[n_], acc[2*(P)+i_][n_], 0, 0, 0); \
        acc[2*(P)+i_][n_] = __builtin_amdgcn_mfma_f32_16x16x32_f16(AR[2+i_], bhF[n_], acc[2*(P)+i_][n_], 0, 0, 0); \
      } \
    } \
  __builtin_amdgcn_s_setprio(0); } while (0)

template <int NPASS, int OUT_HALF>
__global__ __launch_bounds__(512, 1) void gemm_dp(
    const _Float16* __restrict__ Ahi, const _Float16* __restrict__ Alo,
    const _Float16* __restrict__ Bhi, const _Float16* __restrict__ Blo,
    float* __restrict__ Cf, _Float16* __restrict__ Ch,
    int M, int N, int Kd) {
  extern __shared__ char smem_raw[];
  constexpr int NMAT = (NPASS == 3) ? 4 : 2;
  constexpr int NLD  = NMAT * 2;                      // glds16 per thread/tile
  constexpr int BUFB = NMAT * 16384;                  // bytes per K-tile buf
  constexpr int BOFF = (NPASS == 3) ? 32768 : 16384;  // Bhi byte offset

  const int t = threadIdx.x;
  const int lane = t & 63, wid = t >> 6;
  const int wm = wid >> 2, wn = wid & 3;              // 2 x 4 waves
  const int lr = lane & 15;
  // swizzled per-thread k-byte offset for LDS reads (row-quad = (lr>>1)&3)
  const int lkbs = (((lane >> 4) ^ ((lr >> 1) & 3)) << 4);

  // XCD-chunked bijective swizzle (nwg = 512, %8 == 0)
  const int mtiles = M >> 8, ntiles = N >> 8;
  const int nwg = mtiles * ntiles;
  const int qq = nwg >> 3;
  const int v = (blockIdx.x & 7) * qq + (blockIdx.x >> 3);
  const int m0 = (v / ntiles) << 8, n0 = (v % ntiles) << 8;
  const int NT = Kd >> 5;

  f32x4 acc[8][4] = {};
  f16x8 bhF[4], blF[4], aA[4], aB[4];

  // hoisted STAGE addressing: per-thread global base ptrs + LDS dest offs
  const char* gsrc[NLD];
  int ldst[NLD];
#pragma unroll
  for (int j = 0; j < NLD; j++) {
    int s = t + j * 512;                 // slot; runs never cross matrices
    int mm = s >> 10;
    int r = (s & 1023) >> 2;
    int g = s & 3;
    int gs = g ^ ((r >> 1) & 3);         // pre-swizzled source k-chunk
    const _Float16* src; int rb;
    if (mm == 0)      { src = Ahi; rb = m0 + r; }
    else if (mm == 1) { src = (NPASS == 3) ? Alo : Bhi;
                        rb = ((NPASS == 3) ? m0 : n0) + r; }
    else if (mm == 2) { src = Bhi; rb = n0 + r; }
    else              { src = Blo; rb = n0 + r; }
    gsrc[j] = (const char*)(src + (size_t)rb * Kd + gs * 8);
    ldst[j] = s * 16;
  }

  auto STAGE = [&](int kt, int c) {
    char* dstb = smem_raw + c * BUFB;
    const size_t kb = (size_t)kt << 6;   // kt*32 f16 = kt*64 bytes
#pragma unroll
    for (int j = 0; j < NLD; j++)
      glds16(gsrc[j] + kb, dstb + ldst[j]);
  };
  auto RD_B = [&](const char* buf) {
#pragma unroll
    for (int n = 0; n < 4; n++) {
      int row = wn * 64 + n * 16 + lr;
      bhF[n] = *(const f16x8*)(buf + BOFF + row * 64 + lkbs);
      if constexpr (NPASS == 3)
        blF[n] = *(const f16x8*)(buf + BOFF + 16384 + row * 64 + lkbs);
    }
  };
  auto RD_A = [&](const char* buf, int p, f16x8* d) {
#pragma unroll
    for (int i = 0; i < 2; i++) {
      int row = wm * 128 + (2 * p + i) * 16 + lr;
      d[i] = *(const f16x8*)(buf + row * 64 + lkbs);
      if constexpr (NPASS == 3)
        d[2 + i] = *(const f16x8*)(buf + 16384 + row * 64 + lkbs);
    }
  };

  // prologue: tiles 0 and 1 staged; wait tile 0 landed (counted)
  STAGE(0, 0);
  STAGE(1, 1);
  DP_VMCNT_P();
  DP_BAR();

  for (int kt = 0; kt < NT; kt++) {
    const char* buf = (const char*)smem_raw + (kt & 1) * BUFB;
    RD_B(buf);
    RD_A(buf, 0, aA);
    RD_A(buf, 1, aB);
    DP_LGKM_P();                 // B + A-pair0 in regs (A-pair1 in flight)
    DP_QUAD(aA, 0);
    RD_A(buf, 2, aA);
    DP_LGKM_P();                 // A-pair1 ready
    DP_QUAD(aB, 1);
    RD_A(buf, 3, aB);
    DP_LGKM_P();                 // A-pair2 ready
    DP_QUAD(aA, 2);
    DP_LGKM_0();                 // all reads of tile kt done (this wave)
    DP_BAR();                    // ... and block-wide -> safe to overwrite
    if (kt + 2 < NT) {
      STAGE(kt + 2, kt & 1);     // into the buffer we just finished reading
      DP_QUAD(aB, 3);
      DP_VMCNT_P();              // tile kt+1 landed; kt+2 stays in flight
    } else {
      DP_QUAD(aB, 3);
      DP_VMCNT_0();              // epilogue drain
    }
    DP_BAR();                    // publish buf (kt+1)&1
  }

  // epilogue: C write
#pragma unroll
  for (int mi = 0; mi < 8; mi++) {
    int row = m0 + wm * 128 + mi * 16 + ((lane >> 4) << 2);
#pragma unroll
    for (int n = 0; n < 4; n++) {
      int col = n0 + wn * 64 + n * 16 + (lane & 15);
#pragma unroll
      for (int r = 0; r < 4; r++) {
        if constexpr (OUT_HALF)
          Ch[(size_t)(row + r) * N + col] = (_Float16)acc[mi][n][r];
        else
          Cf[(size_t)(row + r) * N + col] = acc[mi][n][r];
      }
    }
  }
}
#undef DP_LGKM_P
#undef DP_LGKM_0
#undef DP_VMCNT_P
#undef DP_VMCNT_0
#undef DP_BAR
#undef DP_QUAD

// ---------------- fallback 128x128 2-phase GEMM (proven) -----------------
template <int NPASS, int OUT_HALF>
__global__ __launch_bounds__(256) void gemm_f16(
    const _Float16* __restrict__ Ahi, const _Float16* __restrict__ Alo,
    const _Float16* __restrict__ Bhi, const _Float16* __restrict__ Blo,
    float* __restrict__ Cf, _Float16* __restrict__ Ch,
    int M, int N, int Kd) {
  constexpr int TILE = 128 * 32;
  __shared__ _Float16 lds[(NPASS == 3 ? 4 : 2) * TILE];
  _Float16* sAh = lds;
  _Float16* sBh = lds + (NPASS == 3 ? 2 : 1) * TILE;
  _Float16* sAl = lds + TILE;
  _Float16* sBl = lds + 3 * TILE;

  const int t = threadIdx.x;
  const int lane = t & 63, wid = t >> 6;
  const int wm = wid >> 1, wn = wid & 1;
  const int lr = lane & 15, lk = (lane >> 4) * 8;

  const int mtiles = M >> 7, ntiles = N >> 7;
  const int nwg = mtiles * ntiles;
  const int qq = nwg >> 3;
  const int v = (blockIdx.x & 7) * qq + (blockIdx.x >> 3);
  const int mx = v / ntiles, ny = v % ntiles;
  const int m0 = mx * 128, n0 = ny * 128;

  f32x4 acc[4][4] = {};

  for (int k0 = 0; k0 < Kd; k0 += 32) {
#pragma unroll
    for (int i = 0; i < 2; i++) {
      int slot = t + i * 256;
      int row = slot >> 2, kc = (slot & 3) * 8;
      glds16(Ahi + (size_t)(m0 + row) * Kd + k0 + kc, sAh + slot * 8);
      glds16(Bhi + (size_t)(n0 + row) * Kd + k0 + kc, sBh + slot * 8);
      if (NPASS == 3) {
        glds16(Alo + (size_t)(m0 + row) * Kd + k0 + kc, sAl + slot * 8);
        glds16(Blo + (size_t)(n0 + row) * Kd + k0 + kc, sBl + slot * 8);
      }
    }
    __syncthreads();

    f16x8 ah[4], bh[4], al[4], bl[4];
#pragma unroll
    for (int f = 0; f < 4; f++) {
      ah[f] = *(const f16x8*)&sAh[(wm * 64 + f * 16 + lr) * 32 + lk];
      bh[f] = *(const f16x8*)&sBh[(wn * 64 + f * 16 + lr) * 32 + lk];
      if (NPASS == 3) {
        al[f] = *(const f16x8*)&sAl[(wm * 64 + f * 16 + lr) * 32 + lk];
        bl[f] = *(const f16x8*)&sBl[(wn * 64 + f * 16 + lr) * 32 + lk];
      }
    }
#pragma unroll
    for (int i = 0; i < 4; i++)
#pragma unroll
      for (int j = 0; j < 4; j++) {
        acc[i][j] = __builtin_amdgcn_mfma_f32_16x16x32_f16(ah[i], bh[j], acc[i][j], 0, 0, 0);
        if (NPASS == 3) {
          acc[i][j] = __builtin_amdgcn_mfma_f32_16x16x32_f16(ah[i], bl[j], acc[i][j], 0, 0, 0);
          acc[i][j] = __builtin_amdgcn_mfma_f32_16x16x32_f16(al[i], bh[j], acc[i][j], 0, 0, 0);
        }
      }
    __syncthreads();
  }

#pragma unroll
  for (int i = 0; i < 4; i++) {
    int row = m0 + wm * 64 + i * 16 + (lane >> 4) * 4;
#pragma unroll
    for (int j = 0; j < 4; j++) {
      int col = n0 + wn * 64 + j * 16 + (lane & 15);
#pragma unroll
      for (int r = 0; r < 4; r++) {
        if (OUT_HALF)
          Ch[(size_t)(row + r) * N + col] = (_Float16)acc[i][j][r];
        else
          Cf[(size_t)(row + r) * N + col] = acc[i][j][r];
      }
    }
  }
}

// -------- per-position head attention: 1 block (256 thr) per (b,s) -------
__global__ __launch_bounds__(256) void attn_kernel(
    const float* __restrict__ Q, const float* __restrict__ K,
    const _Float16* __restrict__ V, const float* __restrict__ mask,
    const float* __restrict__ rsQ, const float* __restrict__ rsK,
    float* __restrict__ wout, _Float16* __restrict__ aout) {
  __shared__ float lq[16][132], lkk[16][132], lv[16][132];
  __shared__ float lw[16][17];
  const int pos = blockIdx.x;
  const int t = threadIdx.x;
  const int h = t >> 4, j = t & 15;
  const size_t rowbase = (size_t)pos * DMODEL + h * DHEAD;

  const float iq = 1.f / (rsQ[(size_t)pos * NHEAD + h] + 1e-6f);
  const float ik = 1.f / (rsK[(size_t)pos * NHEAD + h] + 1e-6f);

  {
    const int dlo = 4 * j, dhi = 64 + 4 * j;
    float4 q0 = *(const float4*)&Q[rowbase + dlo];
    float4 q1 = *(const float4*)&Q[rowbase + dhi];
    q0.x *= iq; q0.y *= iq; q0.z *= iq; q0.w *= iq;
    q1.x *= iq; q1.y *= iq; q1.z *= iq; q1.w *= iq;
    *(float4*)&lq[h][dlo] = q0;
    *(float4*)&lq[h][dhi] = q1;
    float4 k0 = *(const float4*)&K[rowbase + dlo];
    float4 k1 = *(const float4*)&K[rowbase + dhi];
    k0.x *= ik; k0.y *= ik; k0.z *= ik; k0.w *= ik;
    k1.x *= ik; k1.y *= ik; k1.z *= ik; k1.w *= ik;
    *(float4*)&lkk[h][dlo] = k0;
    *(float4*)&lkk[h][dhi] = k1;
    f16x4 v0 = *(const f16x4*)&V[rowbase + dlo];
    f16x4 v1 = *(const f16x4*)&V[rowbase + dhi];
    float4 vf0 = {(float)v0[0], (float)v0[1], (float)v0[2], (float)v0[3]};
    float4 vf1 = {(float)v1[0], (float)v1[1], (float)v1[2], (float)v1[3]};
    *(float4*)&lv[h][dlo] = vf0;
    *(float4*)&lv[h][dhi] = vf1;
  }
  __syncthreads();

  const float4* qr = (const float4*)&lq[h][0];
  const float4* kr = (const float4*)&lkk[j][0];
  float dot = 0.f;
#pragma unroll
  for (int d4 = 0; d4 < 32; d4++) {
    float4 a = qr[d4], b = kr[d4];
    dot = fmaf(a.x, b.x, dot); dot = fmaf(a.y, b.y, dot);
    dot = fmaf(a.z, b.z, dot); dot = fmaf(a.w, b.w, dot);
  }
  float mk = mask[(size_t)pos * 256 + t];
  float x = (dot - 1e9f * mk) * 0.08838834764831845f;  // 1/sqrt(128)
  float mx = x;
#pragma unroll
  for (int m = 1; m < 16; m <<= 1) mx = fmaxf(mx, __shfl_xor(mx, m, 64));
  float e = expf(x - mx);
  float den = e;
#pragma unroll
  for (int m = 1; m < 16; m <<= 1) den += __shfl_xor(den, m, 64);
  float w = e / den;
  wout[(size_t)pos * 256 + t] = w;
  lw[h][j] = w;
  __syncthreads();

  float wreg[16];
#pragma unroll
  for (int k2 = 0; k2 < 16; k2++) wreg[k2] = lw[h][k2];
  float4 a0 = {0.f, 0.f, 0.f, 0.f}, a1 = {0.f, 0.f, 0.f, 0.f};
  const int dlo = 4 * j, dhi = 64 + 4 * j;
#pragma unroll
  for (int k2 = 0; k2 < 16; k2++) {
    float4 v0 = *(const float4*)&lv[k2][dlo];
    float4 v1 = *(const float4*)&lv[k2][dhi];
    float wk = wreg[k2];
    a0.x = fmaf(wk, v0.x, a0.x); a0.y = fmaf(wk, v0.y, a0.y);
    a0.z = fmaf(wk, v0.z, a0.z); a0.w = fmaf(wk, v0.w, a0.w);
    a1.x = fmaf(wk, v1.x, a1.x); a1.y = fmaf(wk, v1.y, a1.y);
    a1.z = fmaf(wk, v1.z, a1.z); a1.w = fmaf(wk, v1.w, a1.w);
  }
  f16x4 o0, o1;
  o0[0] = (_Float16)a0.x; o0[1] = (_Float16)a0.y;
  o0[2] = (_Float16)a0.z; o0[3] = (_Float16)a0.w;
  o1[0] = (_Float16)a1.x; o1[1] = (_Float16)a1.y;
  o1[2] = (_Float16)a1.z; o1[3] = (_Float16)a1.w;
  *(f16x4*)&aout[rowbase + dlo] = o0;
  *(f16x4*)&aout[rowbase + dhi] = o1;
}

// -------------------------------------------------------------------------
extern "C" void kernel_launch(void* const* d_in, const int* in_sizes, int n_in,
                              void* d_out, int out_size, void* d_ws, size_t ws_size,
                              hipStream_t stream) {
  const float* query = (const float*)d_in[0];
  const float* key   = (const float*)d_in[1];
  const float* value = (const float*)d_in[2];
  const float* mask  = (const float*)d_in[3];
  const float* Wq = (const float*)d_in[4];
  const float* Wk = (const float*)d_in[5];
  const float* Wv = (const float*)d_in[6];
  const float* Wo = (const float*)d_in[7];

  float* out  = (float*)d_out;                       // [16384, 2048] fp32
  float* wout = out + (size_t)MROWS * DMODEL;        // [16384, 256] fp32

  const size_t SZ_HALF = (size_t)MROWS * DMODEL * 2; // 67.1 MB
  const size_t SZ_F32  = (size_t)MROWS * DMODEL * 4; // 134.2 MB
  const size_t SZ_W    = (size_t)DMODEL * DMODEL * 2;// 8.4 MB
  const size_t SZ_CS   = (size_t)DMODEL * NHEAD * 4; // 128 KB (fp32)
  const size_t SZ_RS   = (size_t)MROWS * NHEAD * 4;  // 1 MB

  const int n8 = MROWS * DMODEL / 8;
  const int dpgrid = (MROWS / 256) * (DMODEL / 256); // 512 blocks, 1D
  const int ggrid = (MROWS / 128) * (DMODEL / 128);  // fallback grid
  dim3 tgrid4(DMODEL / 32, DMODEL / 32, 4);
  dim3 tgrid(DMODEL / 32, DMODEL / 32);
  dim3 tblk(32, 8);
  dim3 rsgrid(MROWS / 8, 2);
  float* Qbuf = out;   // Q fp32 parked in d_out, overwritten by final GEMM

  const size_t NEED_A = 5 * SZ_HALF + SZ_F32 + 6 * SZ_W + 2 * SZ_CS + 2 * SZ_RS;
  const size_t NEED_B = 3 * SZ_HALF + SZ_F32 + 2 * SZ_W + 2 * SZ_CS + 2 * SZ_RS;
  char* ws = (char*)d_ws;

  if (ws_size >= NEED_A) {
    size_t off = 0;
    _Float16* qh = (_Float16*)(ws + off); off += SZ_HALF;
    _Float16* ql = (_Float16*)(ws + off); off += SZ_HALF;
    _Float16* kh = (_Float16*)(ws + off); off += SZ_HALF;
    _Float16* kl = (_Float16*)(ws + off); off += SZ_HALF;
    _Float16* vh = (_Float16*)(ws + off); off += SZ_HALF;
    float*  Kbuf = (float*)   (ws + off); off += SZ_F32;
    _Float16* wqh = (_Float16*)(ws + off); off += SZ_W;
    _Float16* wql = (_Float16*)(ws + off); off += SZ_W;
    _Float16* wkh = (_Float16*)(ws + off); off += SZ_W;
    _Float16* wkl = (_Float16*)(ws + off); off += SZ_W;
    _Float16* wvh = (_Float16*)(ws + off); off += SZ_W;
    _Float16* woh = (_Float16*)(ws + off); off += SZ_W;
    float* CSq = (float*)(ws + off); off += SZ_CS;
    float* CSk = (float*)(ws + off); off += SZ_CS;
    float* rsQ = (float*)(ws + off); off += SZ_RS;
    float* rsK = (float*)(ws + off); off += SZ_RS;
    _Float16* Vbuf   = qh;   // qh dead after Q-GEMM
    _Float16* attn16 = ql;   // ql dead after Q-GEMM

    colsum_f64<<<DMODEL, 256, 0, stream>>>(Wq, CSq);
    colsum_f64<<<DMODEL, 256, 0, stream>>>(Wk, CSk);
    rowsum_v3<<<rsgrid, 256, 0, stream>>>(query, key, CSq, CSk, rsQ, rsK);
    transpose_all<<<tgrid4, tblk, 0, stream>>>(Wq, Wk, Wv, Wo, wqh, wql, wkh, wkl, wvh, woh);
    split_all<<<dim3(4096, 3), 256, 0, stream>>>(query, key, value, qh, ql, kh, kl, vh, n8);
    gemm_dp<3, 0><<<dpgrid, 512, 131072, stream>>>(qh, ql, wqh, wql, Qbuf, nullptr, MROWS, DMODEL, DMODEL);
    gemm_dp<3, 0><<<dpgrid, 512, 131072, stream>>>(kh, kl, wkh, wkl, Kbuf, nullptr, MROWS, DMODEL, DMODEL);
    gemm_dp<1, 1><<<dpgrid, 512, 65536, stream>>>(vh, nullptr, wvh, nullptr, nullptr, Vbuf, MROWS, DMODEL, DMODEL);
    attn_kernel<<<MROWS, 256, 0, stream>>>(Qbuf, Kbuf, Vbuf, mask, rsQ, rsK, wout, attn16);
    gemm_dp<1, 0><<<dpgrid, 512, 65536, stream>>>(attn16, nullptr, woh, nullptr, out, nullptr, MROWS, DMODEL, DMODEL);
    return;
  }

  if (ws_size < NEED_B) return;  // workspace too small — fail visibly

  // Fallback: sequential-reuse layout with proven 2-phase GEMM
  _Float16* a_hi  = (_Float16*)ws;
  _Float16* a_lo  = (_Float16*)(ws + SZ_HALF);
  float*    Kbuf  = (float*)   (ws + 2 * SZ_HALF);
  _Float16* Vbuf  = (_Float16*)(ws + 2 * SZ_HALF + SZ_F32);
  _Float16* wT_hi = (_Float16*)(ws + 3 * SZ_HALF + SZ_F32);
  _Float16* wT_lo = (_Float16*)(ws + 3 * SZ_HALF + SZ_F32 + SZ_W);
  float*    CSq   = (float*)   (ws + 3 * SZ_HALF + SZ_F32 + 2 * SZ_W);
  float*    CSk   = (float*)   (ws + 3 * SZ_HALF + SZ_F32 + 2 * SZ_W + SZ_CS);
  float*    rsQ   = (float*)   (ws + 3 * SZ_HALF + SZ_F32 + 2 * SZ_W + 2 * SZ_CS);
  float*    rsK   = (float*)   (ws + 3 * SZ_HALF + SZ_F32 + 2 * SZ_W + 2 * SZ_CS + SZ_RS);
  _Float16* attn16 = a_hi;

  colsum_f64<<<DMODEL, 256, 0, stream>>>(Wq, CSq);
  colsum_f64<<<DMODEL, 256, 0, stream>>>(Wk, CSk);
  rowsum_v3<<<rsgrid, 256, 0, stream>>>(query, key, CSq, CSk, rsQ, rsK);

  split_f32_f16<<<4096, 256, 0, stream>>>(query, a_hi, a_lo, n8);
  transpose_split<<<tgrid, tblk, 0, stream>>>(Wq, wT_hi, wT_lo);
  gemm_f16<3, 0><<<ggrid, 256, 0, stream>>>(a_hi, a_lo, wT_hi, wT_lo, Qbuf, nullptr, MROWS, DMODEL, DMODEL);
  split_f32_f16<<<4096, 256, 0, stream>>>(key, a_hi, a_lo, n8);
  transpose_split<<<tgrid, tblk, 0, stream>>>(Wk, wT_hi, wT_lo);
  gemm_f16<3, 0><<<ggrid, 256, 0, stream>>>(a_hi, a_lo, wT_hi, wT_lo, Kbuf, nullptr, MROWS, DMODEL, DMODEL);
  split_f32_f16<<<4096, 256, 0, stream>>>(value, a_hi, nullptr, n8);
  transpose_split<<<tgrid, tblk, 0, stream>>>(Wv, wT_hi, nullptr);
  gemm_f16<1, 1><<<ggrid, 256, 0, stream>>>(a_hi, nullptr, wT_hi, nullptr, nullptr, Vbuf, MROWS, DMODEL, DMODEL);
  attn_kernel<<<MROWS, 256, 0, stream>>>(Qbuf, Kbuf, Vbuf, mask, rsQ, rsK, wout, attn16);
  transpose_split<<<tgrid, tblk, 0, stream>>>(Wo, wT_hi, nullptr);
  gemm_f16<1, 0><<<ggrid, 256, 0, stream>>>(attn16, nullptr, wT_hi, nullptr, out, nullptr, MROWS, DMODEL, DMODEL);
}